// Round 4
// baseline (3941.839 us; speedup 1.0000x reference)
//
#include <hip/hip_runtime.h>
#include <cstdint>
#include <cstddef>

typedef _Float16 half8 __attribute__((ext_vector_type(8)));
typedef float floatx4 __attribute__((ext_vector_type(4)));

#define FLAG_RES  1
#define FLAG_GELU 2
#define FLAG_W32  4
#define FLAG_W16  8
#define FLAG_PART 16

// Fast exact-GELU: erf via Abramowitz-Stegun 7.1.26 (|err| <= 1.5e-7), __expf.
__device__ __forceinline__ float gelu_exact(float x) {
    const float z = fabsf(x) * 0.70710678118654752f;
    const float t = 1.f / fmaf(0.3275911f, z, 1.f);
    const float p = t * (0.254829592f + t * (-0.284496736f +
                     t * (1.421413741f + t * (-1.453152027f + t * 1.061405429f))));
    const float erfa = 1.f - p * __expf(-z * z);
    return 0.5f * x * (1.f + copysignf(erfa, x));
}

// ---------------------------------------------------------------------------
// GEMM (narrow): C(MxN) = A(MxK f16 rm) @ Bt(NxK f16 rm)^T + bias(fp32)
// 128x128 tile, BK=32, 256 thr (2x2 waves of 64x64). Register prefetch +
// LDS ping-pong, ONE barrier per iteration. XOR-swizzled LDS (verified r2:
// SQ_LDS_BANK_CONFLICT 6.3M -> 0). Used for small-N / split-K shapes.
// ---------------------------------------------------------------------------
__global__ __launch_bounds__(256, 2) void gemm_f16(
    const _Float16* __restrict__ A, const _Float16* __restrict__ Bt,
    const float* __restrict__ bias, const float* __restrict__ resid,
    float* __restrict__ out32, _Float16* __restrict__ out16,
    int M, int N, int K, int klen, int flags)
{
    __shared__ __align__(16) _Float16 As[2][128 * 32];
    __shared__ __align__(16) _Float16 Bs[2][128 * 32];
    const int tid = threadIdx.x;
    const int wid = tid >> 6;
    const int lane = tid & 63;
    const int bm = blockIdx.y * 128;
    const int bn = blockIdx.x * 128;
    const int wr = wid >> 1, wc = wid & 1;
    const int lane15 = lane & 15, quad = lane >> 4;
    const int kb = blockIdx.z * klen;

    floatx4 acc[4][4];
#pragma unroll
    for (int i = 0; i < 4; i++)
#pragma unroll
        for (int j = 0; j < 4; j++)
            acc[i][j] = floatx4{0.f, 0.f, 0.f, 0.f};

    const int r4 = lane >> 2;            // row within 16-row group
    const int ch = lane & 3;             // 16B chunk index
    const _Float16* Ap = A + ((size_t)bm + wid * 32 + r4) * K + kb + ch * 8;
    const _Float16* Bp = Bt + ((size_t)bn + wid * 32 + r4) * K + kb + ch * 8;
    const size_t row16 = (size_t)16 * K;
    const int lw = wid * 1024 + r4 * 32 + ((ch ^ ((r4 >> 1) & 3)) << 3);

    int aoff[4], boff[4];
#pragma unroll
    for (int mi = 0; mi < 4; mi++)
        aoff[mi] = (wr * 64 + mi * 16 + lane15) * 32 +
                   ((quad ^ ((lane15 >> 1) & 3)) << 3);
#pragma unroll
    for (int ni = 0; ni < 4; ni++)
        boff[ni] = (wc * 64 + ni * 16 + lane15) * 32 +
                   ((quad ^ ((lane15 >> 1) & 3)) << 3);

    int4 ra0 = *(const int4*)(Ap);
    int4 ra1 = *(const int4*)(Ap + row16);
    int4 rb0 = *(const int4*)(Bp);
    int4 rb1 = *(const int4*)(Bp + row16);

    const int nk = klen >> 5;
    for (int ik = 0; ik < nk; ik++) {
        _Float16* a_ = &As[ik & 1][0];
        _Float16* b_ = &Bs[ik & 1][0];
        *(int4*)(a_ + lw) = ra0;
        *(int4*)(a_ + lw + 512) = ra1;
        *(int4*)(b_ + lw) = rb0;
        *(int4*)(b_ + lw + 512) = rb1;
        __syncthreads();
        if (ik + 1 < nk) {
            const int ko = (ik + 1) << 5;
            ra0 = *(const int4*)(Ap + ko);
            ra1 = *(const int4*)(Ap + row16 + ko);
            rb0 = *(const int4*)(Bp + ko);
            rb1 = *(const int4*)(Bp + row16 + ko);
        }
        half8 af[4], bf[4];
#pragma unroll
        for (int mi = 0; mi < 4; mi++) af[mi] = *(const half8*)&a_[aoff[mi]];
#pragma unroll
        for (int ni = 0; ni < 4; ni++) bf[ni] = *(const half8*)&b_[boff[ni]];
#pragma unroll
        for (int mi = 0; mi < 4; mi++)
#pragma unroll
            for (int ni = 0; ni < 4; ni++)
                acc[mi][ni] = __builtin_amdgcn_mfma_f32_16x16x32_f16(
                    af[mi], bf[ni], acc[mi][ni], 0, 0, 0);
    }

    if (flags & FLAG_PART) {
        float* po = out32 + (size_t)blockIdx.z * ((size_t)M * N);
#pragma unroll
        for (int mi = 0; mi < 4; mi++) {
            const int gmb = bm + wr * 64 + mi * 16 + quad * 4;
#pragma unroll
            for (int ni = 0; ni < 4; ni++) {
                const int gn = bn + wc * 64 + ni * 16 + lane15;
#pragma unroll
                for (int r = 0; r < 4; r++)
                    po[(size_t)(gmb + r) * N + gn] = acc[mi][ni][r];
            }
        }
        return;
    }
#pragma unroll
    for (int mi = 0; mi < 4; mi++) {
        const int gmb = bm + wr * 64 + mi * 16 + quad * 4;
#pragma unroll
        for (int ni = 0; ni < 4; ni++) {
            const int gn = bn + wc * 64 + ni * 16 + lane15;
            const float bv = bias[gn];
#pragma unroll
            for (int r = 0; r < 4; r++) {
                float v = acc[mi][ni][r] + bv;
                if (flags & FLAG_GELU) v = gelu_exact(v);
                const size_t off = (size_t)(gmb + r) * N + gn;
                if (flags & FLAG_RES) v += resid[off];
                if (flags & FLAG_W32) out32[off] = v;
                if (flags & FLAG_W16) out16[off] = (_Float16)v;
            }
        }
    }
}

// ---------------------------------------------------------------------------
// GEMM (wide): 128x256 tile, BK=32, 256 thr (2x2 waves, each 64x128 = 4x8
// MFMA frags). Same sync skeleton as narrow (reg prefetch -> ds_write
// ping-pong -> one barrier; loads stay in flight across barriers). Doubles
// per-wave MFMA:ds_read ratio (32:12 vs 16:8) and halves blocks per output
// (fewer prologue/epilogue amortizations, half the A/B strip re-fetch).
// Requires N % 256 == 0. No split-K / PART path.
// ---------------------------------------------------------------------------
__global__ __launch_bounds__(256, 2) void gemm_f16w(
    const _Float16* __restrict__ A, const _Float16* __restrict__ Bt,
    const float* __restrict__ bias, const float* __restrict__ resid,
    float* __restrict__ out32, _Float16* __restrict__ out16,
    int M, int N, int K, int flags)
{
    __shared__ __align__(16) _Float16 As[2][128 * 32];
    __shared__ __align__(16) _Float16 Bs[2][256 * 32];
    const int tid = threadIdx.x;
    const int wid = tid >> 6;
    const int lane = tid & 63;
    const int bm = blockIdx.y * 128;
    const int bn = blockIdx.x * 256;
    const int wr = wid >> 1, wc = wid & 1;
    const int lane15 = lane & 15, quad = lane >> 4;

    floatx4 acc[4][8];
#pragma unroll
    for (int i = 0; i < 4; i++)
#pragma unroll
        for (int j = 0; j < 8; j++)
            acc[i][j] = floatx4{0.f, 0.f, 0.f, 0.f};

    const int r4 = lane >> 2;            // row within 16-row group
    const int ch = lane & 3;             // 16B chunk index
    // A: per wave 32 rows (2 groups of 16); B: per wave 64 rows (4 groups)
    const _Float16* Ap = A + ((size_t)bm + wid * 32 + r4) * K + ch * 8;
    const _Float16* Bp = Bt + ((size_t)bn + wid * 64 + r4) * K + ch * 8;
    const size_t row16 = (size_t)16 * K;
    const int swz = ((ch ^ ((r4 >> 1) & 3)) << 3);
    const int lwA = wid * 1024 + r4 * 32 + swz;
    const int lwB = wid * 2048 + r4 * 32 + swz;

    int aoff[4], boff[8];
#pragma unroll
    for (int mi = 0; mi < 4; mi++)
        aoff[mi] = (wr * 64 + mi * 16 + lane15) * 32 +
                   ((quad ^ ((lane15 >> 1) & 3)) << 3);
#pragma unroll
    for (int ni = 0; ni < 8; ni++)
        boff[ni] = (wc * 128 + ni * 16 + lane15) * 32 +
                   ((quad ^ ((lane15 >> 1) & 3)) << 3);

    // prefetch tile 0
    int4 ra0 = *(const int4*)(Ap);
    int4 ra1 = *(const int4*)(Ap + row16);
    int4 rb0 = *(const int4*)(Bp);
    int4 rb1 = *(const int4*)(Bp + row16);
    int4 rb2 = *(const int4*)(Bp + 2 * row16);
    int4 rb3 = *(const int4*)(Bp + 3 * row16);

    const int nk = K >> 5;
    for (int ik = 0; ik < nk; ik++) {
        _Float16* a_ = &As[ik & 1][0];
        _Float16* b_ = &Bs[ik & 1][0];
        *(int4*)(a_ + lwA) = ra0;
        *(int4*)(a_ + lwA + 512) = ra1;
        *(int4*)(b_ + lwB) = rb0;
        *(int4*)(b_ + lwB + 512) = rb1;
        *(int4*)(b_ + lwB + 1024) = rb2;
        *(int4*)(b_ + lwB + 1536) = rb3;
        __syncthreads();
        if (ik + 1 < nk) {
            const int ko = (ik + 1) << 5;
            ra0 = *(const int4*)(Ap + ko);
            ra1 = *(const int4*)(Ap + row16 + ko);
            rb0 = *(const int4*)(Bp + ko);
            rb1 = *(const int4*)(Bp + row16 + ko);
            rb2 = *(const int4*)(Bp + 2 * row16 + ko);
            rb3 = *(const int4*)(Bp + 3 * row16 + ko);
        }
        half8 af[4], bf[8];
#pragma unroll
        for (int mi = 0; mi < 4; mi++) af[mi] = *(const half8*)&a_[aoff[mi]];
#pragma unroll
        for (int ni = 0; ni < 8; ni++) bf[ni] = *(const half8*)&b_[boff[ni]];
#pragma unroll
        for (int mi = 0; mi < 4; mi++)
#pragma unroll
            for (int ni = 0; ni < 8; ni++)
                acc[mi][ni] = __builtin_amdgcn_mfma_f32_16x16x32_f16(
                    af[mi], bf[ni], acc[mi][ni], 0, 0, 0);
    }

    // epilogue: C/D layout col = lane&15, row = quad*4 + reg
#pragma unroll
    for (int mi = 0; mi < 4; mi++) {
        const int gmb = bm + wr * 64 + mi * 16 + quad * 4;
#pragma unroll
        for (int ni = 0; ni < 8; ni++) {
            const int gn = bn + wc * 128 + ni * 16 + lane15;
            const float bv = bias[gn];
#pragma unroll
            for (int r = 0; r < 4; r++) {
                float v = acc[mi][ni][r] + bv;
                if (flags & FLAG_GELU) v = gelu_exact(v);
                const size_t off = (size_t)(gmb + r) * N + gn;
                if (flags & FLAG_RES) v += resid[off];
                if (flags & FLAG_W32) out32[off] = v;
                if (flags & FLAG_W16) out16[off] = (_Float16)v;
            }
        }
    }
}

// ---------------------------------------------------------------------------
// Split-K reduce: out[i] = gelu(bias[i%N] + sum_z part[z*MN + i]) as f16.
// ---------------------------------------------------------------------------
__global__ __launch_bounds__(256) void skred_k(
    const float* __restrict__ part, const float* __restrict__ bias,
    _Float16* __restrict__ out, int MN, int N, int S)
{
    const int i = blockIdx.x * 256 + threadIdx.x;
    if (i >= MN) return;
    float s = bias[i % N];
    for (int z = 0; z < S; z++) s += part[(size_t)z * MN + i];
    out[i] = (_Float16)gelu_exact(s);
}

// ---------------------------------------------------------------------------
// Fused split-K reduce (S=4, N=128) + gelu + final (128x3) matmul + bias.
// ---------------------------------------------------------------------------
__global__ __launch_bounds__(256) void skcls_k(
    const float* __restrict__ part, const float* __restrict__ b2,
    const float* __restrict__ w3, const float* __restrict__ b3,
    float* __restrict__ out, int CH)
{
    const int wid = threadIdx.x >> 6, lane = threadIdx.x & 63;
    const int b = blockIdx.x * 4 + wid;
    const size_t MN = (size_t)CH * 128;
    const int c0 = lane, c1 = lane + 64;
    float s0 = b2[c0], s1 = b2[c1];
#pragma unroll
    for (int z = 0; z < 4; z++) {
        s0 += part[z * MN + (size_t)b * 128 + c0];
        s1 += part[z * MN + (size_t)b * 128 + c1];
    }
    const float g0 = gelu_exact(s0), g1 = gelu_exact(s1);
    float a0 = g0 * w3[c0 * 3 + 0] + g1 * w3[c1 * 3 + 0];
    float a1 = g0 * w3[c0 * 3 + 1] + g1 * w3[c1 * 3 + 1];
    float a2 = g0 * w3[c0 * 3 + 2] + g1 * w3[c1 * 3 + 2];
#pragma unroll
    for (int m = 32; m >= 1; m >>= 1) {
        a0 += __shfl_xor(a0, m, 64);
        a1 += __shfl_xor(a1, m, 64);
        a2 += __shfl_xor(a2, m, 64);
    }
    if (lane == 0) {
        out[b * 3 + 0] = a0 + b3[0];
        out[b * 3 + 1] = a1 + b3[1];
        out[b * 3 + 2] = a2 + b3[2];
    }
}

// ---------------------------------------------------------------------------
// Row LayerNorm over 512 cols: fp32 in, fp32 params, f16 out. One wave/row.
// ---------------------------------------------------------------------------
__global__ __launch_bounds__(256) void ln_rows(
    const float* __restrict__ x, const float* __restrict__ w,
    const float* __restrict__ b, _Float16* __restrict__ out)
{
    const int wid = threadIdx.x >> 6, lane = threadIdx.x & 63;
    const size_t row = (size_t)blockIdx.x * 4 + wid;
    const int c0 = lane * 8;
    const float* xr = x + row * 512 + c0;
    float4 v0 = *(const float4*)xr;
    float4 v1 = *(const float4*)(xr + 4);
    float xv[8] = {v0.x, v0.y, v0.z, v0.w, v1.x, v1.y, v1.z, v1.w};
    float s = 0.f, q = 0.f;
#pragma unroll
    for (int j = 0; j < 8; j++) { s += xv[j]; q += xv[j] * xv[j]; }
#pragma unroll
    for (int m = 32; m >= 1; m >>= 1) {
        s += __shfl_xor(s, m, 64);
        q += __shfl_xor(q, m, 64);
    }
    const float mean = s * (1.f / 512.f);
    const float rstd = rsqrtf(q * (1.f / 512.f) - mean * mean + 1e-5f);
    half8 o;
#pragma unroll
    for (int j = 0; j < 8; j++)
        o[j] = (_Float16)((xv[j] - mean) * rstd * w[c0 + j] + b[c0 + j]);
    *(half8*)&out[row * 512 + c0] = o;
}

// ---------------------------------------------------------------------------
// Attention: 4 (b,head) units per 256-thread block (one wave each).
// ---------------------------------------------------------------------------
__global__ __launch_bounds__(256) void attn_k(
    const _Float16* __restrict__ qkv, _Float16* __restrict__ o)
{
    __shared__ float qs[4][12][65], ks[4][12][65], vs[4][12][65];
    __shared__ float att[4][12][16];
    const int wid = threadIdx.x >> 6, lane = threadIdx.x & 63;
    const int unit = blockIdx.x * 4 + wid;
    const int b = unit >> 3, hd = unit & 7;
    const _Float16* base = qkv + (size_t)b * (12 * 1536) + hd * 64 + lane;
#pragma unroll
    for (int r = 0; r < 12; r++) {
        qs[wid][r][lane] = (float)base[r * 1536];
        ks[wid][r][lane] = (float)base[r * 1536 + 512];
        vs[wid][r][lane] = (float)base[r * 1536 + 1024];
    }
    __syncthreads();
#pragma unroll
    for (int i = 0; i < 3; i++) {
        const int p = lane + i * 64;
        if (p < 144) {
            const int qi = p / 12, kj = p - qi * 12;
            float d = 0.f;
            for (int e = 0; e < 64; e++) d += qs[wid][qi][e] * ks[wid][kj][e];
            att[wid][qi][kj] = d * 0.125f;
        }
    }
    __syncthreads();
    if (lane < 12) {
        float mx = att[wid][lane][0];
#pragma unroll
        for (int j = 1; j < 12; j++) mx = fmaxf(mx, att[wid][lane][j]);
        float ev[12], ssum = 0.f;
#pragma unroll
        for (int j = 0; j < 12; j++) { ev[j] = expf(att[wid][lane][j] - mx); ssum += ev[j]; }
        const float inv = 1.f / ssum;
#pragma unroll
        for (int j = 0; j < 12; j++) att[wid][lane][j] = ev[j] * inv;
    }
    __syncthreads();
    _Float16* ob = o + (size_t)b * (12 * 512) + hd * 64 + lane;
#pragma unroll
    for (int qi = 0; qi < 12; qi++) {
        float s = 0.f;
#pragma unroll
        for (int j = 0; j < 12; j++) s += att[wid][qi][j] * vs[wid][j][lane];
        ob[qi * 512] = (_Float16)s;
    }
}

// ---------------------------------------------------------------------------
// Fused factors + per-(batch,feature) time-norm -> (CH*12, 96) f16 patch rows.
// ---------------------------------------------------------------------------
struct FSt { float e12, e26, ag, al, s1c, s2c, s1v; };

__device__ __forceinline__ void fderiv(
    int t, float c, float cprev, float co, float v, float vprev, float vo,
    FSt& s, float f[6])
{
    const float a12 = 2.f / 13.f, a26 = 2.f / 27.f, a14 = 1.f / 14.f;
    const float sv = v > 0.f ? v : 1.f;
    if (t > 0) {
        s.e12 = a12 * c + (1.f - a12) * s.e12;
        s.e26 = a26 * c + (1.f - a26) * s.e26;
    }
    const float macd = s.e12 - s.e26;
    const float delta = t > 0 ? c - cprev : 0.f;
    if (t > 0) {
        s.ag = a14 * fmaxf(delta, 0.f) + (1.f - a14) * s.ag;
        s.al = a14 * fmaxf(-delta, 0.f) + (1.f - a14) * s.al;
    }
    const float rs = s.ag / (s.al + 1e-10f);
    const float rsi = (100.f - 100.f / (1.f + rs)) * 0.01f;
    s.s1c += c; s.s2c += c * c; s.s1v += sv;
    if (t >= 20) {
        const float svo = vo > 0.f ? vo : 1.f;
        s.s1c -= co; s.s2c -= co * co; s.s1v -= svo;
    }
    float bb = 0.f, vmr = 1.f;
    if (t >= 19) {
        const float mean = s.s1c * 0.05f;
        const float sq = s.s2c * 0.05f;
        const float sd = sqrtf(fmaxf(sq - mean * mean, 0.f));
        bb = 4.f * sd / (mean + 1e-8f);
        vmr = sv / (s.s1v * 0.05f + 1e-8f);
    }
    float lr = 0.f, lv = 0.f;
    if (t > 0) {
        lr = logf(fmaxf(c, 1e-8f) / fmaxf(cprev, 1e-8f));
        const float svp = vprev > 0.f ? vprev : 1.f;
        lv = logf(sv / (svp + 1e-8f));
    }
    f[0] = isfinite(macd) ? macd : 0.f;
    f[1] = isfinite(rsi) ? rsi : 0.f;
    f[2] = isfinite(bb) ? bb : 0.f;
    f[3] = isfinite(lr) ? lr : 0.f;
    f[4] = isfinite(lv) ? lv : 0.f;
    f[5] = isfinite(vmr) ? vmr : 0.f;
}

__global__ __launch_bounds__(64) void factors_k(
    const float* __restrict__ x, const float* __restrict__ in_w,
    const float* __restrict__ in_b, _Float16* __restrict__ feats, int CH)
{
    const int tid = threadIdx.x;
    const int b = blockIdx.x * 64 + tid;
    if (b >= CH) return;
    __shared__ float cl[96][64];
    __shared__ float vl[96][64];
    const float* xb = x + (size_t)b * 480;

    float sum[11], ssq[11];
#pragma unroll
    for (int f = 0; f < 11; f++) { sum[f] = 0.f; ssq[f] = 0.f; }

    for (int t = 0; t < 96; t++) {
        const float* xq = xb + t * 5;
        const float a0 = xq[0], a1 = xq[1], a2 = xq[2], c = xq[3], v = xq[4];
        cl[t][tid] = c; vl[t][tid] = v;
        sum[0] += a0; ssq[0] += a0 * a0;
        sum[1] += a1; ssq[1] += a1 * a1;
        sum[2] += a2; ssq[2] += a2 * a2;
        sum[3] += c;  ssq[3] += c * c;
        sum[4] += v;  ssq[4] += v * v;
    }

    {
        const float c0 = cl[0][tid];
        FSt st{c0, c0, 0.f, 0.f, 0.f, 0.f, 0.f};
        for (int t = 0; t < 96; t++) {
            const float c = cl[t][tid], v = vl[t][tid];
            const float cp = t > 0 ? cl[t - 1][tid] : 0.f;
            const float vp = t > 0 ? vl[t - 1][tid] : 0.f;
            const float co = t >= 20 ? cl[t - 20][tid] : 0.f;
            const float vo = t >= 20 ? vl[t - 20][tid] : 0.f;
            float f6[6];
            fderiv(t, c, cp, co, v, vp, vo, st, f6);
#pragma unroll
            for (int j = 0; j < 6; j++) { sum[5 + j] += f6[j]; ssq[5 + j] += f6[j] * f6[j]; }
        }
    }
    float scale[11], shift[11];
#pragma unroll
    for (int f = 0; f < 11; f++) {
        const float m = sum[f] * (1.f / 96.f);
        const float var = ssq[f] * (1.f / 96.f) - m * m;
        const float r = rsqrtf(var + 1e-5f);
        scale[f] = r * in_w[f];
        shift[f] = in_b[f] - m * scale[f];
    }

    {
        const float c0 = cl[0][tid];
        FSt st{c0, c0, 0.f, 0.f, 0.f, 0.f, 0.f};
        _Float16* orow = feats + (size_t)b * 1152;
        for (int t = 0; t < 96; t++) {
            const float c = cl[t][tid], v = vl[t][tid];
            const float cp = t > 0 ? cl[t - 1][tid] : 0.f;
            const float vp = t > 0 ? vl[t - 1][tid] : 0.f;
            const float co = t >= 20 ? cl[t - 20][tid] : 0.f;
            const float vo = t >= 20 ? vl[t - 20][tid] : 0.f;
            float f6[6];
            fderiv(t, c, cp, co, v, vp, vo, st, f6);
            const float* xq = xb + t * 5;
            float o[11] = {xq[0], xq[1], xq[2], c, v, f6[0], f6[1], f6[2], f6[3], f6[4], f6[5]};
            _Float16* op = orow + (t >> 3) * 96 + (t & 7) * 11;
#pragma unroll
            for (int f = 0; f < 11; f++)
                op[f] = (_Float16)(o[f] * scale[f] + shift[f]);
        }
        const int4 z4 = {0, 0, 0, 0};
#pragma unroll
        for (int p = 0; p < 12; p++)
            *(int4*)(orow + p * 96 + 88) = z4;
    }
}

// ---------------------------------------------------------------------------
// Tiled transpose + cast, z-batched: W (K x N) fp32 -> Wt (N x Kpad) f16.
// ---------------------------------------------------------------------------
__global__ __launch_bounds__(256) void tr_k(
    const float* __restrict__ W, _Float16* __restrict__ Wt,
    int K, int N, int Kpad, long long ss, long long ds)
{
    W  += (size_t)blockIdx.z * ss;
    Wt += (size_t)blockIdx.z * ds;
    __shared__ _Float16 t[32][33];
    const int n0 = blockIdx.x * 32, k0 = blockIdx.y * 32;
#pragma unroll
    for (int j = 0; j < 4; j++) {
        const int k = k0 + threadIdx.y + j * 8;
        t[threadIdx.y + j * 8][threadIdx.x] =
            (k < K) ? (_Float16)W[(size_t)k * N + n0 + threadIdx.x] : (_Float16)0.f;
    }
    __syncthreads();
#pragma unroll
    for (int j = 0; j < 4; j++) {
        const int n = n0 + threadIdx.y + j * 8;
        Wt[(size_t)n * Kpad + k0 + threadIdx.x] = t[threadIdx.x][threadIdx.y + j * 8];
    }
}

// ---------------------------------------------------------------------------
extern "C" void kernel_launch(void* const* d_in, const int* in_sizes, int n_in,
                              void* d_out, int out_size, void* d_ws, size_t ws_size,
                              hipStream_t stream)
{
    static const int EXP[23] = {1966080, 11, 11, 45056, 512, 2048, 2048,
        3145728, 6144, 1048576, 2048, 2048, 2048, 4194304, 8192, 4194304, 2048,
        3145728, 512, 65536, 128, 384, 3};
    static const int S2D[23] = {18, 20, 22, 17, 19, 21, 2, 1, 6, 5, 12, 11,
        14, 16, 13, 15, 10, 9, 4, 3, 8, 7, 0};
    const void* in[23];
    if (n_in != 23 || out_size != 12288) return;
    bool ok = true;
    for (int i = 0; i < 23; i++) ok = ok && (in_sizes[i] == EXP[i]);
    if (ok) {
        for (int i = 0; i < 23; i++) in[i] = d_in[i];
    } else {
        bool ok2 = true;
        for (int s = 0; s < 23; s++) ok2 = ok2 && (in_sizes[s] == EXP[S2D[s]]);
        if (!ok2) return;
        for (int s = 0; s < 23; s++) in[S2D[s]] = d_in[s];
    }
    const float* x      = (const float*)in[0];
    const float* in_w   = (const float*)in[1];
    const float* in_b   = (const float*)in[2];
    const float* pe_w   = (const float*)in[3];
    const float* pe_b   = (const float*)in[4];
    const float* ln1_w  = (const float*)in[5];
    const float* ln1_b  = (const float*)in[6];
    const float* qkv_w  = (const float*)in[7];
    const float* qkv_b  = (const float*)in[8];
    const float* out_w  = (const float*)in[9];
    const float* out_b  = (const float*)in[10];
    const float* ln2_w  = (const float*)in[11];
    const float* ln2_b  = (const float*)in[12];
    const float* mlp_w1 = (const float*)in[13];
    const float* mlp_b1 = (const float*)in[14];
    const float* mlp_w2 = (const float*)in[15];
    const float* mlp_b2 = (const float*)in[16];
    const float* cls_w1 = (const float*)in[17];
    const float* cls_b1 = (const float*)in[18];
    const float* cls_w2 = (const float*)in[19];
    const float* cls_b2 = (const float*)in[20];
    const float* cls_w3 = (const float*)in[21];
    const float* cls_b3 = (const float*)in[22];

    // ---- f16 weight arena (~31.7 MB) ----
    char* ws = (char*)d_ws;
    size_t off = 0;
    _Float16* wt_pe  = (_Float16*)(ws + off); off += (size_t)512 * 96 * 2;
    _Float16* wt_qkv = (_Float16*)(ws + off); off += (size_t)4 * 1536 * 512 * 2;
    _Float16* wt_out = (_Float16*)(ws + off); off += (size_t)4 * 512 * 512 * 2;
    _Float16* wt_m1  = (_Float16*)(ws + off); off += (size_t)4 * 2048 * 512 * 2;
    _Float16* wt_m2  = (_Float16*)(ws + off); off += (size_t)4 * 512 * 2048 * 2;
    _Float16* wt_c1  = (_Float16*)(ws + off); off += (size_t)512 * 6144 * 2;
    _Float16* wt_c2  = (_Float16*)(ws + off); off += (size_t)128 * 512 * 2;
    const size_t wbytes = off;

    // per-batch bytes = h32 24576 + abuf 12288 + bbuf 49152
    const size_t per = 86016 + 64;
    int CH = 2048;
    while (CH > 128 && wbytes + (size_t)CH * per > ws_size) CH >>= 1;
    const int nch = 4096 / CH;
    const int M = CH * 12;

    float*    h32  = (float*)(ws + off);    off += (size_t)M * 512 * 4;
    _Float16* abuf = (_Float16*)(ws + off); off += (size_t)M * 512 * 2;
    _Float16* bbuf = (_Float16*)(ws + off); off += (size_t)M * 2048 * 2;

    _Float16* feats = bbuf;                 // dead after pe GEMM
    _Float16* f1 = (_Float16*)h32;          // classifier temp (h32 dead then)
    float* part1 = (float*)bbuf;                          // 8*CH*512 fp32
    float* part2 = part1 + (size_t)8 * CH * 512;          // 4*CH*128 fp32

    // ---- weight prep: fp32 (K,N) -> f16 (N,Kpad) transposed, z-batched ----
    tr_k<<<dim3(16, 3, 1),   dim3(32, 8), 0, stream>>>(pe_w, wt_pe, 88, 512, 96, 0, 0);
    tr_k<<<dim3(48, 16, 4),  dim3(32, 8), 0, stream>>>(qkv_w, wt_qkv, 512, 1536, 512,
        (long long)512 * 1536, (long long)1536 * 512);
    tr_k<<<dim3(16, 16, 4),  dim3(32, 8), 0, stream>>>(out_w, wt_out, 512, 512, 512,
        (long long)512 * 512, (long long)512 * 512);
    tr_k<<<dim3(64, 16, 4),  dim3(32, 8), 0, stream>>>(mlp_w1, wt_m1, 512, 2048, 512,
        (long long)512 * 2048, (long long)2048 * 512);
    tr_k<<<dim3(16, 64, 4),  dim3(32, 8), 0, stream>>>(mlp_w2, wt_m2, 2048, 512, 2048,
        (long long)2048 * 512, (long long)512 * 2048);
    tr_k<<<dim3(16, 192, 1), dim3(32, 8), 0, stream>>>(cls_w1, wt_c1, 6144, 512, 6144, 0, 0);
    tr_k<<<dim3(4, 16, 1),   dim3(32, 8), 0, stream>>>(cls_w2, wt_c2, 512, 128, 512, 0, 0);

    for (int c = 0; c < nch; c++) {
        const float* xc = x + (size_t)c * CH * 480;
        factors_k<<<CH / 64, 64, 0, stream>>>(xc, in_w, in_b, feats, CH);
        gemm_f16<<<dim3(4, M / 128), 256, 0, stream>>>(
            feats, wt_pe, pe_b, nullptr, h32, nullptr, M, 512, 96, 96, FLAG_W32);

        for (int i = 0; i < 4; i++) {
            ln_rows<<<M / 4, 256, 0, stream>>>(h32, ln1_w + i * 512, ln1_b + i * 512, abuf);
            gemm_f16w<<<dim3(6, M / 128), 256, 0, stream>>>(
                abuf, wt_qkv + (size_t)i * 1536 * 512, qkv_b + i * 1536,
                nullptr, nullptr, bbuf, M, 1536, 512, FLAG_W16);
            attn_k<<<CH * 2, 256, 0, stream>>>(bbuf, abuf);
            gemm_f16<<<dim3(4, M / 128), 256, 0, stream>>>(
                abuf, wt_out + (size_t)i * 512 * 512, out_b + i * 512,
                h32, h32, nullptr, M, 512, 512, 512, FLAG_RES | FLAG_W32);
            ln_rows<<<M / 4, 256, 0, stream>>>(h32, ln2_w + i * 512, ln2_b + i * 512, abuf);
            gemm_f16w<<<dim3(8, M / 128), 256, 0, stream>>>(
                abuf, wt_m1 + (size_t)i * 2048 * 512, mlp_b1 + i * 2048,
                nullptr, nullptr, bbuf, M, 2048, 512, FLAG_W16 | FLAG_GELU);
            // at i==3 the fp32 residual stream is dead afterwards
            const int fl = FLAG_RES | (i == 3 ? FLAG_W16 : FLAG_W32);
            gemm_f16w<<<dim3(2, M / 128), 256, 0, stream>>>(
                bbuf, wt_m2 + (size_t)i * 512 * 2048, mlp_b2 + i * 512,
                h32, h32, abuf, M, 512, 2048, fl);
        }

        // classifier: abuf viewed as (CH, 6144) f16; split-K via fp32 partials
        gemm_f16<<<dim3(4, CH / 128, 8), 256, 0, stream>>>(
            abuf, wt_c1, nullptr, nullptr, part1, nullptr, CH, 512, 6144, 768, FLAG_PART);
        skred_k<<<(CH * 512 + 255) / 256, 256, 0, stream>>>(
            part1, cls_b1, f1, CH * 512, 512, 8);
        gemm_f16<<<dim3(1, CH / 128, 4), 256, 0, stream>>>(
            f1, wt_c2, nullptr, nullptr, part2, nullptr, CH, 128, 512, 128, FLAG_PART);
        skcls_k<<<CH / 4, 256, 0, stream>>>(
            part2, cls_b2, cls_w3, cls_b3, (float*)d_out + (size_t)c * CH * 3, CH);
    }
}

// Round 5
// 3312.821 us; speedup vs baseline: 1.1899x; 1.1899x over previous
//
#include <hip/hip_runtime.h>
#include <cstdint>
#include <cstddef>

typedef _Float16 half8 __attribute__((ext_vector_type(8)));
typedef float floatx4 __attribute__((ext_vector_type(4)));

#define FLAG_RES  1
#define FLAG_GELU 2
#define FLAG_W32  4
#define FLAG_W16  8
#define FLAG_PART 16

// Fast exact-GELU: erf via Abramowitz-Stegun 7.1.26 (|err| <= 1.5e-7), __expf.
__device__ __forceinline__ float gelu_exact(float x) {
    const float z = fabsf(x) * 0.70710678118654752f;
    const float t = 1.f / fmaf(0.3275911f, z, 1.f);
    const float p = t * (0.254829592f + t * (-0.284496736f +
                     t * (1.421413741f + t * (-1.453152027f + t * 1.061405429f))));
    const float erfa = 1.f - p * __expf(-z * z);
    return 0.5f * x * (1.f + copysignf(erfa, x));
}

// async global->LDS (16B/lane): dest is wave-uniform base + lane*16.
// Verified in this session (round 1: compiled, ran, passed correctness).
typedef const __attribute__((address_space(1))) void GV;
typedef __attribute__((address_space(3))) void LV;
__device__ __forceinline__ void gl_lds16(const void* g, void* l) {
    __builtin_amdgcn_global_load_lds((GV*)g, (LV*)l, 16, 0, 0);
}

// ---------------------------------------------------------------------------
// GEMM: C(MxN) = A(MxK f16 rm) @ Bt(NxK f16 rm)^T + bias(fp32)
// 128x128 tile, BK=32, 256 thr (2x2 waves of 64x64). Staging via
// global_load_lds dwordx4 (no reg round-trip, no staging VALU): LDS dest is
// linear, so the XOR swizzle is applied by PRE-SWIZZLING the per-lane global
// SOURCE chunk (cs = ch ^ ((row>>1)&3)); fragment ds_read uses the same XOR
// (verified r2-r3: SQ_LDS_BANK_CONFLICT 6.3M -> 0). LDS ping-pong, ONE
// barrier per iteration: next-tile gloads issue right after this tile's
// barrier and are drained by the compiler's vmcnt(0) at the NEXT barrier,
// overlapping the whole ds_read+MFMA phase.
// blockIdx.z = split-K slice of length klen (klen%32==0). FLAG_PART writes
// raw fp32 partials to out32 + z*M*N (no bias/act/res).
// ---------------------------------------------------------------------------
__global__ __launch_bounds__(256, 3) void gemm_f16(
    const _Float16* __restrict__ A, const _Float16* __restrict__ Bt,
    const float* __restrict__ bias, const float* __restrict__ resid,
    float* __restrict__ out32, _Float16* __restrict__ out16,
    int M, int N, int K, int klen, int flags)
{
    __shared__ __align__(16) _Float16 As[2][128 * 32];
    __shared__ __align__(16) _Float16 Bs[2][128 * 32];
    const int tid = threadIdx.x;
    const int wid = tid >> 6;
    const int lane = tid & 63;
    const int bm = blockIdx.y * 128;
    const int bn = blockIdx.x * 128;
    const int wr = wid >> 1, wc = wid & 1;
    const int lane15 = lane & 15, quad = lane >> 4;
    const int kb = blockIdx.z * klen;

    floatx4 acc[4][4];
#pragma unroll
    for (int i = 0; i < 4; i++)
#pragma unroll
        for (int j = 0; j < 4; j++)
            acc[i][j] = floatx4{0.f, 0.f, 0.f, 0.f};

    // staging map: lane -> row rr within 16-row group, 16B chunk ch.
    // source chunk pre-swizzled so linear LDS dest ends up XOR-swizzled.
    const int rr = lane >> 2;
    const int ch = lane & 3;
    const int cs = ch ^ ((rr >> 1) & 3);     // (row>>1)&3 == (rr>>1)&3 here
    const _Float16* asrc0 = A + ((size_t)bm + wid * 32 + rr) * K + kb + cs * 8;
    const _Float16* asrc1 = asrc0 + (size_t)16 * K;
    const _Float16* bsrc0 = Bt + ((size_t)bn + wid * 32 + rr) * K + kb + cs * 8;
    const _Float16* bsrc1 = bsrc0 + (size_t)16 * K;

    // fragment read offsets (halfs), swizzle-matched, loop-invariant
    int aoff[4], boff[4];
#pragma unroll
    for (int mi = 0; mi < 4; mi++)
        aoff[mi] = (wr * 64 + mi * 16 + lane15) * 32 +
                   ((quad ^ ((lane15 >> 1) & 3)) << 3);
#pragma unroll
    for (int ni = 0; ni < 4; ni++)
        boff[ni] = (wc * 64 + ni * 16 + lane15) * 32 +
                   ((quad ^ ((lane15 >> 1) & 3)) << 3);

    const int nk = klen >> 5;
    {   // prologue: stage tile 0 -> buffer 0 (wave-uniform LDS bases)
        _Float16* ab = &As[0][wid * 1024];
        _Float16* bb = &Bs[0][wid * 1024];
        gl_lds16(asrc0, ab);
        gl_lds16(asrc1, ab + 512);
        gl_lds16(bsrc0, bb);
        gl_lds16(bsrc1, bb + 512);
    }
    for (int ik = 0; ik < nk; ik++) {
        __syncthreads();   // compiler drains vmcnt -> tile ik resident; prior
                           // reads of the other buffer are long complete.
        if (ik + 1 < nk) { // stage tile ik+1 into the other buffer NOW; the
            const int ko = (ik + 1) << 5;     // loads fly during ds_read+MFMA
            _Float16* ab = &As[(ik + 1) & 1][wid * 1024];
            _Float16* bb = &Bs[(ik + 1) & 1][wid * 1024];
            gl_lds16(asrc0 + ko, ab);
            gl_lds16(asrc1 + ko, ab + 512);
            gl_lds16(bsrc0 + ko, bb);
            gl_lds16(bsrc1 + ko, bb + 512);
        }
        const _Float16* a_ = As[ik & 1];
        const _Float16* b_ = Bs[ik & 1];
        half8 af[4], bf[4];
#pragma unroll
        for (int mi = 0; mi < 4; mi++) af[mi] = *(const half8*)&a_[aoff[mi]];
#pragma unroll
        for (int ni = 0; ni < 4; ni++) bf[ni] = *(const half8*)&b_[boff[ni]];
#pragma unroll
        for (int mi = 0; mi < 4; mi++)
#pragma unroll
            for (int ni = 0; ni < 4; ni++)
                acc[mi][ni] = __builtin_amdgcn_mfma_f32_16x16x32_f16(
                    af[mi], bf[ni], acc[mi][ni], 0, 0, 0);
    }

    // epilogue: C/D layout col = lane&15, row = quad*4 + reg
    if (flags & FLAG_PART) {
        float* po = out32 + (size_t)blockIdx.z * ((size_t)M * N);
#pragma unroll
        for (int mi = 0; mi < 4; mi++) {
            const int gmb = bm + wr * 64 + mi * 16 + quad * 4;
#pragma unroll
            for (int ni = 0; ni < 4; ni++) {
                const int gn = bn + wc * 64 + ni * 16 + lane15;
#pragma unroll
                for (int r = 0; r < 4; r++)
                    po[(size_t)(gmb + r) * N + gn] = acc[mi][ni][r];
            }
        }
        return;
    }
#pragma unroll
    for (int mi = 0; mi < 4; mi++) {
        const int gmb = bm + wr * 64 + mi * 16 + quad * 4;
#pragma unroll
        for (int ni = 0; ni < 4; ni++) {
            const int gn = bn + wc * 64 + ni * 16 + lane15;
            const float bv = bias[gn];
#pragma unroll
            for (int r = 0; r < 4; r++) {
                float v = acc[mi][ni][r] + bv;
                if (flags & FLAG_GELU) v = gelu_exact(v);
                const size_t off = (size_t)(gmb + r) * N + gn;
                if (flags & FLAG_RES) v += resid[off];
                if (flags & FLAG_W32) out32[off] = v;
                if (flags & FLAG_W16) out16[off] = (_Float16)v;
            }
        }
    }
}

// ---------------------------------------------------------------------------
// Split-K reduce: out[i] = gelu(bias[i%N] + sum_z part[z*MN + i]) as f16.
// ---------------------------------------------------------------------------
__global__ __launch_bounds__(256) void skred_k(
    const float* __restrict__ part, const float* __restrict__ bias,
    _Float16* __restrict__ out, int MN, int N, int S)
{
    const int i = blockIdx.x * 256 + threadIdx.x;
    if (i >= MN) return;
    float s = bias[i % N];
    for (int z = 0; z < S; z++) s += part[(size_t)z * MN + i];
    out[i] = (_Float16)gelu_exact(s);
}

// ---------------------------------------------------------------------------
// Fused split-K reduce (S=4, N=128) + gelu + final (128x3) matmul + bias.
// ---------------------------------------------------------------------------
__global__ __launch_bounds__(256) void skcls_k(
    const float* __restrict__ part, const float* __restrict__ b2,
    const float* __restrict__ w3, const float* __restrict__ b3,
    float* __restrict__ out, int CH)
{
    const int wid = threadIdx.x >> 6, lane = threadIdx.x & 63;
    const int b = blockIdx.x * 4 + wid;
    const size_t MN = (size_t)CH * 128;
    const int c0 = lane, c1 = lane + 64;
    float s0 = b2[c0], s1 = b2[c1];
#pragma unroll
    for (int z = 0; z < 4; z++) {
        s0 += part[z * MN + (size_t)b * 128 + c0];
        s1 += part[z * MN + (size_t)b * 128 + c1];
    }
    const float g0 = gelu_exact(s0), g1 = gelu_exact(s1);
    float a0 = g0 * w3[c0 * 3 + 0] + g1 * w3[c1 * 3 + 0];
    float a1 = g0 * w3[c0 * 3 + 1] + g1 * w3[c1 * 3 + 1];
    float a2 = g0 * w3[c0 * 3 + 2] + g1 * w3[c1 * 3 + 2];
#pragma unroll
    for (int m = 32; m >= 1; m >>= 1) {
        a0 += __shfl_xor(a0, m, 64);
        a1 += __shfl_xor(a1, m, 64);
        a2 += __shfl_xor(a2, m, 64);
    }
    if (lane == 0) {
        out[b * 3 + 0] = a0 + b3[0];
        out[b * 3 + 1] = a1 + b3[1];
        out[b * 3 + 2] = a2 + b3[2];
    }
}

// ---------------------------------------------------------------------------
// Row LayerNorm over 512 cols: fp32 in, fp32 params, f16 out. One wave/row.
// ---------------------------------------------------------------------------
__global__ __launch_bounds__(256) void ln_rows(
    const float* __restrict__ x, const float* __restrict__ w,
    const float* __restrict__ b, _Float16* __restrict__ out)
{
    const int wid = threadIdx.x >> 6, lane = threadIdx.x & 63;
    const size_t row = (size_t)blockIdx.x * 4 + wid;
    const int c0 = lane * 8;
    const float* xr = x + row * 512 + c0;
    float4 v0 = *(const float4*)xr;
    float4 v1 = *(const float4*)(xr + 4);
    float xv[8] = {v0.x, v0.y, v0.z, v0.w, v1.x, v1.y, v1.z, v1.w};
    float s = 0.f, q = 0.f;
#pragma unroll
    for (int j = 0; j < 8; j++) { s += xv[j]; q += xv[j] * xv[j]; }
#pragma unroll
    for (int m = 32; m >= 1; m >>= 1) {
        s += __shfl_xor(s, m, 64);
        q += __shfl_xor(q, m, 64);
    }
    const float mean = s * (1.f / 512.f);
    const float rstd = rsqrtf(q * (1.f / 512.f) - mean * mean + 1e-5f);
    half8 o;
#pragma unroll
    for (int j = 0; j < 8; j++)
        o[j] = (_Float16)((xv[j] - mean) * rstd * w[c0 + j] + b[c0 + j]);
    *(half8*)&out[row * 512 + c0] = o;
}

// ---------------------------------------------------------------------------
// Attention: 4 (b,head) units per 256-thread block (one wave each).
// ---------------------------------------------------------------------------
__global__ __launch_bounds__(256) void attn_k(
    const _Float16* __restrict__ qkv, _Float16* __restrict__ o)
{
    __shared__ float qs[4][12][65], ks[4][12][65], vs[4][12][65];
    __shared__ float att[4][12][16];
    const int wid = threadIdx.x >> 6, lane = threadIdx.x & 63;
    const int unit = blockIdx.x * 4 + wid;
    const int b = unit >> 3, hd = unit & 7;
    const _Float16* base = qkv + (size_t)b * (12 * 1536) + hd * 64 + lane;
#pragma unroll
    for (int r = 0; r < 12; r++) {
        qs[wid][r][lane] = (float)base[r * 1536];
        ks[wid][r][lane] = (float)base[r * 1536 + 512];
        vs[wid][r][lane] = (float)base[r * 1536 + 1024];
    }
    __syncthreads();
#pragma unroll
    for (int i = 0; i < 3; i++) {
        const int p = lane + i * 64;
        if (p < 144) {
            const int qi = p / 12, kj = p - qi * 12;
            float d = 0.f;
            for (int e = 0; e < 64; e++) d += qs[wid][qi][e] * ks[wid][kj][e];
            att[wid][qi][kj] = d * 0.125f;
        }
    }
    __syncthreads();
    if (lane < 12) {
        float mx = att[wid][lane][0];
#pragma unroll
        for (int j = 1; j < 12; j++) mx = fmaxf(mx, att[wid][lane][j]);
        float ev[12], ssum = 0.f;
#pragma unroll
        for (int j = 0; j < 12; j++) { ev[j] = expf(att[wid][lane][j] - mx); ssum += ev[j]; }
        const float inv = 1.f / ssum;
#pragma unroll
        for (int j = 0; j < 12; j++) att[wid][lane][j] = ev[j] * inv;
    }
    __syncthreads();
    _Float16* ob = o + (size_t)b * (12 * 512) + hd * 64 + lane;
#pragma unroll
    for (int qi = 0; qi < 12; qi++) {
        float s = 0.f;
#pragma unroll
        for (int j = 0; j < 12; j++) s += att[wid][qi][j] * vs[wid][j][lane];
        ob[qi * 512] = (_Float16)s;
    }
}

// ---------------------------------------------------------------------------
// Fused factors + per-(batch,feature) time-norm -> (CH*12, 96) f16 patch rows.
// ---------------------------------------------------------------------------
struct FSt { float e12, e26, ag, al, s1c, s2c, s1v; };

__device__ __forceinline__ void fderiv(
    int t, float c, float cprev, float co, float v, float vprev, float vo,
    FSt& s, float f[6])
{
    const float a12 = 2.f / 13.f, a26 = 2.f / 27.f, a14 = 1.f / 14.f;
    const float sv = v > 0.f ? v : 1.f;
    if (t > 0) {
        s.e12 = a12 * c + (1.f - a12) * s.e12;
        s.e26 = a26 * c + (1.f - a26) * s.e26;
    }
    const float macd = s.e12 - s.e26;
    const float delta = t > 0 ? c - cprev : 0.f;
    if (t > 0) {
        s.ag = a14 * fmaxf(delta, 0.f) + (1.f - a14) * s.ag;
        s.al = a14 * fmaxf(-delta, 0.f) + (1.f - a14) * s.al;
    }
    const float rs = s.ag / (s.al + 1e-10f);
    const float rsi = (100.f - 100.f / (1.f + rs)) * 0.01f;
    s.s1c += c; s.s2c += c * c; s.s1v += sv;
    if (t >= 20) {
        const float svo = vo > 0.f ? vo : 1.f;
        s.s1c -= co; s.s2c -= co * co; s.s1v -= svo;
    }
    float bb = 0.f, vmr = 1.f;
    if (t >= 19) {
        const float mean = s.s1c * 0.05f;
        const float sq = s.s2c * 0.05f;
        const float sd = sqrtf(fmaxf(sq - mean * mean, 0.f));
        bb = 4.f * sd / (mean + 1e-8f);
        vmr = sv / (s.s1v * 0.05f + 1e-8f);
    }
    float lr = 0.f, lv = 0.f;
    if (t > 0) {
        lr = logf(fmaxf(c, 1e-8f) / fmaxf(cprev, 1e-8f));
        const float svp = vprev > 0.f ? vprev : 1.f;
        lv = logf(sv / (svp + 1e-8f));
    }
    f[0] = isfinite(macd) ? macd : 0.f;
    f[1] = isfinite(rsi) ? rsi : 0.f;
    f[2] = isfinite(bb) ? bb : 0.f;
    f[3] = isfinite(lr) ? lr : 0.f;
    f[4] = isfinite(lv) ? lv : 0.f;
    f[5] = isfinite(vmr) ? vmr : 0.f;
}

__global__ __launch_bounds__(64) void factors_k(
    const float* __restrict__ x, const float* __restrict__ in_w,
    const float* __restrict__ in_b, _Float16* __restrict__ feats, int CH)
{
    const int tid = threadIdx.x;
    const int b = blockIdx.x * 64 + tid;
    if (b >= CH) return;
    __shared__ float cl[96][64];
    __shared__ float vl[96][64];
    const float* xb = x + (size_t)b * 480;

    float sum[11], ssq[11];
#pragma unroll
    for (int f = 0; f < 11; f++) { sum[f] = 0.f; ssq[f] = 0.f; }

    for (int t = 0; t < 96; t++) {
        const float* xq = xb + t * 5;
        const float a0 = xq[0], a1 = xq[1], a2 = xq[2], c = xq[3], v = xq[4];
        cl[t][tid] = c; vl[t][tid] = v;
        sum[0] += a0; ssq[0] += a0 * a0;
        sum[1] += a1; ssq[1] += a1 * a1;
        sum[2] += a2; ssq[2] += a2 * a2;
        sum[3] += c;  ssq[3] += c * c;
        sum[4] += v;  ssq[4] += v * v;
    }

    {
        const float c0 = cl[0][tid];
        FSt st{c0, c0, 0.f, 0.f, 0.f, 0.f, 0.f};
        for (int t = 0; t < 96; t++) {
            const float c = cl[t][tid], v = vl[t][tid];
            const float cp = t > 0 ? cl[t - 1][tid] : 0.f;
            const float vp = t > 0 ? vl[t - 1][tid] : 0.f;
            const float co = t >= 20 ? cl[t - 20][tid] : 0.f;
            const float vo = t >= 20 ? vl[t - 20][tid] : 0.f;
            float f6[6];
            fderiv(t, c, cp, co, v, vp, vo, st, f6);
#pragma unroll
            for (int j = 0; j < 6; j++) { sum[5 + j] += f6[j]; ssq[5 + j] += f6[j] * f6[j]; }
        }
    }
    float scale[11], shift[11];
#pragma unroll
    for (int f = 0; f < 11; f++) {
        const float m = sum[f] * (1.f / 96.f);
        const float var = ssq[f] * (1.f / 96.f) - m * m;
        const float r = rsqrtf(var + 1e-5f);
        scale[f] = r * in_w[f];
        shift[f] = in_b[f] - m * scale[f];
    }

    {
        const float c0 = cl[0][tid];
        FSt st{c0, c0, 0.f, 0.f, 0.f, 0.f, 0.f};
        _Float16* orow = feats + (size_t)b * 1152;
        for (int t = 0; t < 96; t++) {
            const float c = cl[t][tid], v = vl[t][tid];
            const float cp = t > 0 ? cl[t - 1][tid] : 0.f;
            const float vp = t > 0 ? vl[t - 1][tid] : 0.f;
            const float co = t >= 20 ? cl[t - 20][tid] : 0.f;
            const float vo = t >= 20 ? vl[t - 20][tid] : 0.f;
            float f6[6];
            fderiv(t, c, cp, co, v, vp, vo, st, f6);
            const float* xq = xb + t * 5;
            float o[11] = {xq[0], xq[1], xq[2], c, v, f6[0], f6[1], f6[2], f6[3], f6[4], f6[5]};
            _Float16* op = orow + (t >> 3) * 96 + (t & 7) * 11;
#pragma unroll
            for (int f = 0; f < 11; f++)
                op[f] = (_Float16)(o[f] * scale[f] + shift[f]);
        }
        const int4 z4 = {0, 0, 0, 0};
#pragma unroll
        for (int p = 0; p < 12; p++)
            *(int4*)(orow + p * 96 + 88) = z4;
    }
}

// ---------------------------------------------------------------------------
// Tiled transpose + cast, z-batched: W (K x N) fp32 -> Wt (N x Kpad) f16.
// ---------------------------------------------------------------------------
__global__ __launch_bounds__(256) void tr_k(
    const float* __restrict__ W, _Float16* __restrict__ Wt,
    int K, int N, int Kpad, long long ss, long long ds)
{
    W  += (size_t)blockIdx.z * ss;
    Wt += (size_t)blockIdx.z * ds;
    __shared__ _Float16 t[32][33];
    const int n0 = blockIdx.x * 32, k0 = blockIdx.y * 32;
#pragma unroll
    for (int j = 0; j < 4; j++) {
        const int k = k0 + threadIdx.y + j * 8;
        t[threadIdx.y + j * 8][threadIdx.x] =
            (k < K) ? (_Float16)W[(size_t)k * N + n0 + threadIdx.x] : (_Float16)0.f;
    }
    __syncthreads();
#pragma unroll
    for (int j = 0; j < 4; j++) {
        const int n = n0 + threadIdx.y + j * 8;
        Wt[(size_t)n * Kpad + k0 + threadIdx.x] = t[threadIdx.x][threadIdx.y + j * 8];
    }
}

// ---------------------------------------------------------------------------
extern "C" void kernel_launch(void* const* d_in, const int* in_sizes, int n_in,
                              void* d_out, int out_size, void* d_ws, size_t ws_size,
                              hipStream_t stream)
{
    static const int EXP[23] = {1966080, 11, 11, 45056, 512, 2048, 2048,
        3145728, 6144, 1048576, 2048, 2048, 2048, 4194304, 8192, 4194304, 2048,
        3145728, 512, 65536, 128, 384, 3};
    static const int S2D[23] = {18, 20, 22, 17, 19, 21, 2, 1, 6, 5, 12, 11,
        14, 16, 13, 15, 10, 9, 4, 3, 8, 7, 0};
    const void* in[23];
    if (n_in != 23 || out_size != 12288) return;
    bool ok = true;
    for (int i = 0; i < 23; i++) ok = ok && (in_sizes[i] == EXP[i]);
    if (ok) {
        for (int i = 0; i < 23; i++) in[i] = d_in[i];
    } else {
        bool ok2 = true;
        for (int s = 0; s < 23; s++) ok2 = ok2 && (in_sizes[s] == EXP[S2D[s]]);
        if (!ok2) return;
        for (int s = 0; s < 23; s++) in[S2D[s]] = d_in[s];
    }
    const float* x      = (const float*)in[0];
    const float* in_w   = (const float*)in[1];
    const float* in_b   = (const float*)in[2];
    const float* pe_w   = (const float*)in[3];
    const float* pe_b   = (const float*)in[4];
    const float* ln1_w  = (const float*)in[5];
    const float* ln1_b  = (const float*)in[6];
    const float* qkv_w  = (const float*)in[7];
    const float* qkv_b  = (const float*)in[8];
    const float* out_w  = (const float*)in[9];
    const float* out_b  = (const float*)in[10];
    const float* ln2_w  = (const float*)in[11];
    const float* ln2_b  = (const float*)in[12];
    const float* mlp_w1 = (const float*)in[13];
    const float* mlp_b1 = (const float*)in[14];
    const float* mlp_w2 = (const float*)in[15];
    const float* mlp_b2 = (const float*)in[16];
    const float* cls_w1 = (const float*)in[17];
    const float* cls_b1 = (const float*)in[18];
    const float* cls_w2 = (const float*)in[19];
    const float* cls_b2 = (const float*)in[20];
    const float* cls_w3 = (const float*)in[21];
    const float* cls_b3 = (const float*)in[22];

    // ---- f16 weight arena (~31.7 MB) ----
    char* ws = (char*)d_ws;
    size_t off = 0;
    _Float16* wt_pe  = (_Float16*)(ws + off); off += (size_t)512 * 96 * 2;
    _Float16* wt_qkv = (_Float16*)(ws + off); off += (size_t)4 * 1536 * 512 * 2;
    _Float16* wt_out = (_Float16*)(ws + off); off += (size_t)4 * 512 * 512 * 2;
    _Float16* wt_m1  = (_Float16*)(ws + off); off += (size_t)4 * 2048 * 512 * 2;
    _Float16* wt_m2  = (_Float16*)(ws + off); off += (size_t)4 * 512 * 2048 * 2;
    _Float16* wt_c1  = (_Float16*)(ws + off); off += (size_t)512 * 6144 * 2;
    _Float16* wt_c2  = (_Float16*)(ws + off); off += (size_t)128 * 512 * 2;
    const size_t wbytes = off;

    // per-batch bytes = h32 24576 + abuf 12288 + bbuf 49152
    const size_t per = 86016 + 64;
    int CH = 2048;
    while (CH > 128 && wbytes + (size_t)CH * per > ws_size) CH >>= 1;
    const int nch = 4096 / CH;
    const int M = CH * 12;

    float*    h32  = (float*)(ws + off);    off += (size_t)M * 512 * 4;
    _Float16* abuf = (_Float16*)(ws + off); off += (size_t)M * 512 * 2;
    _Float16* bbuf = (_Float16*)(ws + off); off += (size_t)M * 2048 * 2;

    _Float16* feats = bbuf;                 // dead after pe GEMM
    _Float16* f1 = (_Float16*)h32;          // classifier temp (h32 dead then)
    float* part1 = (float*)bbuf;                          // 8*CH*512 fp32
    float* part2 = part1 + (size_t)8 * CH * 512;          // 4*CH*128 fp32

    // ---- weight prep: fp32 (K,N) -> f16 (N,Kpad) transposed, z-batched ----
    tr_k<<<dim3(16, 3, 1),   dim3(32, 8), 0, stream>>>(pe_w, wt_pe, 88, 512, 96, 0, 0);
    tr_k<<<dim3(48, 16, 4),  dim3(32, 8), 0, stream>>>(qkv_w, wt_qkv, 512, 1536, 512,
        (long long)512 * 1536, (long long)1536 * 512);
    tr_k<<<dim3(16, 16, 4),  dim3(32, 8), 0, stream>>>(out_w, wt_out, 512, 512, 512,
        (long long)512 * 512, (long long)512 * 512);
    tr_k<<<dim3(64, 16, 4),  dim3(32, 8), 0, stream>>>(mlp_w1, wt_m1, 512, 2048, 512,
        (long long)512 * 2048, (long long)2048 * 512);
    tr_k<<<dim3(16, 64, 4),  dim3(32, 8), 0, stream>>>(mlp_w2, wt_m2, 2048, 512, 2048,
        (long long)2048 * 512, (long long)512 * 2048);
    tr_k<<<dim3(16, 192, 1), dim3(32, 8), 0, stream>>>(cls_w1, wt_c1, 6144, 512, 6144, 0, 0);
    tr_k<<<dim3(4, 16, 1),   dim3(32, 8), 0, stream>>>(cls_w2, wt_c2, 512, 128, 512, 0, 0);

    for (int c = 0; c < nch; c++) {
        const float* xc = x + (size_t)c * CH * 480;
        factors_k<<<CH / 64, 64, 0, stream>>>(xc, in_w, in_b, feats, CH);
        gemm_f16<<<dim3(4, M / 128), 256, 0, stream>>>(
            feats, wt_pe, pe_b, nullptr, h32, nullptr, M, 512, 96, 96, FLAG_W32);

        for (int i = 0; i < 4; i++) {
            ln_rows<<<M / 4, 256, 0, stream>>>(h32, ln1_w + i * 512, ln1_b + i * 512, abuf);
            gemm_f16<<<dim3(12, M / 128), 256, 0, stream>>>(
                abuf, wt_qkv + (size_t)i * 1536 * 512, qkv_b + i * 1536,
                nullptr, nullptr, bbuf, M, 1536, 512, 512, FLAG_W16);
            attn_k<<<CH * 2, 256, 0, stream>>>(bbuf, abuf);
            gemm_f16<<<dim3(4, M / 128), 256, 0, stream>>>(
                abuf, wt_out + (size_t)i * 512 * 512, out_b + i * 512,
                h32, h32, nullptr, M, 512, 512, 512, FLAG_RES | FLAG_W32);
            ln_rows<<<M / 4, 256, 0, stream>>>(h32, ln2_w + i * 512, ln2_b + i * 512, abuf);
            gemm_f16<<<dim3(16, M / 128), 256, 0, stream>>>(
                abuf, wt_m1 + (size_t)i * 2048 * 512, mlp_b1 + i * 2048,
                nullptr, nullptr, bbuf, M, 2048, 512, 512, FLAG_W16 | FLAG_GELU);
            // at i==3 the fp32 residual stream is dead afterwards
            const int fl = FLAG_RES | (i == 3 ? FLAG_W16 : FLAG_W32);
            gemm_f16<<<dim3(4, M / 128), 256, 0, stream>>>(
                bbuf, wt_m2 + (size_t)i * 512 * 2048, mlp_b2 + i * 512,
                h32, h32, abuf, M, 512, 2048, 2048, fl);
        }

        // classifier: abuf viewed as (CH, 6144) f16; split-K via fp32 partials
        gemm_f16<<<dim3(4, CH / 128, 8), 256, 0, stream>>>(
            abuf, wt_c1, nullptr, nullptr, part1, nullptr, CH, 512, 6144, 768, FLAG_PART);
        skred_k<<<(CH * 512 + 255) / 256, 256, 0, stream>>>(
            part1, cls_b1, f1, CH * 512, 512, 8);
        gemm_f16<<<dim3(1, CH / 128, 4), 256, 0, stream>>>(
            f1, wt_c2, nullptr, nullptr, part2, nullptr, CH, 128, 512, 128, FLAG_PART);
        skcls_k<<<CH / 4, 256, 0, stream>>>(
            part2, cls_b2, cls_w3, cls_b3, (float*)d_out + (size_t)c * CH * 3, CH);
    }
}

// Round 6
// 3098.443 us; speedup vs baseline: 1.2722x; 1.0692x over previous
//
#include <hip/hip_runtime.h>
#include <cstdint>
#include <cstddef>

typedef _Float16 half8 __attribute__((ext_vector_type(8)));
typedef float floatx4 __attribute__((ext_vector_type(4)));

#define FLAG_RES  1
#define FLAG_GELU 2
#define FLAG_W32  4
#define FLAG_W16  8
#define FLAG_PART 16

// Fast exact-GELU: erf via Abramowitz-Stegun 7.1.26 (|err| <= 1.5e-7), __expf.
__device__ __forceinline__ float gelu_exact(float x) {
    const float z = fabsf(x) * 0.70710678118654752f;
    const float t = 1.f / fmaf(0.3275911f, z, 1.f);
    const float p = t * (0.254829592f + t * (-0.284496736f +
                     t * (1.421413741f + t * (-1.453152027f + t * 1.061405429f))));
    const float erfa = 1.f - p * __expf(-z * z);
    return 0.5f * x * (1.f + copysignf(erfa, x));
}

// async global->LDS (16B/lane): dest is wave-uniform base + lane*16.
typedef const __attribute__((address_space(1))) void GV;
typedef __attribute__((address_space(3))) void LV;
__device__ __forceinline__ void gl_lds16(const void* g, void* l) {
    __builtin_amdgcn_global_load_lds((GV*)g, (LV*)l, 16, 0, 0);
}

// XCD-aware chunked block swizzle (bijective when nwg % 8 == 0; identity
// otherwise). Default dispatch round-robins consecutive ids across the 8
// XCDs, so N-strips sharing one A-strip land on different private L2s and
// each re-fetches A. Remap gives each XCD contiguous id runs -> same-A
// blocks share one L2.
__device__ __forceinline__ void swz_bid(int& bx, int& by) {
    const int gx = gridDim.x;
    const int nwg = gx * gridDim.y;
    int id = blockIdx.y * gx + blockIdx.x;
    if ((nwg & 7) == 0) {
        const int q = nwg >> 3;
        id = (id & 7) * q + (id >> 3);
    }
    bx = id % gx;
    by = id / gx;
}

// ---------------------------------------------------------------------------
// GEMM (reg-staged): C(MxN) = A(MxK f16 rm) @ Bt(NxK f16 rm)^T + bias(fp32)
// 128x128 tile, BK=32, 256 thr (2x2 waves of 64x64). Register prefetch +
// LDS ping-pong, ONE barrier per iteration. XOR-swizzled LDS (verified r2:
// SQ_LDS_BANK_CONFLICT 6.3M -> 0). Measured best for mlp1 (short K, big
// grid): 100 us vs 128 us gload_lds (r3 vs r5).
// ---------------------------------------------------------------------------
__global__ __launch_bounds__(256, 2) void gemm_f16(
    const _Float16* __restrict__ A, const _Float16* __restrict__ Bt,
    const float* __restrict__ bias, const float* __restrict__ resid,
    float* __restrict__ out32, _Float16* __restrict__ out16,
    int M, int N, int K, int klen, int flags)
{
    __shared__ __align__(16) _Float16 As[2][128 * 32];
    __shared__ __align__(16) _Float16 Bs[2][128 * 32];
    const int tid = threadIdx.x;
    const int wid = tid >> 6;
    const int lane = tid & 63;
    int bxs, bys;
    swz_bid(bxs, bys);
    const int bm = bys * 128;
    const int bn = bxs * 128;
    const int wr = wid >> 1, wc = wid & 1;
    const int lane15 = lane & 15, quad = lane >> 4;
    const int kb = blockIdx.z * klen;

    floatx4 acc[4][4];
#pragma unroll
    for (int i = 0; i < 4; i++)
#pragma unroll
        for (int j = 0; j < 4; j++)
            acc[i][j] = floatx4{0.f, 0.f, 0.f, 0.f};

    const int r4 = lane >> 2;            // row within 16-row group
    const int ch = lane & 3;             // 16B chunk index
    const _Float16* Ap = A + ((size_t)bm + wid * 32 + r4) * K + kb + ch * 8;
    const _Float16* Bp = Bt + ((size_t)bn + wid * 32 + r4) * K + kb + ch * 8;
    const size_t row16 = (size_t)16 * K;
    const int lw = wid * 1024 + r4 * 32 + ((ch ^ ((r4 >> 1) & 3)) << 3);

    int aoff[4], boff[4];
#pragma unroll
    for (int mi = 0; mi < 4; mi++)
        aoff[mi] = (wr * 64 + mi * 16 + lane15) * 32 +
                   ((quad ^ ((lane15 >> 1) & 3)) << 3);
#pragma unroll
    for (int ni = 0; ni < 4; ni++)
        boff[ni] = (wc * 64 + ni * 16 + lane15) * 32 +
                   ((quad ^ ((lane15 >> 1) & 3)) << 3);

    int4 ra0 = *(const int4*)(Ap);
    int4 ra1 = *(const int4*)(Ap + row16);
    int4 rb0 = *(const int4*)(Bp);
    int4 rb1 = *(const int4*)(Bp + row16);

    const int nk = klen >> 5;
    for (int ik = 0; ik < nk; ik++) {
        _Float16* a_ = &As[ik & 1][0];
        _Float16* b_ = &Bs[ik & 1][0];
        *(int4*)(a_ + lw) = ra0;
        *(int4*)(a_ + lw + 512) = ra1;
        *(int4*)(b_ + lw) = rb0;
        *(int4*)(b_ + lw + 512) = rb1;
        __syncthreads();
        if (ik + 1 < nk) {
            const int ko = (ik + 1) << 5;
            ra0 = *(const int4*)(Ap + ko);
            ra1 = *(const int4*)(Ap + row16 + ko);
            rb0 = *(const int4*)(Bp + ko);
            rb1 = *(const int4*)(Bp + row16 + ko);
        }
        half8 af[4], bf[4];
#pragma unroll
        for (int mi = 0; mi < 4; mi++) af[mi] = *(const half8*)&a_[aoff[mi]];
#pragma unroll
        for (int ni = 0; ni < 4; ni++) bf[ni] = *(const half8*)&b_[boff[ni]];
#pragma unroll
        for (int mi = 0; mi < 4; mi++)
#pragma unroll
            for (int ni = 0; ni < 4; ni++)
                acc[mi][ni] = __builtin_amdgcn_mfma_f32_16x16x32_f16(
                    af[mi], bf[ni], acc[mi][ni], 0, 0, 0);
    }

    if (flags & FLAG_PART) {
        float* po = out32 + (size_t)blockIdx.z * ((size_t)M * N);
#pragma unroll
        for (int mi = 0; mi < 4; mi++) {
            const int gmb = bm + wr * 64 + mi * 16 + quad * 4;
#pragma unroll
            for (int ni = 0; ni < 4; ni++) {
                const int gn = bn + wc * 64 + ni * 16 + lane15;
#pragma unroll
                for (int r = 0; r < 4; r++)
                    po[(size_t)(gmb + r) * N + gn] = acc[mi][ni][r];
            }
        }
        return;
    }
#pragma unroll
    for (int mi = 0; mi < 4; mi++) {
        const int gmb = bm + wr * 64 + mi * 16 + quad * 4;
#pragma unroll
        for (int ni = 0; ni < 4; ni++) {
            const int gn = bn + wc * 64 + ni * 16 + lane15;
            const float bv = bias[gn];
#pragma unroll
            for (int r = 0; r < 4; r++) {
                float v = acc[mi][ni][r] + bv;
                if (flags & FLAG_GELU) v = gelu_exact(v);
                const size_t off = (size_t)(gmb + r) * N + gn;
                if (flags & FLAG_RES) v += resid[off];
                if (flags & FLAG_W32) out32[off] = v;
                if (flags & FLAG_W16) out16[off] = (_Float16)v;
            }
        }
    }
}

// ---------------------------------------------------------------------------
// GEMM (gload_lds-staged): same tile/skeleton, staging via global_load_lds
// dwordx4 with pre-swizzled SOURCE chunk (linear LDS dest -> swizzled layout).
// Measured best for the non-mlp1 GEMMs (r5 total beat r3 while mlp1
// regressed): no staging VALU, no reg round-trip.
// ---------------------------------------------------------------------------
__global__ __launch_bounds__(256, 3) void gemm_f16g(
    const _Float16* __restrict__ A, const _Float16* __restrict__ Bt,
    const float* __restrict__ bias, const float* __restrict__ resid,
    float* __restrict__ out32, _Float16* __restrict__ out16,
    int M, int N, int K, int klen, int flags)
{
    __shared__ __align__(16) _Float16 As[2][128 * 32];
    __shared__ __align__(16) _Float16 Bs[2][128 * 32];
    const int tid = threadIdx.x;
    const int wid = tid >> 6;
    const int lane = tid & 63;
    int bxs, bys;
    swz_bid(bxs, bys);
    const int bm = bys * 128;
    const int bn = bxs * 128;
    const int wr = wid >> 1, wc = wid & 1;
    const int lane15 = lane & 15, quad = lane >> 4;
    const int kb = blockIdx.z * klen;

    floatx4 acc[4][4];
#pragma unroll
    for (int i = 0; i < 4; i++)
#pragma unroll
        for (int j = 0; j < 4; j++)
            acc[i][j] = floatx4{0.f, 0.f, 0.f, 0.f};

    const int rr = lane >> 2;
    const int ch = lane & 3;
    const int cs = ch ^ ((rr >> 1) & 3);
    const _Float16* asrc0 = A + ((size_t)bm + wid * 32 + rr) * K + kb + cs * 8;
    const _Float16* asrc1 = asrc0 + (size_t)16 * K;
    const _Float16* bsrc0 = Bt + ((size_t)bn + wid * 32 + rr) * K + kb + cs * 8;
    const _Float16* bsrc1 = bsrc0 + (size_t)16 * K;

    int aoff[4], boff[4];
#pragma unroll
    for (int mi = 0; mi < 4; mi++)
        aoff[mi] = (wr * 64 + mi * 16 + lane15) * 32 +
                   ((quad ^ ((lane15 >> 1) & 3)) << 3);
#pragma unroll
    for (int ni = 0; ni < 4; ni++)
        boff[ni] = (wc * 64 + ni * 16 + lane15) * 32 +
                   ((quad ^ ((lane15 >> 1) & 3)) << 3);

    const int nk = klen >> 5;
    {
        _Float16* ab = &As[0][wid * 1024];
        _Float16* bb = &Bs[0][wid * 1024];
        gl_lds16(asrc0, ab);
        gl_lds16(asrc1, ab + 512);
        gl_lds16(bsrc0, bb);
        gl_lds16(bsrc1, bb + 512);
    }
    for (int ik = 0; ik < nk; ik++) {
        __syncthreads();
        if (ik + 1 < nk) {
            const int ko = (ik + 1) << 5;
            _Float16* ab = &As[(ik + 1) & 1][wid * 1024];
            _Float16* bb = &Bs[(ik + 1) & 1][wid * 1024];
            gl_lds16(asrc0 + ko, ab);
            gl_lds16(asrc1 + ko, ab + 512);
            gl_lds16(bsrc0 + ko, bb);
            gl_lds16(bsrc1 + ko, bb + 512);
        }
        const _Float16* a_ = As[ik & 1];
        const _Float16* b_ = Bs[ik & 1];
        half8 af[4], bf[4];
#pragma unroll
        for (int mi = 0; mi < 4; mi++) af[mi] = *(const half8*)&a_[aoff[mi]];
#pragma unroll
        for (int ni = 0; ni < 4; ni++) bf[ni] = *(const half8*)&b_[boff[ni]];
#pragma unroll
        for (int mi = 0; mi < 4; mi++)
#pragma unroll
            for (int ni = 0; ni < 4; ni++)
                acc[mi][ni] = __builtin_amdgcn_mfma_f32_16x16x32_f16(
                    af[mi], bf[ni], acc[mi][ni], 0, 0, 0);
    }

    if (flags & FLAG_PART) {
        float* po = out32 + (size_t)blockIdx.z * ((size_t)M * N);
#pragma unroll
        for (int mi = 0; mi < 4; mi++) {
            const int gmb = bm + wr * 64 + mi * 16 + quad * 4;
#pragma unroll
            for (int ni = 0; ni < 4; ni++) {
                const int gn = bn + wc * 64 + ni * 16 + lane15;
#pragma unroll
                for (int r = 0; r < 4; r++)
                    po[(size_t)(gmb + r) * N + gn] = acc[mi][ni][r];
            }
        }
        return;
    }
#pragma unroll
    for (int mi = 0; mi < 4; mi++) {
        const int gmb = bm + wr * 64 + mi * 16 + quad * 4;
#pragma unroll
        for (int ni = 0; ni < 4; ni++) {
            const int gn = bn + wc * 64 + ni * 16 + lane15;
            const float bv = bias[gn];
#pragma unroll
            for (int r = 0; r < 4; r++) {
                float v = acc[mi][ni][r] + bv;
                if (flags & FLAG_GELU) v = gelu_exact(v);
                const size_t off = (size_t)(gmb + r) * N + gn;
                if (flags & FLAG_RES) v += resid[off];
                if (flags & FLAG_W32) out32[off] = v;
                if (flags & FLAG_W16) out16[off] = (_Float16)v;
            }
        }
    }
}

// ---------------------------------------------------------------------------
// Split-K reduce: out[i] = gelu(bias[i%N] + sum_z part[z*MN + i]) as f16.
// ---------------------------------------------------------------------------
__global__ __launch_bounds__(256) void skred_k(
    const float* __restrict__ part, const float* __restrict__ bias,
    _Float16* __restrict__ out, int MN, int N, int S)
{
    const int i = blockIdx.x * 256 + threadIdx.x;
    if (i >= MN) return;
    float s = bias[i % N];
    for (int z = 0; z < S; z++) s += part[(size_t)z * MN + i];
    out[i] = (_Float16)gelu_exact(s);
}

// ---------------------------------------------------------------------------
// Fused split-K reduce (S=4, N=128) + gelu + final (128x3) matmul + bias.
// ---------------------------------------------------------------------------
__global__ __launch_bounds__(256) void skcls_k(
    const float* __restrict__ part, const float* __restrict__ b2,
    const float* __restrict__ w3, const float* __restrict__ b3,
    float* __restrict__ out, int CH)
{
    const int wid = threadIdx.x >> 6, lane = threadIdx.x & 63;
    const int b = blockIdx.x * 4 + wid;
    const size_t MN = (size_t)CH * 128;
    const int c0 = lane, c1 = lane + 64;
    float s0 = b2[c0], s1 = b2[c1];
#pragma unroll
    for (int z = 0; z < 4; z++) {
        s0 += part[z * MN + (size_t)b * 128 + c0];
        s1 += part[z * MN + (size_t)b * 128 + c1];
    }
    const float g0 = gelu_exact(s0), g1 = gelu_exact(s1);
    float a0 = g0 * w3[c0 * 3 + 0] + g1 * w3[c1 * 3 + 0];
    float a1 = g0 * w3[c0 * 3 + 1] + g1 * w3[c1 * 3 + 1];
    float a2 = g0 * w3[c0 * 3 + 2] + g1 * w3[c1 * 3 + 2];
#pragma unroll
    for (int m = 32; m >= 1; m >>= 1) {
        a0 += __shfl_xor(a0, m, 64);
        a1 += __shfl_xor(a1, m, 64);
        a2 += __shfl_xor(a2, m, 64);
    }
    if (lane == 0) {
        out[b * 3 + 0] = a0 + b3[0];
        out[b * 3 + 1] = a1 + b3[1];
        out[b * 3 + 2] = a2 + b3[2];
    }
}

// ---------------------------------------------------------------------------
// Row LayerNorm over 512 cols: fp32 in, fp32 params, f16 out. One wave/row.
// ---------------------------------------------------------------------------
__global__ __launch_bounds__(256) void ln_rows(
    const float* __restrict__ x, const float* __restrict__ w,
    const float* __restrict__ b, _Float16* __restrict__ out)
{
    const int wid = threadIdx.x >> 6, lane = threadIdx.x & 63;
    const size_t row = (size_t)blockIdx.x * 4 + wid;
    const int c0 = lane * 8;
    const float* xr = x + row * 512 + c0;
    float4 v0 = *(const float4*)xr;
    float4 v1 = *(const float4*)(xr + 4);
    float xv[8] = {v0.x, v0.y, v0.z, v0.w, v1.x, v1.y, v1.z, v1.w};
    float s = 0.f, q = 0.f;
#pragma unroll
    for (int j = 0; j < 8; j++) { s += xv[j]; q += xv[j] * xv[j]; }
#pragma unroll
    for (int m = 32; m >= 1; m >>= 1) {
        s += __shfl_xor(s, m, 64);
        q += __shfl_xor(q, m, 64);
    }
    const float mean = s * (1.f / 512.f);
    const float rstd = rsqrtf(q * (1.f / 512.f) - mean * mean + 1e-5f);
    half8 o;
#pragma unroll
    for (int j = 0; j < 8; j++)
        o[j] = (_Float16)((xv[j] - mean) * rstd * w[c0 + j] + b[c0 + j]);
    *(half8*)&out[row * 512 + c0] = o;
}

// ---------------------------------------------------------------------------
// Attention: 4 (b,head) units per 256-thread block (one wave each).
// ---------------------------------------------------------------------------
__global__ __launch_bounds__(256) void attn_k(
    const _Float16* __restrict__ qkv, _Float16* __restrict__ o)
{
    __shared__ float qs[4][12][65], ks[4][12][65], vs[4][12][65];
    __shared__ float att[4][12][16];
    const int wid = threadIdx.x >> 6, lane = threadIdx.x & 63;
    const int unit = blockIdx.x * 4 + wid;
    const int b = unit >> 3, hd = unit & 7;
    const _Float16* base = qkv + (size_t)b * (12 * 1536) + hd * 64 + lane;
#pragma unroll
    for (int r = 0; r < 12; r++) {
        qs[wid][r][lane] = (float)base[r * 1536];
        ks[wid][r][lane] = (float)base[r * 1536 + 512];
        vs[wid][r][lane] = (float)base[r * 1536 + 1024];
    }
    __syncthreads();
#pragma unroll
    for (int i = 0; i < 3; i++) {
        const int p = lane + i * 64;
        if (p < 144) {
            const int qi = p / 12, kj = p - qi * 12;
            float d = 0.f;
            for (int e = 0; e < 64; e++) d += qs[wid][qi][e] * ks[wid][kj][e];
            att[wid][qi][kj] = d * 0.125f;
        }
    }
    __syncthreads();
    if (lane < 12) {
        float mx = att[wid][lane][0];
#pragma unroll
        for (int j = 1; j < 12; j++) mx = fmaxf(mx, att[wid][lane][j]);
        float ev[12], ssum = 0.f;
#pragma unroll
        for (int j = 0; j < 12; j++) { ev[j] = expf(att[wid][lane][j] - mx); ssum += ev[j]; }
        const float inv = 1.f / ssum;
#pragma unroll
        for (int j = 0; j < 12; j++) att[wid][lane][j] = ev[j] * inv;
    }
    __syncthreads();
    _Float16* ob = o + (size_t)b * (12 * 512) + hd * 64 + lane;
#pragma unroll
    for (int qi = 0; qi < 12; qi++) {
        float s = 0.f;
#pragma unroll
        for (int j = 0; j < 12; j++) s += att[wid][qi][j] * vs[wid][j][lane];
        ob[qi * 512] = (_Float16)s;
    }
}

// ---------------------------------------------------------------------------
// Fused factors + per-(batch,feature) time-norm -> (CH*12, 96) f16 patch rows.
// ---------------------------------------------------------------------------
struct FSt { float e12, e26, ag, al, s1c, s2c, s1v; };

__device__ __forceinline__ void fderiv(
    int t, float c, float cprev, float co, float v, float vprev, float vo,
    FSt& s, float f[6])
{
    const float a12 = 2.f / 13.f, a26 = 2.f / 27.f, a14 = 1.f / 14.f;
    const float sv = v > 0.f ? v : 1.f;
    if (t > 0) {
        s.e12 = a12 * c + (1.f - a12) * s.e12;
        s.e26 = a26 * c + (1.f - a26) * s.e26;
    }
    const float macd = s.e12 - s.e26;
    const float delta = t > 0 ? c - cprev : 0.f;
    if (t > 0) {
        s.ag = a14 * fmaxf(delta, 0.f) + (1.f - a14) * s.ag;
        s.al = a14 * fmaxf(-delta, 0.f) + (1.f - a14) * s.al;
    }
    const float rs = s.ag / (s.al + 1e-10f);
    const float rsi = (100.f - 100.f / (1.f + rs)) * 0.01f;
    s.s1c += c; s.s2c += c * c; s.s1v += sv;
    if (t >= 20) {
        const float svo = vo > 0.f ? vo : 1.f;
        s.s1c -= co; s.s2c -= co * co; s.s1v -= svo;
    }
    float bb = 0.f, vmr = 1.f;
    if (t >= 19) {
        const float mean = s.s1c * 0.05f;
        const float sq = s.s2c * 0.05f;
        const float sd = sqrtf(fmaxf(sq - mean * mean, 0.f));
        bb = 4.f * sd / (mean + 1e-8f);
        vmr = sv / (s.s1v * 0.05f + 1e-8f);
    }
    float lr = 0.f, lv = 0.f;
    if (t > 0) {
        lr = logf(fmaxf(c, 1e-8f) / fmaxf(cprev, 1e-8f));
        const float svp = vprev > 0.f ? vprev : 1.f;
        lv = logf(sv / (svp + 1e-8f));
    }
    f[0] = isfinite(macd) ? macd : 0.f;
    f[1] = isfinite(rsi) ? rsi : 0.f;
    f[2] = isfinite(bb) ? bb : 0.f;
    f[3] = isfinite(lr) ? lr : 0.f;
    f[4] = isfinite(lv) ? lv : 0.f;
    f[5] = isfinite(vmr) ? vmr : 0.f;
}

__global__ __launch_bounds__(64) void factors_k(
    const float* __restrict__ x, const float* __restrict__ in_w,
    const float* __restrict__ in_b, _Float16* __restrict__ feats, int CH)
{
    const int tid = threadIdx.x;
    const int b = blockIdx.x * 64 + tid;
    if (b >= CH) return;
    __shared__ float cl[96][64];
    __shared__ float vl[96][64];
    const float* xb = x + (size_t)b * 480;

    float sum[11], ssq[11];
#pragma unroll
    for (int f = 0; f < 11; f++) { sum[f] = 0.f; ssq[f] = 0.f; }

    for (int t = 0; t < 96; t++) {
        const float* xq = xb + t * 5;
        const float a0 = xq[0], a1 = xq[1], a2 = xq[2], c = xq[3], v = xq[4];
        cl[t][tid] = c; vl[t][tid] = v;
        sum[0] += a0; ssq[0] += a0 * a0;
        sum[1] += a1; ssq[1] += a1 * a1;
        sum[2] += a2; ssq[2] += a2 * a2;
        sum[3] += c;  ssq[3] += c * c;
        sum[4] += v;  ssq[4] += v * v;
    }

    {
        const float c0 = cl[0][tid];
        FSt st{c0, c0, 0.f, 0.f, 0.f, 0.f, 0.f};
        for (int t = 0; t < 96; t++) {
            const float c = cl[t][tid], v = vl[t][tid];
            const float cp = t > 0 ? cl[t - 1][tid] : 0.f;
            const float vp = t > 0 ? vl[t - 1][tid] : 0.f;
            const float co = t >= 20 ? cl[t - 20][tid] : 0.f;
            const float vo = t >= 20 ? vl[t - 20][tid] : 0.f;
            float f6[6];
            fderiv(t, c, cp, co, v, vp, vo, st, f6);
#pragma unroll
            for (int j = 0; j < 6; j++) { sum[5 + j] += f6[j]; ssq[5 + j] += f6[j] * f6[j]; }
        }
    }
    float scale[11], shift[11];
#pragma unroll
    for (int f = 0; f < 11; f++) {
        const float m = sum[f] * (1.f / 96.f);
        const float var = ssq[f] * (1.f / 96.f) - m * m;
        const float r = rsqrtf(var + 1e-5f);
        scale[f] = r * in_w[f];
        shift[f] = in_b[f] - m * scale[f];
    }

    {
        const float c0 = cl[0][tid];
        FSt st{c0, c0, 0.f, 0.f, 0.f, 0.f, 0.f};
        _Float16* orow = feats + (size_t)b * 1152;
        for (int t = 0; t < 96; t++) {
            const float c = cl[t][tid], v = vl[t][tid];
            const float cp = t > 0 ? cl[t - 1][tid] : 0.f;
            const float vp = t > 0 ? vl[t - 1][tid] : 0.f;
            const float co = t >= 20 ? cl[t - 20][tid] : 0.f;
            const float vo = t >= 20 ? vl[t - 20][tid] : 0.f;
            float f6[6];
            fderiv(t, c, cp, co, v, vp, vo, st, f6);
            const float* xq = xb + t * 5;
            float o[11] = {xq[0], xq[1], xq[2], c, v, f6[0], f6[1], f6[2], f6[3], f6[4], f6[5]};
            _Float16* op = orow + (t >> 3) * 96 + (t & 7) * 11;
#pragma unroll
            for (int f = 0; f < 11; f++)
                op[f] = (_Float16)(o[f] * scale[f] + shift[f]);
        }
        const int4 z4 = {0, 0, 0, 0};
#pragma unroll
        for (int p = 0; p < 12; p++)
            *(int4*)(orow + p * 96 + 88) = z4;
    }
}

// ---------------------------------------------------------------------------
// Tiled transpose + cast, z-batched: W (K x N) fp32 -> Wt (N x Kpad) f16.
// ---------------------------------------------------------------------------
__global__ __launch_bounds__(256) void tr_k(
    const float* __restrict__ W, _Float16* __restrict__ Wt,
    int K, int N, int Kpad, long long ss, long long ds)
{
    W  += (size_t)blockIdx.z * ss;
    Wt += (size_t)blockIdx.z * ds;
    __shared__ _Float16 t[32][33];
    const int n0 = blockIdx.x * 32, k0 = blockIdx.y * 32;
#pragma unroll
    for (int j = 0; j < 4; j++) {
        const int k = k0 + threadIdx.y + j * 8;
        t[threadIdx.y + j * 8][threadIdx.x] =
            (k < K) ? (_Float16)W[(size_t)k * N + n0 + threadIdx.x] : (_Float16)0.f;
    }
    __syncthreads();
#pragma unroll
    for (int j = 0; j < 4; j++) {
        const int n = n0 + threadIdx.y + j * 8;
        Wt[(size_t)n * Kpad + k0 + threadIdx.x] = t[threadIdx.x][threadIdx.y + j * 8];
    }
}

// ---------------------------------------------------------------------------
extern "C" void kernel_launch(void* const* d_in, const int* in_sizes, int n_in,
                              void* d_out, int out_size, void* d_ws, size_t ws_size,
                              hipStream_t stream)
{
    static const int EXP[23] = {1966080, 11, 11, 45056, 512, 2048, 2048,
        3145728, 6144, 1048576, 2048, 2048, 2048, 4194304, 8192, 4194304, 2048,
        3145728, 512, 65536, 128, 384, 3};
    static const int S2D[23] = {18, 20, 22, 17, 19, 21, 2, 1, 6, 5, 12, 11,
        14, 16, 13, 15, 10, 9, 4, 3, 8, 7, 0};
    const void* in[23];
    if (n_in != 23 || out_size != 12288) return;
    bool ok = true;
    for (int i = 0; i < 23; i++) ok = ok && (in_sizes[i] == EXP[i]);
    if (ok) {
        for (int i = 0; i < 23; i++) in[i] = d_in[i];
    } else {
        bool ok2 = true;
        for (int s = 0; s < 23; s++) ok2 = ok2 && (in_sizes[s] == EXP[S2D[s]]);
        if (!ok2) return;
        for (int s = 0; s < 23; s++) in[S2D[s]] = d_in[s];
    }
    const float* x      = (const float*)in[0];
    const float* in_w   = (const float*)in[1];
    const float* in_b   = (const float*)in[2];
    const float* pe_w   = (const float*)in[3];
    const float* pe_b   = (const float*)in[4];
    const float* ln1_w  = (const float*)in[5];
    const float* ln1_b  = (const float*)in[6];
    const float* qkv_w  = (const float*)in[7];
    const float* qkv_b  = (const float*)in[8];
    const float* out_w  = (const float*)in[9];
    const float* out_b  = (const float*)in[10];
    const float* ln2_w  = (const float*)in[11];
    const float* ln2_b  = (const float*)in[12];
    const float* mlp_w1 = (const float*)in[13];
    const float* mlp_b1 = (const float*)in[14];
    const float* mlp_w2 = (const float*)in[15];
    const float* mlp_b2 = (const float*)in[16];
    const float* cls_w1 = (const float*)in[17];
    const float* cls_b1 = (const float*)in[18];
    const float* cls_w2 = (const float*)in[19];
    const float* cls_b2 = (const float*)in[20];
    const float* cls_w3 = (const float*)in[21];
    const float* cls_b3 = (const float*)in[22];

    // ---- f16 weight arena (~31.7 MB) ----
    char* ws = (char*)d_ws;
    size_t off = 0;
    _Float16* wt_pe  = (_Float16*)(ws + off); off += (size_t)512 * 96 * 2;
    _Float16* wt_qkv = (_Float16*)(ws + off); off += (size_t)4 * 1536 * 512 * 2;
    _Float16* wt_out = (_Float16*)(ws + off); off += (size_t)4 * 512 * 512 * 2;
    _Float16* wt_m1  = (_Float16*)(ws + off); off += (size_t)4 * 2048 * 512 * 2;
    _Float16* wt_m2  = (_Float16*)(ws + off); off += (size_t)4 * 512 * 2048 * 2;
    _Float16* wt_c1  = (_Float16*)(ws + off); off += (size_t)512 * 6144 * 2;
    _Float16* wt_c2  = (_Float16*)(ws + off); off += (size_t)128 * 512 * 2;
    const size_t wbytes = off;

    // per-batch bytes = h32 24576 + abuf 12288 + bbuf 49152
    const size_t per = 86016 + 64;
    int CH = 2048;
    while (CH > 128 && wbytes + (size_t)CH * per > ws_size) CH >>= 1;
    const int nch = 4096 / CH;
    const int M = CH * 12;

    float*    h32  = (float*)(ws + off);    off += (size_t)M * 512 * 4;
    _Float16* abuf = (_Float16*)(ws + off); off += (size_t)M * 512 * 2;
    _Float16* bbuf = (_Float16*)(ws + off); off += (size_t)M * 2048 * 2;

    _Float16* feats = bbuf;                 // dead after pe GEMM
    _Float16* f1 = (_Float16*)h32;          // classifier temp (h32 dead then)
    float* part1 = (float*)bbuf;                          // 8*CH*512 fp32
    float* part2 = part1 + (size_t)8 * CH * 512;          // 4*CH*128 fp32

    // ---- weight prep: fp32 (K,N) -> f16 (N,Kpad) transposed, z-batched ----
    tr_k<<<dim3(16, 3, 1),   dim3(32, 8), 0, stream>>>(pe_w, wt_pe, 88, 512, 96, 0, 0);
    tr_k<<<dim3(48, 16, 4),  dim3(32, 8), 0, stream>>>(qkv_w, wt_qkv, 512, 1536, 512,
        (long long)512 * 1536, (long long)1536 * 512);
    tr_k<<<dim3(16, 16, 4),  dim3(32, 8), 0, stream>>>(out_w, wt_out, 512, 512, 512,
        (long long)512 * 512, (long long)512 * 512);
    tr_k<<<dim3(64, 16, 4),  dim3(32, 8), 0, stream>>>(mlp_w1, wt_m1, 512, 2048, 512,
        (long long)512 * 2048, (long long)2048 * 512);
    tr_k<<<dim3(16, 64, 4),  dim3(32, 8), 0, stream>>>(mlp_w2, wt_m2, 2048, 512, 2048,
        (long long)2048 * 512, (long long)512 * 2048);
    tr_k<<<dim3(16, 192, 1), dim3(32, 8), 0, stream>>>(cls_w1, wt_c1, 6144, 512, 6144, 0, 0);
    tr_k<<<dim3(4, 16, 1),   dim3(32, 8), 0, stream>>>(cls_w2, wt_c2, 512, 128, 512, 0, 0);

    for (int c = 0; c < nch; c++) {
        const float* xc = x + (size_t)c * CH * 480;
        factors_k<<<CH / 64, 64, 0, stream>>>(xc, in_w, in_b, feats, CH);
        gemm_f16g<<<dim3(4, M / 128), 256, 0, stream>>>(
            feats, wt_pe, pe_b, nullptr, h32, nullptr, M, 512, 96, 96, FLAG_W32);

        for (int i = 0; i < 4; i++) {
            ln_rows<<<M / 4, 256, 0, stream>>>(h32, ln1_w + i * 512, ln1_b + i * 512, abuf);
            gemm_f16g<<<dim3(12, M / 128), 256, 0, stream>>>(
                abuf, wt_qkv + (size_t)i * 1536 * 512, qkv_b + i * 1536,
                nullptr, nullptr, bbuf, M, 1536, 512, 512, FLAG_W16);
            attn_k<<<CH * 2, 256, 0, stream>>>(bbuf, abuf);
            gemm_f16g<<<dim3(4, M / 128), 256, 0, stream>>>(
                abuf, wt_out + (size_t)i * 512 * 512, out_b + i * 512,
                h32, h32, nullptr, M, 512, 512, 512, FLAG_RES | FLAG_W32);
            ln_rows<<<M / 4, 256, 0, stream>>>(h32, ln2_w + i * 512, ln2_b + i * 512, abuf);
            // mlp1: reg-staged variant (measured 100us vs 128us gload, r3/r5)
            gemm_f16<<<dim3(16, M / 128), 256, 0, stream>>>(
                abuf, wt_m1 + (size_t)i * 2048 * 512, mlp_b1 + i * 2048,
                nullptr, nullptr, bbuf, M, 2048, 512, 512, FLAG_W16 | FLAG_GELU);
            // at i==3 the fp32 residual stream is dead afterwards
            const int fl = FLAG_RES | (i == 3 ? FLAG_W16 : FLAG_W32);
            gemm_f16g<<<dim3(4, M / 128), 256, 0, stream>>>(
                bbuf, wt_m2 + (size_t)i * 512 * 2048, mlp_b2 + i * 512,
                h32, h32, abuf, M, 512, 2048, 2048, fl);
        }

        // classifier: abuf viewed as (CH, 6144) f16; split-K via fp32 partials
        gemm_f16g<<<dim3(4, CH / 128, 8), 256, 0, stream>>>(
            abuf, wt_c1, nullptr, nullptr, part1, nullptr, CH, 512, 6144, 768, FLAG_PART);
        skred_k<<<(CH * 512 + 255) / 256, 256, 0, stream>>>(
            part1, cls_b1, f1, CH * 512, 512, 8);
        gemm_f16g<<<dim3(1, CH / 128, 4), 256, 0, stream>>>(
            f1, wt_c2, nullptr, nullptr, part2, nullptr, CH, 128, 512, 128, FLAG_PART);
        skcls_k<<<CH / 4, 256, 0, stream>>>(
            part2, cls_b2, cls_w3, cls_b3, (float*)d_out + (size_t)c * CH * 3, CH);
    }
}

// Round 7
// 3022.077 us; speedup vs baseline: 1.3043x; 1.0253x over previous
//
#include <hip/hip_runtime.h>
#include <cstdint>
#include <cstddef>

typedef _Float16 half8 __attribute__((ext_vector_type(8)));
typedef float floatx4 __attribute__((ext_vector_type(4)));

#define FLAG_RES  1
#define FLAG_GELU 2
#define FLAG_W32  4
#define FLAG_W16  8
#define FLAG_PART 16

// Fast exact-GELU: erf via Abramowitz-Stegun 7.1.26 (|err| <= 1.5e-7).
// rcp via v_rcp_f32 (~1 ulp) instead of IEEE divide: ~10 fewer VALU insts,
// matters because the mlp1 epilogue (64 gelus/thread) is VALU-bound (r6:
// VALUBusy 62%, FETCH-insensitive).
__device__ __forceinline__ float gelu_exact(float x) {
    const float z = fabsf(x) * 0.70710678118654752f;
    const float t = __builtin_amdgcn_rcpf(fmaf(0.3275911f, z, 1.f));
    const float p = t * (0.254829592f + t * (-0.284496736f +
                     t * (1.421413741f + t * (-1.453152027f + t * 1.061405429f))));
    const float erfa = 1.f - p * __expf(-z * z);
    return 0.5f * x * (1.f + copysignf(erfa, x));
}

// async global->LDS (16B/lane): dest is wave-uniform base + lane*16.
typedef const __attribute__((address_space(1))) void GV;
typedef __attribute__((address_space(3))) void LV;
__device__ __forceinline__ void gl_lds16(const void* g, void* l) {
    __builtin_amdgcn_global_load_lds((GV*)g, (LV*)l, 16, 0, 0);
}

// XCD-aware chunked block swizzle (bijective when nwg % 8 == 0; identity
// otherwise). Verified r6: mlp1 FETCH_SIZE 101.5 -> 37 MB.
__device__ __forceinline__ void swz_bid(int& bx, int& by) {
    const int gx = gridDim.x;
    const int nwg = gx * gridDim.y;
    int id = blockIdx.y * gx + blockIdx.x;
    if ((nwg & 7) == 0) {
        const int q = nwg >> 3;
        id = (id & 7) * q + (id >> 3);
    }
    bx = id % gx;
    by = id / gx;
}

// ---------------------------------------------------------------------------
// GEMM (reg-staged): C(MxN) = A(MxK f16 rm) @ Bt(NxK f16 rm)^T + bias(fp32)
// 128x128 tile, BK=32, 256 thr (2x2 waves of 64x64). Register prefetch +
// LDS ping-pong, ONE barrier per iteration. XOR-swizzled LDS (verified r2:
// SQ_LDS_BANK_CONFLICT 6.3M -> 0). Measured best for mlp1 (short K, big
// grid): 100 us vs 128 us gload_lds (r3 vs r5).
// ---------------------------------------------------------------------------
__global__ __launch_bounds__(256, 2) void gemm_f16(
    const _Float16* __restrict__ A, const _Float16* __restrict__ Bt,
    const float* __restrict__ bias, const float* __restrict__ resid,
    float* __restrict__ out32, _Float16* __restrict__ out16,
    int M, int N, int K, int klen, int flags)
{
    __shared__ __align__(16) _Float16 As[2][128 * 32];
    __shared__ __align__(16) _Float16 Bs[2][128 * 32];
    const int tid = threadIdx.x;
    const int wid = tid >> 6;
    const int lane = tid & 63;
    int bxs, bys;
    swz_bid(bxs, bys);
    const int bm = bys * 128;
    const int bn = bxs * 128;
    const int wr = wid >> 1, wc = wid & 1;
    const int lane15 = lane & 15, quad = lane >> 4;
    const int kb = blockIdx.z * klen;

    floatx4 acc[4][4];
#pragma unroll
    for (int i = 0; i < 4; i++)
#pragma unroll
        for (int j = 0; j < 4; j++)
            acc[i][j] = floatx4{0.f, 0.f, 0.f, 0.f};

    const int r4 = lane >> 2;            // row within 16-row group
    const int ch = lane & 3;             // 16B chunk index
    const _Float16* Ap = A + ((size_t)bm + wid * 32 + r4) * K + kb + ch * 8;
    const _Float16* Bp = Bt + ((size_t)bn + wid * 32 + r4) * K + kb + ch * 8;
    const size_t row16 = (size_t)16 * K;
    const int lw = wid * 1024 + r4 * 32 + ((ch ^ ((r4 >> 1) & 3)) << 3);

    int aoff[4], boff[4];
#pragma unroll
    for (int mi = 0; mi < 4; mi++)
        aoff[mi] = (wr * 64 + mi * 16 + lane15) * 32 +
                   ((quad ^ ((lane15 >> 1) & 3)) << 3);
#pragma unroll
    for (int ni = 0; ni < 4; ni++)
        boff[ni] = (wc * 64 + ni * 16 + lane15) * 32 +
                   ((quad ^ ((lane15 >> 1) & 3)) << 3);

    int4 ra0 = *(const int4*)(Ap);
    int4 ra1 = *(const int4*)(Ap + row16);
    int4 rb0 = *(const int4*)(Bp);
    int4 rb1 = *(const int4*)(Bp + row16);

    const int nk = klen >> 5;
    for (int ik = 0; ik < nk; ik++) {
        _Float16* a_ = &As[ik & 1][0];
        _Float16* b_ = &Bs[ik & 1][0];
        *(int4*)(a_ + lw) = ra0;
        *(int4*)(a_ + lw + 512) = ra1;
        *(int4*)(b_ + lw) = rb0;
        *(int4*)(b_ + lw + 512) = rb1;
        __syncthreads();
        if (ik + 1 < nk) {
            const int ko = (ik + 1) << 5;
            ra0 = *(const int4*)(Ap + ko);
            ra1 = *(const int4*)(Ap + row16 + ko);
            rb0 = *(const int4*)(Bp + ko);
            rb1 = *(const int4*)(Bp + row16 + ko);
        }
        half8 af[4], bf[4];
#pragma unroll
        for (int mi = 0; mi < 4; mi++) af[mi] = *(const half8*)&a_[aoff[mi]];
#pragma unroll
        for (int ni = 0; ni < 4; ni++) bf[ni] = *(const half8*)&b_[boff[ni]];
#pragma unroll
        for (int mi = 0; mi < 4; mi++)
#pragma unroll
            for (int ni = 0; ni < 4; ni++)
                acc[mi][ni] = __builtin_amdgcn_mfma_f32_16x16x32_f16(
                    af[mi], bf[ni], acc[mi][ni], 0, 0, 0);
    }

    if (flags & FLAG_PART) {
        float* po = out32 + (size_t)blockIdx.z * ((size_t)M * N);
#pragma unroll
        for (int mi = 0; mi < 4; mi++) {
            const int gmb = bm + wr * 64 + mi * 16 + quad * 4;
#pragma unroll
            for (int ni = 0; ni < 4; ni++) {
                const int gn = bn + wc * 64 + ni * 16 + lane15;
#pragma unroll
                for (int r = 0; r < 4; r++)
                    po[(size_t)(gmb + r) * N + gn] = acc[mi][ni][r];
            }
        }
        return;
    }
#pragma unroll
    for (int mi = 0; mi < 4; mi++) {
        const int gmb = bm + wr * 64 + mi * 16 + quad * 4;
#pragma unroll
        for (int ni = 0; ni < 4; ni++) {
            const int gn = bn + wc * 64 + ni * 16 + lane15;
            const float bv = bias[gn];
#pragma unroll
            for (int r = 0; r < 4; r++) {
                float v = acc[mi][ni][r] + bv;
                if (flags & FLAG_GELU) v = gelu_exact(v);
                const size_t off = (size_t)(gmb + r) * N + gn;
                if (flags & FLAG_RES) v += resid[off];
                if (flags & FLAG_W32) out32[off] = v;
                if (flags & FLAG_W16) out16[off] = (_Float16)v;
            }
        }
    }
}

// ---------------------------------------------------------------------------
// GEMM (gload_lds-staged): same tile/skeleton, staging via global_load_lds
// dwordx4 with pre-swizzled SOURCE chunk. Best for non-mlp1 GEMMs (r5/r6).
// ---------------------------------------------------------------------------
__global__ __launch_bounds__(256, 3) void gemm_f16g(
    const _Float16* __restrict__ A, const _Float16* __restrict__ Bt,
    const float* __restrict__ bias, const float* __restrict__ resid,
    float* __restrict__ out32, _Float16* __restrict__ out16,
    int M, int N, int K, int klen, int flags)
{
    __shared__ __align__(16) _Float16 As[2][128 * 32];
    __shared__ __align__(16) _Float16 Bs[2][128 * 32];
    const int tid = threadIdx.x;
    const int wid = tid >> 6;
    const int lane = tid & 63;
    int bxs, bys;
    swz_bid(bxs, bys);
    const int bm = bys * 128;
    const int bn = bxs * 128;
    const int wr = wid >> 1, wc = wid & 1;
    const int lane15 = lane & 15, quad = lane >> 4;
    const int kb = blockIdx.z * klen;

    floatx4 acc[4][4];
#pragma unroll
    for (int i = 0; i < 4; i++)
#pragma unroll
        for (int j = 0; j < 4; j++)
            acc[i][j] = floatx4{0.f, 0.f, 0.f, 0.f};

    const int rr = lane >> 2;
    const int ch = lane & 3;
    const int cs = ch ^ ((rr >> 1) & 3);
    const _Float16* asrc0 = A + ((size_t)bm + wid * 32 + rr) * K + kb + cs * 8;
    const _Float16* asrc1 = asrc0 + (size_t)16 * K;
    const _Float16* bsrc0 = Bt + ((size_t)bn + wid * 32 + rr) * K + kb + cs * 8;
    const _Float16* bsrc1 = bsrc0 + (size_t)16 * K;

    int aoff[4], boff[4];
#pragma unroll
    for (int mi = 0; mi < 4; mi++)
        aoff[mi] = (wr * 64 + mi * 16 + lane15) * 32 +
                   ((quad ^ ((lane15 >> 1) & 3)) << 3);
#pragma unroll
    for (int ni = 0; ni < 4; ni++)
        boff[ni] = (wc * 64 + ni * 16 + lane15) * 32 +
                   ((quad ^ ((lane15 >> 1) & 3)) << 3);

    const int nk = klen >> 5;
    {
        _Float16* ab = &As[0][wid * 1024];
        _Float16* bb = &Bs[0][wid * 1024];
        gl_lds16(asrc0, ab);
        gl_lds16(asrc1, ab + 512);
        gl_lds16(bsrc0, bb);
        gl_lds16(bsrc1, bb + 512);
    }
    for (int ik = 0; ik < nk; ik++) {
        __syncthreads();
        if (ik + 1 < nk) {
            const int ko = (ik + 1) << 5;
            _Float16* ab = &As[(ik + 1) & 1][wid * 1024];
            _Float16* bb = &Bs[(ik + 1) & 1][wid * 1024];
            gl_lds16(asrc0 + ko, ab);
            gl_lds16(asrc1 + ko, ab + 512);
            gl_lds16(bsrc0 + ko, bb);
            gl_lds16(bsrc1 + ko, bb + 512);
        }
        const _Float16* a_ = As[ik & 1];
        const _Float16* b_ = Bs[ik & 1];
        half8 af[4], bf[4];
#pragma unroll
        for (int mi = 0; mi < 4; mi++) af[mi] = *(const half8*)&a_[aoff[mi]];
#pragma unroll
        for (int ni = 0; ni < 4; ni++) bf[ni] = *(const half8*)&b_[boff[ni]];
#pragma unroll
        for (int mi = 0; mi < 4; mi++)
#pragma unroll
            for (int ni = 0; ni < 4; ni++)
                acc[mi][ni] = __builtin_amdgcn_mfma_f32_16x16x32_f16(
                    af[mi], bf[ni], acc[mi][ni], 0, 0, 0);
    }

    if (flags & FLAG_PART) {
        float* po = out32 + (size_t)blockIdx.z * ((size_t)M * N);
#pragma unroll
        for (int mi = 0; mi < 4; mi++) {
            const int gmb = bm + wr * 64 + mi * 16 + quad * 4;
#pragma unroll
            for (int ni = 0; ni < 4; ni++) {
                const int gn = bn + wc * 64 + ni * 16 + lane15;
#pragma unroll
                for (int r = 0; r < 4; r++)
                    po[(size_t)(gmb + r) * N + gn] = acc[mi][ni][r];
            }
        }
        return;
    }
#pragma unroll
    for (int mi = 0; mi < 4; mi++) {
        const int gmb = bm + wr * 64 + mi * 16 + quad * 4;
#pragma unroll
        for (int ni = 0; ni < 4; ni++) {
            const int gn = bn + wc * 64 + ni * 16 + lane15;
            const float bv = bias[gn];
#pragma unroll
            for (int r = 0; r < 4; r++) {
                float v = acc[mi][ni][r] + bv;
                if (flags & FLAG_GELU) v = gelu_exact(v);
                const size_t off = (size_t)(gmb + r) * N + gn;
                if (flags & FLAG_RES) v += resid[off];
                if (flags & FLAG_W32) out32[off] = v;
                if (flags & FLAG_W16) out16[off] = (_Float16)v;
            }
        }
    }
}

// ---------------------------------------------------------------------------
// Split-K reduce: out[i] = gelu(bias[i%N] + sum_z part[z*MN + i]) as f16.
// ---------------------------------------------------------------------------
__global__ __launch_bounds__(256) void skred_k(
    const float* __restrict__ part, const float* __restrict__ bias,
    _Float16* __restrict__ out, int MN, int N, int S)
{
    const int i = blockIdx.x * 256 + threadIdx.x;
    if (i >= MN) return;
    float s = bias[i % N];
    for (int z = 0; z < S; z++) s += part[(size_t)z * MN + i];
    out[i] = (_Float16)gelu_exact(s);
}

// ---------------------------------------------------------------------------
// Fused split-K reduce (S=4, N=128) + gelu + final (128x3) matmul + bias.
// ---------------------------------------------------------------------------
__global__ __launch_bounds__(256) void skcls_k(
    const float* __restrict__ part, const float* __restrict__ b2,
    const float* __restrict__ w3, const float* __restrict__ b3,
    float* __restrict__ out, int CH)
{
    const int wid = threadIdx.x >> 6, lane = threadIdx.x & 63;
    const int b = blockIdx.x * 4 + wid;
    const size_t MN = (size_t)CH * 128;
    const int c0 = lane, c1 = lane + 64;
    float s0 = b2[c0], s1 = b2[c1];
#pragma unroll
    for (int z = 0; z < 4; z++) {
        s0 += part[z * MN + (size_t)b * 128 + c0];
        s1 += part[z * MN + (size_t)b * 128 + c1];
    }
    const float g0 = gelu_exact(s0), g1 = gelu_exact(s1);
    float a0 = g0 * w3[c0 * 3 + 0] + g1 * w3[c1 * 3 + 0];
    float a1 = g0 * w3[c0 * 3 + 1] + g1 * w3[c1 * 3 + 1];
    float a2 = g0 * w3[c0 * 3 + 2] + g1 * w3[c1 * 3 + 2];
#pragma unroll
    for (int m = 32; m >= 1; m >>= 1) {
        a0 += __shfl_xor(a0, m, 64);
        a1 += __shfl_xor(a1, m, 64);
        a2 += __shfl_xor(a2, m, 64);
    }
    if (lane == 0) {
        out[b * 3 + 0] = a0 + b3[0];
        out[b * 3 + 1] = a1 + b3[1];
        out[b * 3 + 2] = a2 + b3[2];
    }
}

// ---------------------------------------------------------------------------
// Row LayerNorm over 512 cols: fp32 in, fp32 params, f16 out. One wave/row.
// ---------------------------------------------------------------------------
__global__ __launch_bounds__(256) void ln_rows(
    const float* __restrict__ x, const float* __restrict__ w,
    const float* __restrict__ b, _Float16* __restrict__ out)
{
    const int wid = threadIdx.x >> 6, lane = threadIdx.x & 63;
    const size_t row = (size_t)blockIdx.x * 4 + wid;
    const int c0 = lane * 8;
    const float* xr = x + row * 512 + c0;
    float4 v0 = *(const float4*)xr;
    float4 v1 = *(const float4*)(xr + 4);
    float xv[8] = {v0.x, v0.y, v0.z, v0.w, v1.x, v1.y, v1.z, v1.w};
    float s = 0.f, q = 0.f;
#pragma unroll
    for (int j = 0; j < 8; j++) { s += xv[j]; q += xv[j] * xv[j]; }
#pragma unroll
    for (int m = 32; m >= 1; m >>= 1) {
        s += __shfl_xor(s, m, 64);
        q += __shfl_xor(q, m, 64);
    }
    const float mean = s * (1.f / 512.f);
    const float rstd = rsqrtf(q * (1.f / 512.f) - mean * mean + 1e-5f);
    half8 o;
#pragma unroll
    for (int j = 0; j < 8; j++)
        o[j] = (_Float16)((xv[j] - mean) * rstd * w[c0 + j] + b[c0 + j]);
    *(half8*)&out[row * 512 + c0] = o;
}

// ---------------------------------------------------------------------------
// Attention via MFMA: 4 (b,head) units per 256-thr block, one wave each.
// 12x64 Q,K,V padded to 16-row MFMA tiles (pad rows CLAMPED to valid memory
// so every operand is finite; pad contributions are exactly 0 because the
// P-fragment is 0 there; pad outputs not stored).
// Fragment layouts verified by this session's working GEMM:
//   A: row=lane&15, k=(lane>>4)*8+j ; B: col=lane&15, same k
//   C/D: col=lane&15, row=(lane>>4)*4+reg.
// ---------------------------------------------------------------------------
__global__ __launch_bounds__(256) void attn_k(
    const _Float16* __restrict__ qkv, _Float16* __restrict__ o)
{
    __shared__ float patt[4][16][17];   // per-wave P redistribution slice
    const int wid = threadIdx.x >> 6, lane = threadIdx.x & 63;
    const int unit = blockIdx.x * 4 + wid;
    const int b = unit >> 3, hd = unit & 7;
    const int lane15 = lane & 15, quad = lane >> 4;
    const _Float16* base = qkv + (size_t)b * 18432 + hd * 64;

    // ---- S = Q K^T : 2 MFMA over K=64 ----
    const int rq = lane15 < 12 ? lane15 : 11;         // clamp pad rows
    const _Float16* qrow = base + (size_t)rq * 1536;
    half8 qa0 = *(const half8*)(qrow + quad * 8);
    half8 qa1 = *(const half8*)(qrow + 32 + quad * 8);
    half8 kb0 = *(const half8*)(qrow + 512 + quad * 8);
    half8 kb1 = *(const half8*)(qrow + 544 + quad * 8);
    floatx4 s = floatx4{0.f, 0.f, 0.f, 0.f};
    s = __builtin_amdgcn_mfma_f32_16x16x32_f16(qa0, kb0, s, 0, 0, 0);
    s = __builtin_amdgcn_mfma_f32_16x16x32_f16(qa1, kb1, s, 0, 0, 0);
    // lane holds S[qi = quad*4+r][kj = lane15]

    // ---- softmax over kj (reduction across 16-lane groups) ----
    const bool kok = lane15 < 12;
    float p[4];
#pragma unroll
    for (int r = 0; r < 4; r++) {
        const float sv = s[r] * 0.125f;               // 1/sqrt(64)
        float mx = kok ? sv : -1e30f;
#pragma unroll
        for (int m = 1; m <= 8; m <<= 1)
            mx = fmaxf(mx, __shfl_xor(mx, m, 64));
        const float ev = kok ? __expf(sv - mx) : 0.f;
        float ss = ev;
#pragma unroll
        for (int m = 1; m <= 8; m <<= 1)
            ss += __shfl_xor(ss, m, 64);
        p[r] = ev * __builtin_amdgcn_rcpf(ss);
    }
    // redistribute P (C-layout) -> A-fragment layout via per-wave LDS slice;
    // single-wave DS ops are in-order, compiler inserts the lgkmcnt wait.
#pragma unroll
    for (int r = 0; r < 4; r++)
        patt[wid][quad * 4 + r][lane15] = p[r];

    half8 pa;
#pragma unroll
    for (int j = 0; j < 8; j++) {
        const int kj = quad * 8 + j;                  // 0..31 across quads
        pa[j] = (quad < 2) ? (_Float16)patt[wid][lane15][kj & 15]
                           : (_Float16)0.f;          // P cols 12..15 are 0
    }

    // ---- O = P V : 4 MFMA over d-groups of 16 ----
    const _Float16* vbase = base + 1024;
    floatx4 oacc[4];
#pragma unroll
    for (int ni = 0; ni < 4; ni++) {
        half8 vb;
#pragma unroll
        for (int j = 0; j < 8; j++) {
            int kv = quad * 8 + j;
            if (kv > 11) kv = 11;                     // clamped; A=0 there
            vb[j] = vbase[(size_t)kv * 1536 + ni * 16 + lane15];
        }
        oacc[ni] = __builtin_amdgcn_mfma_f32_16x16x32_f16(
            pa, vb, floatx4{0.f, 0.f, 0.f, 0.f}, 0, 0, 0);
    }
    _Float16* ob = o + (size_t)b * 6144 + hd * 64;
#pragma unroll
    for (int r = 0; r < 4; r++) {
        const int qi = quad * 4 + r;
        if (qi < 12) {
#pragma unroll
            for (int ni = 0; ni < 4; ni++)
                ob[(size_t)qi * 512 + ni * 16 + lane15] = (_Float16)oacc[ni][r];
        }
    }
}

// ---------------------------------------------------------------------------
// Fused factors + per-(batch,feature) time-norm -> (CH*12, 96) f16 patch rows.
// ---------------------------------------------------------------------------
struct FSt { float e12, e26, ag, al, s1c, s2c, s1v; };

__device__ __forceinline__ void fderiv(
    int t, float c, float cprev, float co, float v, float vprev, float vo,
    FSt& s, float f[6])
{
    const float a12 = 2.f / 13.f, a26 = 2.f / 27.f, a14 = 1.f / 14.f;
    const float sv = v > 0.f ? v : 1.f;
    if (t > 0) {
        s.e12 = a12 * c + (1.f - a12) * s.e12;
        s.e26 = a26 * c + (1.f - a26) * s.e26;
    }
    const float macd = s.e12 - s.e26;
    const float delta = t > 0 ? c - cprev : 0.f;
    if (t > 0) {
        s.ag = a14 * fmaxf(delta, 0.f) + (1.f - a14) * s.ag;
        s.al = a14 * fmaxf(-delta, 0.f) + (1.f - a14) * s.al;
    }
    const float rs = s.ag / (s.al + 1e-10f);
    const float rsi = (100.f - 100.f / (1.f + rs)) * 0.01f;
    s.s1c += c; s.s2c += c * c; s.s1v += sv;
    if (t >= 20) {
        const float svo = vo > 0.f ? vo : 1.f;
        s.s1c -= co; s.s2c -= co * co; s.s1v -= svo;
    }
    float bb = 0.f, vmr = 1.f;
    if (t >= 19) {
        const float mean = s.s1c * 0.05f;
        const float sq = s.s2c * 0.05f;
        const float sd = sqrtf(fmaxf(sq - mean * mean, 0.f));
        bb = 4.f * sd / (mean + 1e-8f);
        vmr = sv / (s.s1v * 0.05f + 1e-8f);
    }
    float lr = 0.f, lv = 0.f;
    if (t > 0) {
        lr = logf(fmaxf(c, 1e-8f) / fmaxf(cprev, 1e-8f));
        const float svp = vprev > 0.f ? vprev : 1.f;
        lv = logf(sv / (svp + 1e-8f));
    }
    f[0] = isfinite(macd) ? macd : 0.f;
    f[1] = isfinite(rsi) ? rsi : 0.f;
    f[2] = isfinite(bb) ? bb : 0.f;
    f[3] = isfinite(lr) ? lr : 0.f;
    f[4] = isfinite(lv) ? lv : 0.f;
    f[5] = isfinite(vmr) ? vmr : 0.f;
}

__global__ __launch_bounds__(64) void factors_k(
    const float* __restrict__ x, const float* __restrict__ in_w,
    const float* __restrict__ in_b, _Float16* __restrict__ feats, int CH)
{
    const int tid = threadIdx.x;
    const int b = blockIdx.x * 64 + tid;
    if (b >= CH) return;
    __shared__ float cl[96][64];
    __shared__ float vl[96][64];
    const float* xb = x + (size_t)b * 480;

    float sum[11], ssq[11];
#pragma unroll
    for (int f = 0; f < 11; f++) { sum[f] = 0.f; ssq[f] = 0.f; }

    for (int t = 0; t < 96; t++) {
        const float* xq = xb + t * 5;
        const float a0 = xq[0], a1 = xq[1], a2 = xq[2], c = xq[3], v = xq[4];
        cl[t][tid] = c; vl[t][tid] = v;
        sum[0] += a0; ssq[0] += a0 * a0;
        sum[1] += a1; ssq[1] += a1 * a1;
        sum[2] += a2; ssq[2] += a2 * a2;
        sum[3] += c;  ssq[3] += c * c;
        sum[4] += v;  ssq[4] += v * v;
    }

    {
        const float c0 = cl[0][tid];
        FSt st{c0, c0, 0.f, 0.f, 0.f, 0.f, 0.f};
        for (int t = 0; t < 96; t++) {
            const float c = cl[t][tid], v = vl[t][tid];
            const float cp = t > 0 ? cl[t - 1][tid] : 0.f;
            const float vp = t > 0 ? vl[t - 1][tid] : 0.f;
            const float co = t >= 20 ? cl[t - 20][tid] : 0.f;
            const float vo = t >= 20 ? vl[t - 20][tid] : 0.f;
            float f6[6];
            fderiv(t, c, cp, co, v, vp, vo, st, f6);
#pragma unroll
            for (int j = 0; j < 6; j++) { sum[5 + j] += f6[j]; ssq[5 + j] += f6[j] * f6[j]; }
        }
    }
    float scale[11], shift[11];
#pragma unroll
    for (int f = 0; f < 11; f++) {
        const float m = sum[f] * (1.f / 96.f);
        const float var = ssq[f] * (1.f / 96.f) - m * m;
        const float r = rsqrtf(var + 1e-5f);
        scale[f] = r * in_w[f];
        shift[f] = in_b[f] - m * scale[f];
    }

    {
        const float c0 = cl[0][tid];
        FSt st{c0, c0, 0.f, 0.f, 0.f, 0.f, 0.f};
        _Float16* orow = feats + (size_t)b * 1152;
        for (int t = 0; t < 96; t++) {
            const float c = cl[t][tid], v = vl[t][tid];
            const float cp = t > 0 ? cl[t - 1][tid] : 0.f;
            const float vp = t > 0 ? vl[t - 1][tid] : 0.f;
            const float co = t >= 20 ? cl[t - 20][tid] : 0.f;
            const float vo = t >= 20 ? vl[t - 20][tid] : 0.f;
            float f6[6];
            fderiv(t, c, cp, co, v, vp, vo, st, f6);
            const float* xq = xb + t * 5;
            float o[11] = {xq[0], xq[1], xq[2], c, v, f6[0], f6[1], f6[2], f6[3], f6[4], f6[5]};
            _Float16* op = orow + (t >> 3) * 96 + (t & 7) * 11;
#pragma unroll
            for (int f = 0; f < 11; f++)
                op[f] = (_Float16)(o[f] * scale[f] + shift[f]);
        }
        const int4 z4 = {0, 0, 0, 0};
#pragma unroll
        for (int p = 0; p < 12; p++)
            *(int4*)(orow + p * 96 + 88) = z4;
    }
}

// ---------------------------------------------------------------------------
// Tiled transpose + cast, z-batched: W (K x N) fp32 -> Wt (N x Kpad) f16.
// ---------------------------------------------------------------------------
__global__ __launch_bounds__(256) void tr_k(
    const float* __restrict__ W, _Float16* __restrict__ Wt,
    int K, int N, int Kpad, long long ss, long long ds)
{
    W  += (size_t)blockIdx.z * ss;
    Wt += (size_t)blockIdx.z * ds;
    __shared__ _Float16 t[32][33];
    const int n0 = blockIdx.x * 32, k0 = blockIdx.y * 32;
#pragma unroll
    for (int j = 0; j < 4; j++) {
        const int k = k0 + threadIdx.y + j * 8;
        t[threadIdx.y + j * 8][threadIdx.x] =
            (k < K) ? (_Float16)W[(size_t)k * N + n0 + threadIdx.x] : (_Float16)0.f;
    }
    __syncthreads();
#pragma unroll
    for (int j = 0; j < 4; j++) {
        const int n = n0 + threadIdx.y + j * 8;
        Wt[(size_t)n * Kpad + k0 + threadIdx.x] = t[threadIdx.x][threadIdx.y + j * 8];
    }
}

// ---------------------------------------------------------------------------
extern "C" void kernel_launch(void* const* d_in, const int* in_sizes, int n_in,
                              void* d_out, int out_size, void* d_ws, size_t ws_size,
                              hipStream_t stream)
{
    static const int EXP[23] = {1966080, 11, 11, 45056, 512, 2048, 2048,
        3145728, 6144, 1048576, 2048, 2048, 2048, 4194304, 8192, 4194304, 2048,
        3145728, 512, 65536, 128, 384, 3};
    static const int S2D[23] = {18, 20, 22, 17, 19, 21, 2, 1, 6, 5, 12, 11,
        14, 16, 13, 15, 10, 9, 4, 3, 8, 7, 0};
    const void* in[23];
    if (n_in != 23 || out_size != 12288) return;
    bool ok = true;
    for (int i = 0; i < 23; i++) ok = ok && (in_sizes[i] == EXP[i]);
    if (ok) {
        for (int i = 0; i < 23; i++) in[i] = d_in[i];
    } else {
        bool ok2 = true;
        for (int s = 0; s < 23; s++) ok2 = ok2 && (in_sizes[s] == EXP[S2D[s]]);
        if (!ok2) return;
        for (int s = 0; s < 23; s++) in[S2D[s]] = d_in[s];
    }
    const float* x      = (const float*)in[0];
    const float* in_w   = (const float*)in[1];
    const float* in_b   = (const float*)in[2];
    const float* pe_w   = (const float*)in[3];
    const float* pe_b   = (const float*)in[4];
    const float* ln1_w  = (const float*)in[5];
    const float* ln1_b  = (const float*)in[6];
    const float* qkv_w  = (const float*)in[7];
    const float* qkv_b  = (const float*)in[8];
    const float* out_w  = (const float*)in[9];
    const float* out_b  = (const float*)in[10];
    const float* ln2_w  = (const float*)in[11];
    const float* ln2_b  = (const float*)in[12];
    const float* mlp_w1 = (const float*)in[13];
    const float* mlp_b1 = (const float*)in[14];
    const float* mlp_w2 = (const float*)in[15];
    const float* mlp_b2 = (const float*)in[16];
    const float* cls_w1 = (const float*)in[17];
    const float* cls_b1 = (const float*)in[18];
    const float* cls_w2 = (const float*)in[19];
    const float* cls_b2 = (const float*)in[20];
    const float* cls_w3 = (const float*)in[21];
    const float* cls_b3 = (const float*)in[22];

    // ---- f16 weight arena (~31.7 MB) ----
    char* ws = (char*)d_ws;
    size_t off = 0;
    _Float16* wt_pe  = (_Float16*)(ws + off); off += (size_t)512 * 96 * 2;
    _Float16* wt_qkv = (_Float16*)(ws + off); off += (size_t)4 * 1536 * 512 * 2;
    _Float16* wt_out = (_Float16*)(ws + off); off += (size_t)4 * 512 * 512 * 2;
    _Float16* wt_m1  = (_Float16*)(ws + off); off += (size_t)4 * 2048 * 512 * 2;
    _Float16* wt_m2  = (_Float16*)(ws + off); off += (size_t)4 * 512 * 2048 * 2;
    _Float16* wt_c1  = (_Float16*)(ws + off); off += (size_t)512 * 6144 * 2;
    _Float16* wt_c2  = (_Float16*)(ws + off); off += (size_t)128 * 512 * 2;
    const size_t wbytes = off;

    // per-batch bytes = h32 24576 + abuf 12288 + bbuf 49152
    const size_t per = 86016 + 64;
    int CH = 2048;
    while (CH > 128 && wbytes + (size_t)CH * per > ws_size) CH >>= 1;
    const int nch = 4096 / CH;
    const int M = CH * 12;

    float*    h32  = (float*)(ws + off);    off += (size_t)M * 512 * 4;
    _Float16* abuf = (_Float16*)(ws + off); off += (size_t)M * 512 * 2;
    _Float16* bbuf = (_Float16*)(ws + off); off += (size_t)M * 2048 * 2;

    _Float16* feats = bbuf;                 // dead after pe GEMM
    _Float16* f1 = (_Float16*)h32;          // classifier temp (h32 dead then)
    float* part1 = (float*)bbuf;                          // 8*CH*512 fp32
    float* part2 = part1 + (size_t)8 * CH * 512;          // 4*CH*128 fp32

    // ---- weight prep: fp32 (K,N) -> f16 (N,Kpad) transposed, z-batched ----
    tr_k<<<dim3(16, 3, 1),   dim3(32, 8), 0, stream>>>(pe_w, wt_pe, 88, 512, 96, 0, 0);
    tr_k<<<dim3(48, 16, 4),  dim3(32, 8), 0, stream>>>(qkv_w, wt_qkv, 512, 1536, 512,
        (long long)512 * 1536, (long long)1536 * 512);
    tr_k<<<dim3(16, 16, 4),  dim3(32, 8), 0, stream>>>(out_w, wt_out, 512, 512, 512,
        (long long)512 * 512, (long long)512 * 512);
    tr_k<<<dim3(64, 16, 4),  dim3(32, 8), 0, stream>>>(mlp_w1, wt_m1, 512, 2048, 512,
        (long long)512 * 2048, (long long)2048 * 512);
    tr_k<<<dim3(16, 64, 4),  dim3(32, 8), 0, stream>>>(mlp_w2, wt_m2, 2048, 512, 2048,
        (long long)2048 * 512, (long long)512 * 2048);
    tr_k<<<dim3(16, 192, 1), dim3(32, 8), 0, stream>>>(cls_w1, wt_c1, 6144, 512, 6144, 0, 0);
    tr_k<<<dim3(4, 16, 1),   dim3(32, 8), 0, stream>>>(cls_w2, wt_c2, 512, 128, 512, 0, 0);

    for (int c = 0; c < nch; c++) {
        const float* xc = x + (size_t)c * CH * 480;
        factors_k<<<CH / 64, 64, 0, stream>>>(xc, in_w, in_b, feats, CH);
        gemm_f16g<<<dim3(4, M / 128), 256, 0, stream>>>(
            feats, wt_pe, pe_b, nullptr, h32, nullptr, M, 512, 96, 96, FLAG_W32);

        for (int i = 0; i < 4; i++) {
            ln_rows<<<M / 4, 256, 0, stream>>>(h32, ln1_w + i * 512, ln1_b + i * 512, abuf);
            gemm_f16g<<<dim3(12, M / 128), 256, 0, stream>>>(
                abuf, wt_qkv + (size_t)i * 1536 * 512, qkv_b + i * 1536,
                nullptr, nullptr, bbuf, M, 1536, 512, 512, FLAG_W16);
            attn_k<<<CH * 2, 256, 0, stream>>>(bbuf, abuf);
            gemm_f16g<<<dim3(4, M / 128), 256, 0, stream>>>(
                abuf, wt_out + (size_t)i * 512 * 512, out_b + i * 512,
                h32, h32, nullptr, M, 512, 512, 512, FLAG_RES | FLAG_W32);
            ln_rows<<<M / 4, 256, 0, stream>>>(h32, ln2_w + i * 512, ln2_b + i * 512, abuf);
            // mlp1: reg-staged variant (measured 100us vs 128us gload, r3/r5)
            gemm_f16<<<dim3(16, M / 128), 256, 0, stream>>>(
                abuf, wt_m1 + (size_t)i * 2048 * 512, mlp_b1 + i * 2048,
                nullptr, nullptr, bbuf, M, 2048, 512, 512, FLAG_W16 | FLAG_GELU);
            // at i==3 the fp32 residual stream is dead afterwards
            const int fl = FLAG_RES | (i == 3 ? FLAG_W16 : FLAG_W32);
            gemm_f16g<<<dim3(4, M / 128), 256, 0, stream>>>(
                bbuf, wt_m2 + (size_t)i * 512 * 2048, mlp_b2 + i * 512,
                h32, h32, abuf, M, 512, 2048, 2048, fl);
        }

        // classifier: abuf viewed as (CH, 6144) f16; split-K via fp32 partials
        gemm_f16g<<<dim3(4, CH / 128, 8), 256, 0, stream>>>(
            abuf, wt_c1, nullptr, nullptr, part1, nullptr, CH, 512, 6144, 768, FLAG_PART);
        skred_k<<<(CH * 512 + 255) / 256, 256, 0, stream>>>(
            part1, cls_b1, f1, CH * 512, 512, 8);
        gemm_f16g<<<dim3(1, CH / 128, 4), 256, 0, stream>>>(
            f1, wt_c2, nullptr, nullptr, part2, nullptr, CH, 128, 512, 128, FLAG_PART);
        skcls_k<<<CH / 4, 256, 0, stream>>>(
            part2, cls_b2, cls_w3, cls_b3, (float*)d_out + (size_t)c * CH * 3, CH);
    }
}

// Round 8
// 2767.945 us; speedup vs baseline: 1.4241x; 1.0918x over previous
//
#include <hip/hip_runtime.h>
#include <cstdint>
#include <cstddef>

typedef _Float16 half8 __attribute__((ext_vector_type(8)));
typedef float floatx4 __attribute__((ext_vector_type(4)));

#define FLAG_RES  1
#define FLAG_GELU 2
#define FLAG_W32  4
#define FLAG_W16  8
#define FLAG_PART 16

// Fast exact-GELU: erf via Abramowitz-Stegun 7.1.26 (|err| <= 1.5e-7).
__device__ __forceinline__ float gelu_exact(float x) {
    const float z = fabsf(x) * 0.70710678118654752f;
    const float t = __builtin_amdgcn_rcpf(fmaf(0.3275911f, z, 1.f));
    const float p = t * (0.254829592f + t * (-0.284496736f +
                     t * (1.421413741f + t * (-1.453152027f + t * 1.061405429f))));
    const float erfa = 1.f - p * __expf(-z * z);
    return 0.5f * x * (1.f + copysignf(erfa, x));
}

// async global->LDS (16B/lane): dest is wave-uniform base + lane*16.
typedef const __attribute__((address_space(1))) void GV;
typedef __attribute__((address_space(3))) void LV;
__device__ __forceinline__ void gl_lds16(const void* g, void* l) {
    __builtin_amdgcn_global_load_lds((GV*)g, (LV*)l, 16, 0, 0);
}

// XCD-aware chunked block swizzle (bijective when nwg % 8 == 0; identity
// otherwise). Verified r6: mlp1 FETCH_SIZE 101.5 -> 37 MB.
__device__ __forceinline__ void swz_bid(int& bx, int& by) {
    const int gx = gridDim.x;
    const int nwg = gx * gridDim.y;
    int id = blockIdx.y * gx + blockIdx.x;
    if ((nwg & 7) == 0) {
        const int q = nwg >> 3;
        id = (id & 7) * q + (id >> 3);
    }
    bx = id % gx;
    by = id / gx;
}

// ---------------------------------------------------------------------------
// GEMM (reg-staged): C(MxN) = A(MxK f16 rm) @ Bt(NxK f16 rm)^T + bias(fp32)
// 128x128 tile, BK=32, 256 thr. XOR-swizzled LDS (r2: conflicts 6.3M -> 0).
// Best for mlp1 (short K, big grid): 100 vs 128 us gload_lds (r3/r5).
// ---------------------------------------------------------------------------
__global__ __launch_bounds__(256, 2) void gemm_f16(
    const _Float16* __restrict__ A, const _Float16* __restrict__ Bt,
    const float* __restrict__ bias, const float* __restrict__ resid,
    float* __restrict__ out32, _Float16* __restrict__ out16,
    int M, int N, int K, int klen, int flags)
{
    __shared__ __align__(16) _Float16 As[2][128 * 32];
    __shared__ __align__(16) _Float16 Bs[2][128 * 32];
    const int tid = threadIdx.x;
    const int wid = tid >> 6;
    const int lane = tid & 63;
    int bxs, bys;
    swz_bid(bxs, bys);
    const int bm = bys * 128;
    const int bn = bxs * 128;
    const int wr = wid >> 1, wc = wid & 1;
    const int lane15 = lane & 15, quad = lane >> 4;
    const int kb = blockIdx.z * klen;

    floatx4 acc[4][4];
#pragma unroll
    for (int i = 0; i < 4; i++)
#pragma unroll
        for (int j = 0; j < 4; j++)
            acc[i][j] = floatx4{0.f, 0.f, 0.f, 0.f};

    const int r4 = lane >> 2;
    const int ch = lane & 3;
    const _Float16* Ap = A + ((size_t)bm + wid * 32 + r4) * K + kb + ch * 8;
    const _Float16* Bp = Bt + ((size_t)bn + wid * 32 + r4) * K + kb + ch * 8;
    const size_t row16 = (size_t)16 * K;
    const int lw = wid * 1024 + r4 * 32 + ((ch ^ ((r4 >> 1) & 3)) << 3);

    int aoff[4], boff[4];
#pragma unroll
    for (int mi = 0; mi < 4; mi++)
        aoff[mi] = (wr * 64 + mi * 16 + lane15) * 32 +
                   ((quad ^ ((lane15 >> 1) & 3)) << 3);
#pragma unroll
    for (int ni = 0; ni < 4; ni++)
        boff[ni] = (wc * 64 + ni * 16 + lane15) * 32 +
                   ((quad ^ ((lane15 >> 1) & 3)) << 3);

    int4 ra0 = *(const int4*)(Ap);
    int4 ra1 = *(const int4*)(Ap + row16);
    int4 rb0 = *(const int4*)(Bp);
    int4 rb1 = *(const int4*)(Bp + row16);

    const int nk = klen >> 5;
    for (int ik = 0; ik < nk; ik++) {
        _Float16* a_ = &As[ik & 1][0];
        _Float16* b_ = &Bs[ik & 1][0];
        *(int4*)(a_ + lw) = ra0;
        *(int4*)(a_ + lw + 512) = ra1;
        *(int4*)(b_ + lw) = rb0;
        *(int4*)(b_ + lw + 512) = rb1;
        __syncthreads();
        if (ik + 1 < nk) {
            const int ko = (ik + 1) << 5;
            ra0 = *(const int4*)(Ap + ko);
            ra1 = *(const int4*)(Ap + row16 + ko);
            rb0 = *(const int4*)(Bp + ko);
            rb1 = *(const int4*)(Bp + row16 + ko);
        }
        half8 af[4], bf[4];
#pragma unroll
        for (int mi = 0; mi < 4; mi++) af[mi] = *(const half8*)&a_[aoff[mi]];
#pragma unroll
        for (int ni = 0; ni < 4; ni++) bf[ni] = *(const half8*)&b_[boff[ni]];
#pragma unroll
        for (int mi = 0; mi < 4; mi++)
#pragma unroll
            for (int ni = 0; ni < 4; ni++)
                acc[mi][ni] = __builtin_amdgcn_mfma_f32_16x16x32_f16(
                    af[mi], bf[ni], acc[mi][ni], 0, 0, 0);
    }

    if (flags & FLAG_PART) {
        float* po = out32 + (size_t)blockIdx.z * ((size_t)M * N);
#pragma unroll
        for (int mi = 0; mi < 4; mi++) {
            const int gmb = bm + wr * 64 + mi * 16 + quad * 4;
#pragma unroll
            for (int ni = 0; ni < 4; ni++) {
                const int gn = bn + wc * 64 + ni * 16 + lane15;
#pragma unroll
                for (int r = 0; r < 4; r++)
                    po[(size_t)(gmb + r) * N + gn] = acc[mi][ni][r];
            }
        }
        return;
    }
#pragma unroll
    for (int mi = 0; mi < 4; mi++) {
        const int gmb = bm + wr * 64 + mi * 16 + quad * 4;
#pragma unroll
        for (int ni = 0; ni < 4; ni++) {
            const int gn = bn + wc * 64 + ni * 16 + lane15;
            const float bv = bias[gn];
#pragma unroll
            for (int r = 0; r < 4; r++) {
                float v = acc[mi][ni][r] + bv;
                if (flags & FLAG_GELU) v = gelu_exact(v);
                const size_t off = (size_t)(gmb + r) * N + gn;
                if (flags & FLAG_RES) v += resid[off];
                if (flags & FLAG_W32) out32[off] = v;
                if (flags & FLAG_W16) out16[off] = (_Float16)v;
            }
        }
    }
}

// ---------------------------------------------------------------------------
// GEMM (gload_lds-staged): pre-swizzled SOURCE chunk. Best non-mlp1 (r5/r6).
// ---------------------------------------------------------------------------
__global__ __launch_bounds__(256, 3) void gemm_f16g(
    const _Float16* __restrict__ A, const _Float16* __restrict__ Bt,
    const float* __restrict__ bias, const float* __restrict__ resid,
    float* __restrict__ out32, _Float16* __restrict__ out16,
    int M, int N, int K, int klen, int flags)
{
    __shared__ __align__(16) _Float16 As[2][128 * 32];
    __shared__ __align__(16) _Float16 Bs[2][128 * 32];
    const int tid = threadIdx.x;
    const int wid = tid >> 6;
    const int lane = tid & 63;
    int bxs, bys;
    swz_bid(bxs, bys);
    const int bm = bys * 128;
    const int bn = bxs * 128;
    const int wr = wid >> 1, wc = wid & 1;
    const int lane15 = lane & 15, quad = lane >> 4;
    const int kb = blockIdx.z * klen;

    floatx4 acc[4][4];
#pragma unroll
    for (int i = 0; i < 4; i++)
#pragma unroll
        for (int j = 0; j < 4; j++)
            acc[i][j] = floatx4{0.f, 0.f, 0.f, 0.f};

    const int rr = lane >> 2;
    const int ch = lane & 3;
    const int cs = ch ^ ((rr >> 1) & 3);
    const _Float16* asrc0 = A + ((size_t)bm + wid * 32 + rr) * K + kb + cs * 8;
    const _Float16* asrc1 = asrc0 + (size_t)16 * K;
    const _Float16* bsrc0 = Bt + ((size_t)bn + wid * 32 + rr) * K + kb + cs * 8;
    const _Float16* bsrc1 = bsrc0 + (size_t)16 * K;

    int aoff[4], boff[4];
#pragma unroll
    for (int mi = 0; mi < 4; mi++)
        aoff[mi] = (wr * 64 + mi * 16 + lane15) * 32 +
                   ((quad ^ ((lane15 >> 1) & 3)) << 3);
#pragma unroll
    for (int ni = 0; ni < 4; ni++)
        boff[ni] = (wc * 64 + ni * 16 + lane15) * 32 +
                   ((quad ^ ((lane15 >> 1) & 3)) << 3);

    const int nk = klen >> 5;
    {
        _Float16* ab = &As[0][wid * 1024];
        _Float16* bb = &Bs[0][wid * 1024];
        gl_lds16(asrc0, ab);
        gl_lds16(asrc1, ab + 512);
        gl_lds16(bsrc0, bb);
        gl_lds16(bsrc1, bb + 512);
    }
    for (int ik = 0; ik < nk; ik++) {
        __syncthreads();
        if (ik + 1 < nk) {
            const int ko = (ik + 1) << 5;
            _Float16* ab = &As[(ik + 1) & 1][wid * 1024];
            _Float16* bb = &Bs[(ik + 1) & 1][wid * 1024];
            gl_lds16(asrc0 + ko, ab);
            gl_lds16(asrc1 + ko, ab + 512);
            gl_lds16(bsrc0 + ko, bb);
            gl_lds16(bsrc1 + ko, bb + 512);
        }
        const _Float16* a_ = As[ik & 1];
        const _Float16* b_ = Bs[ik & 1];
        half8 af[4], bf[4];
#pragma unroll
        for (int mi = 0; mi < 4; mi++) af[mi] = *(const half8*)&a_[aoff[mi]];
#pragma unroll
        for (int ni = 0; ni < 4; ni++) bf[ni] = *(const half8*)&b_[boff[ni]];
#pragma unroll
        for (int mi = 0; mi < 4; mi++)
#pragma unroll
            for (int ni = 0; ni < 4; ni++)
                acc[mi][ni] = __builtin_amdgcn_mfma_f32_16x16x32_f16(
                    af[mi], bf[ni], acc[mi][ni], 0, 0, 0);
    }

    if (flags & FLAG_PART) {
        float* po = out32 + (size_t)blockIdx.z * ((size_t)M * N);
#pragma unroll
        for (int mi = 0; mi < 4; mi++) {
            const int gmb = bm + wr * 64 + mi * 16 + quad * 4;
#pragma unroll
            for (int ni = 0; ni < 4; ni++) {
                const int gn = bn + wc * 64 + ni * 16 + lane15;
#pragma unroll
                for (int r = 0; r < 4; r++)
                    po[(size_t)(gmb + r) * N + gn] = acc[mi][ni][r];
            }
        }
        return;
    }
#pragma unroll
    for (int mi = 0; mi < 4; mi++) {
        const int gmb = bm + wr * 64 + mi * 16 + quad * 4;
#pragma unroll
        for (int ni = 0; ni < 4; ni++) {
            const int gn = bn + wc * 64 + ni * 16 + lane15;
            const float bv = bias[gn];
#pragma unroll
            for (int r = 0; r < 4; r++) {
                float v = acc[mi][ni][r] + bv;
                if (flags & FLAG_GELU) v = gelu_exact(v);
                const size_t off = (size_t)(gmb + r) * N + gn;
                if (flags & FLAG_RES) v += resid[off];
                if (flags & FLAG_W32) out32[off] = v;
                if (flags & FLAG_W16) out16[off] = (_Float16)v;
            }
        }
    }
}

// ---------------------------------------------------------------------------
// Split-K reduce: out[i] = gelu(bias[i%N] + sum_z part[z*MN + i]) as f16.
// ---------------------------------------------------------------------------
__global__ __launch_bounds__(256) void skred_k(
    const float* __restrict__ part, const float* __restrict__ bias,
    _Float16* __restrict__ out, int MN, int N, int S)
{
    const int i = blockIdx.x * 256 + threadIdx.x;
    if (i >= MN) return;
    float s = bias[i % N];
    for (int z = 0; z < S; z++) s += part[(size_t)z * MN + i];
    out[i] = (_Float16)gelu_exact(s);
}

// ---------------------------------------------------------------------------
// Fused split-K reduce (S=4, N=128) + gelu + final (128x3) matmul + bias.
// ---------------------------------------------------------------------------
__global__ __launch_bounds__(256) void skcls_k(
    const float* __restrict__ part, const float* __restrict__ b2,
    const float* __restrict__ w3, const float* __restrict__ b3,
    float* __restrict__ out, int CH)
{
    const int wid = threadIdx.x >> 6, lane = threadIdx.x & 63;
    const int b = blockIdx.x * 4 + wid;
    const size_t MN = (size_t)CH * 128;
    const int c0 = lane, c1 = lane + 64;
    float s0 = b2[c0], s1 = b2[c1];
#pragma unroll
    for (int z = 0; z < 4; z++) {
        s0 += part[z * MN + (size_t)b * 128 + c0];
        s1 += part[z * MN + (size_t)b * 128 + c1];
    }
    const float g0 = gelu_exact(s0), g1 = gelu_exact(s1);
    float a0 = g0 * w3[c0 * 3 + 0] + g1 * w3[c1 * 3 + 0];
    float a1 = g0 * w3[c0 * 3 + 1] + g1 * w3[c1 * 3 + 1];
    float a2 = g0 * w3[c0 * 3 + 2] + g1 * w3[c1 * 3 + 2];
#pragma unroll
    for (int m = 32; m >= 1; m >>= 1) {
        a0 += __shfl_xor(a0, m, 64);
        a1 += __shfl_xor(a1, m, 64);
        a2 += __shfl_xor(a2, m, 64);
    }
    if (lane == 0) {
        out[b * 3 + 0] = a0 + b3[0];
        out[b * 3 + 1] = a1 + b3[1];
        out[b * 3 + 2] = a2 + b3[2];
    }
}

// ---------------------------------------------------------------------------
// Row LayerNorm over 512 cols: fp32 in, fp32 params, f16 out. One wave/row.
// ---------------------------------------------------------------------------
__global__ __launch_bounds__(256) void ln_rows(
    const float* __restrict__ x, const float* __restrict__ w,
    const float* __restrict__ b, _Float16* __restrict__ out)
{
    const int wid = threadIdx.x >> 6, lane = threadIdx.x & 63;
    const size_t row = (size_t)blockIdx.x * 4 + wid;
    const int c0 = lane * 8;
    const float* xr = x + row * 512 + c0;
    float4 v0 = *(const float4*)xr;
    float4 v1 = *(const float4*)(xr + 4);
    float xv[8] = {v0.x, v0.y, v0.z, v0.w, v1.x, v1.y, v1.z, v1.w};
    float s = 0.f, q = 0.f;
#pragma unroll
    for (int j = 0; j < 8; j++) { s += xv[j]; q += xv[j] * xv[j]; }
#pragma unroll
    for (int m = 32; m >= 1; m >>= 1) {
        s += __shfl_xor(s, m, 64);
        q += __shfl_xor(q, m, 64);
    }
    const float mean = s * (1.f / 512.f);
    const float rstd = rsqrtf(q * (1.f / 512.f) - mean * mean + 1e-5f);
    half8 o;
#pragma unroll
    for (int j = 0; j < 8; j++)
        o[j] = (_Float16)((xv[j] - mean) * rstd * w[c0 + j] + b[c0 + j]);
    *(half8*)&out[row * 512 + c0] = o;
}

// ---------------------------------------------------------------------------
// Attention via MFMA: 4 (b,head) units per 256-thr block, one wave each.
// (r7: verified, replaced serial-VALU version)
// ---------------------------------------------------------------------------
__global__ __launch_bounds__(256) void attn_k(
    const _Float16* __restrict__ qkv, _Float16* __restrict__ o)
{
    __shared__ float patt[4][16][17];
    const int wid = threadIdx.x >> 6, lane = threadIdx.x & 63;
    const int unit = blockIdx.x * 4 + wid;
    const int b = unit >> 3, hd = unit & 7;
    const int lane15 = lane & 15, quad = lane >> 4;
    const _Float16* base = qkv + (size_t)b * 18432 + hd * 64;

    const int rq = lane15 < 12 ? lane15 : 11;
    const _Float16* qrow = base + (size_t)rq * 1536;
    half8 qa0 = *(const half8*)(qrow + quad * 8);
    half8 qa1 = *(const half8*)(qrow + 32 + quad * 8);
    half8 kb0 = *(const half8*)(qrow + 512 + quad * 8);
    half8 kb1 = *(const half8*)(qrow + 544 + quad * 8);
    floatx4 s = floatx4{0.f, 0.f, 0.f, 0.f};
    s = __builtin_amdgcn_mfma_f32_16x16x32_f16(qa0, kb0, s, 0, 0, 0);
    s = __builtin_amdgcn_mfma_f32_16x16x32_f16(qa1, kb1, s, 0, 0, 0);

    const bool kok = lane15 < 12;
    float p[4];
#pragma unroll
    for (int r = 0; r < 4; r++) {
        const float sv = s[r] * 0.125f;
        float mx = kok ? sv : -1e30f;
#pragma unroll
        for (int m = 1; m <= 8; m <<= 1)
            mx = fmaxf(mx, __shfl_xor(mx, m, 64));
        const float ev = kok ? __expf(sv - mx) : 0.f;
        float ss = ev;
#pragma unroll
        for (int m = 1; m <= 8; m <<= 1)
            ss += __shfl_xor(ss, m, 64);
        p[r] = ev * __builtin_amdgcn_rcpf(ss);
    }
#pragma unroll
    for (int r = 0; r < 4; r++)
        patt[wid][quad * 4 + r][lane15] = p[r];

    half8 pa;
#pragma unroll
    for (int j = 0; j < 8; j++) {
        const int kj = quad * 8 + j;
        pa[j] = (quad < 2) ? (_Float16)patt[wid][lane15][kj & 15]
                           : (_Float16)0.f;
    }

    const _Float16* vbase = base + 1024;
    floatx4 oacc[4];
#pragma unroll
    for (int ni = 0; ni < 4; ni++) {
        half8 vb;
#pragma unroll
        for (int j = 0; j < 8; j++) {
            int kv = quad * 8 + j;
            if (kv > 11) kv = 11;
            vb[j] = vbase[(size_t)kv * 1536 + ni * 16 + lane15];
        }
        oacc[ni] = __builtin_amdgcn_mfma_f32_16x16x32_f16(
            pa, vb, floatx4{0.f, 0.f, 0.f, 0.f}, 0, 0, 0);
    }
    _Float16* ob = o + (size_t)b * 6144 + hd * 64;
#pragma unroll
    for (int r = 0; r < 4; r++) {
        const int qi = quad * 4 + r;
        if (qi < 12) {
#pragma unroll
            for (int ni = 0; ni < 4; ni++)
                ob[(size_t)qi * 512 + ni * 16 + lane15] = (_Float16)oacc[ni][r];
        }
    }
}

// ---------------------------------------------------------------------------
// t-PARALLEL factors + time-norm -> (CH*12, 96) f16 patch rows.
// r7 diagnosis: thread-per-row version had 0.35% occupancy / 1.7% VALUBusy
// (2048 threads total, serial 96-step scans, ~94 us). Now: one thread per
// (row, t) -> 384-thr blocks (4 rows x 96 t), grid CH/4 = 96x the waves.
// The 4 EMA recurrences (e12, e26, avg_gain, avg_loss) are affine maps
// e_t = m*e_{t-1} + b_t, computed EXACTLY via Hillis-Steele scan over
// affine composition (t=0 element is the constant map (0, init)).
// Rolling 20-window sums: direct 20-tap loop (conflict-free LDS).
// Per-feature time-stats: 11 threads/row serial-reduce (hidden by TLP).
// ---------------------------------------------------------------------------
__global__ __launch_bounds__(384) void factors_k(
    const float* __restrict__ x, const float* __restrict__ in_w,
    const float* __restrict__ in_b, _Float16* __restrict__ feats, int CH)
{
    __shared__ __align__(16) float cls[4][96];
    __shared__ __align__(16) float vls[4][96];
    __shared__ __align__(16) float scratch[4224];  // scans (3072) / fv (4224)
    __shared__ float sstat[4][11][2];

    const int rt = threadIdx.x;            // 0..383
    const int row = rt / 96;
    const int t = rt - row * 96;
    const int b = blockIdx.x * 4 + row;    // CH is a multiple of 4

    const float a12 = 2.f / 13.f, a26 = 2.f / 27.f, a14 = 1.f / 14.f;

    // load + stage
    const float* xq = x + ((size_t)b * 96 + t) * 5;
    const float f0 = xq[0], f1 = xq[1], f2 = xq[2], c = xq[3], v = xq[4];
    cls[row][t] = c;
    vls[row][t] = v;
    __syncthreads();

    // elementwise neighbors
    const float cp = t > 0 ? cls[row][t - 1] : 0.f;
    const float vpr = t > 0 ? vls[row][t - 1] : 0.f;
    const float sv = v > 0.f ? v : 1.f;
    const float delta = t > 0 ? c - cp : 0.f;
    const float gain = fmaxf(delta, 0.f), loss = fmaxf(-delta, 0.f);
    float lr = 0.f, lv = 0.f;
    if (t > 0) {
        lr = logf(fmaxf(c, 1e-8f) / fmaxf(cp, 1e-8f));
        const float svp = vpr > 0.f ? vpr : 1.f;
        lv = logf(sv / (svp + 1e-8f));
    }

    // EMA scans: element = affine map (m, bb); t=0 is the constant (0, init)
    float* sm = scratch;          // [scan*384 + row*96 + t]
    float* sb = scratch + 1536;
    const int i0 = row * 96 + t;
    sm[0 * 384 + i0] = t ? (1.f - a12) : 0.f;  sb[0 * 384 + i0] = t ? a12 * c : c;
    sm[1 * 384 + i0] = t ? (1.f - a26) : 0.f;  sb[1 * 384 + i0] = t ? a26 * c : c;
    sm[2 * 384 + i0] = t ? (1.f - a14) : 0.f;  sb[2 * 384 + i0] = t ? a14 * gain : 0.f;
    sm[3 * 384 + i0] = t ? (1.f - a14) : 0.f;  sb[3 * 384 + i0] = t ? a14 * loss : 0.f;
    __syncthreads();
#pragma unroll
    for (int s = 1; s < 96; s <<= 1) {
        float pm[4], pb[4];
        const bool act = (t >= s);
        if (act) {
            const int ip = i0 - s;
#pragma unroll
            for (int sc = 0; sc < 4; sc++) {
                pm[sc] = sm[sc * 384 + ip];
                pb[sc] = sb[sc * 384 + ip];
            }
        }
        __syncthreads();
        if (act) {
#pragma unroll
            for (int sc = 0; sc < 4; sc++) {
                const float m2 = sm[sc * 384 + i0];
                const float b2 = sb[sc * 384 + i0];
                sm[sc * 384 + i0] = pm[sc] * m2;
                sb[sc * 384 + i0] = fmaf(m2, pb[sc], b2);
            }
        }
        __syncthreads();
    }
    const float e12 = sb[0 * 384 + i0];
    const float e26 = sb[1 * 384 + i0];
    const float ag  = sb[2 * 384 + i0];
    const float al  = sb[3 * 384 + i0];

    const float macd = e12 - e26;
    const float rs = ag / (al + 1e-10f);
    const float rsi = (100.f - 100.f / (1.f + rs)) * 0.01f;

    // rolling 20-window (bollinger + vol-mean-ratio)
    float bb = 0.f, vmr = 1.f;
    if (t >= 19) {
        float s1c = 0.f, s2c = 0.f, s1v = 0.f;
#pragma unroll
        for (int k = 0; k < 20; k++) {
            const float cc = cls[row][t - k];
            const float vv = vls[row][t - k];
            s1c += cc; s2c += cc * cc; s1v += vv > 0.f ? vv : 1.f;
        }
        const float mean = s1c * 0.05f;
        const float sq = s2c * 0.05f;
        const float sd = sqrtf(fmaxf(sq - mean * mean, 0.f));
        bb = 4.f * sd / (mean + 1e-8f);
        vmr = sv / (s1v * 0.05f + 1e-8f);
    }

    float fvv[11];
    fvv[0] = f0; fvv[1] = f1; fvv[2] = f2; fvv[3] = c; fvv[4] = v;
    fvv[5] = isfinite(macd) ? macd : 0.f;
    fvv[6] = isfinite(rsi) ? rsi : 0.f;
    fvv[7] = isfinite(bb) ? bb : 0.f;
    fvv[8] = isfinite(lr) ? lr : 0.f;
    fvv[9] = isfinite(lv) ? lv : 0.f;
    fvv[10] = isfinite(vmr) ? vmr : 0.f;

    __syncthreads();               // scans dead -> reuse scratch as fv
    float* fv = scratch;           // [(row*11 + f)*96 + t]
#pragma unroll
    for (int f = 0; f < 11; f++)
        fv[(row * 11 + f) * 96 + t] = fvv[f];
    __syncthreads();

    // per-(row,feature) time stats
    if (t < 11) {
        const float* p = &fv[(row * 11 + t) * 96];
        float s = 0.f, q = 0.f;
        for (int k = 0; k < 96; k++) { const float u = p[k]; s += u; q += u * u; }
        const float m = s * (1.f / 96.f);
        const float var = q * (1.f / 96.f) - m * m;
        const float r = rsqrtf(var + 1e-5f);
        const float sc = r * in_w[t];
        sstat[row][t][0] = sc;
        sstat[row][t][1] = in_b[t] - m * sc;
    }
    __syncthreads();

    // normalized f16 patch-row output + zero pad cols 88..95
    _Float16* orow = feats + (size_t)b * 1152 + (t >> 3) * 96;
    _Float16* op = orow + (t & 7) * 11;
#pragma unroll
    for (int f = 0; f < 11; f++)
        op[f] = (_Float16)(fv[(row * 11 + f) * 96 + t] * sstat[row][f][0] +
                           sstat[row][f][1]);
    if ((t & 7) == 0) {
        const int4 z4 = {0, 0, 0, 0};
        *(int4*)(orow + 88) = z4;
    }
}

// ---------------------------------------------------------------------------
// Tiled transpose + cast, z-batched: W (K x N) fp32 -> Wt (N x Kpad) f16.
// ---------------------------------------------------------------------------
__global__ __launch_bounds__(256) void tr_k(
    const float* __restrict__ W, _Float16* __restrict__ Wt,
    int K, int N, int Kpad, long long ss, long long ds)
{
    W  += (size_t)blockIdx.z * ss;
    Wt += (size_t)blockIdx.z * ds;
    __shared__ _Float16 t[32][33];
    const int n0 = blockIdx.x * 32, k0 = blockIdx.y * 32;
#pragma unroll
    for (int j = 0; j < 4; j++) {
        const int k = k0 + threadIdx.y + j * 8;
        t[threadIdx.y + j * 8][threadIdx.x] =
            (k < K) ? (_Float16)W[(size_t)k * N + n0 + threadIdx.x] : (_Float16)0.f;
    }
    __syncthreads();
#pragma unroll
    for (int j = 0; j < 4; j++) {
        const int n = n0 + threadIdx.y + j * 8;
        Wt[(size_t)n * Kpad + k0 + threadIdx.x] = t[threadIdx.x][threadIdx.y + j * 8];
    }
}

// ---------------------------------------------------------------------------
extern "C" void kernel_launch(void* const* d_in, const int* in_sizes, int n_in,
                              void* d_out, int out_size, void* d_ws, size_t ws_size,
                              hipStream_t stream)
{
    static const int EXP[23] = {1966080, 11, 11, 45056, 512, 2048, 2048,
        3145728, 6144, 1048576, 2048, 2048, 2048, 4194304, 8192, 4194304, 2048,
        3145728, 512, 65536, 128, 384, 3};
    static const int S2D[23] = {18, 20, 22, 17, 19, 21, 2, 1, 6, 5, 12, 11,
        14, 16, 13, 15, 10, 9, 4, 3, 8, 7, 0};
    const void* in[23];
    if (n_in != 23 || out_size != 12288) return;
    bool ok = true;
    for (int i = 0; i < 23; i++) ok = ok && (in_sizes[i] == EXP[i]);
    if (ok) {
        for (int i = 0; i < 23; i++) in[i] = d_in[i];
    } else {
        bool ok2 = true;
        for (int s = 0; s < 23; s++) ok2 = ok2 && (in_sizes[s] == EXP[S2D[s]]);
        if (!ok2) return;
        for (int s = 0; s < 23; s++) in[S2D[s]] = d_in[s];
    }
    const float* x      = (const float*)in[0];
    const float* in_w   = (const float*)in[1];
    const float* in_b   = (const float*)in[2];
    const float* pe_w   = (const float*)in[3];
    const float* pe_b   = (const float*)in[4];
    const float* ln1_w  = (const float*)in[5];
    const float* ln1_b  = (const float*)in[6];
    const float* qkv_w  = (const float*)in[7];
    const float* qkv_b  = (const float*)in[8];
    const float* out_w  = (const float*)in[9];
    const float* out_b  = (const float*)in[10];
    const float* ln2_w  = (const float*)in[11];
    const float* ln2_b  = (const float*)in[12];
    const float* mlp_w1 = (const float*)in[13];
    const float* mlp_b1 = (const float*)in[14];
    const float* mlp_w2 = (const float*)in[15];
    const float* mlp_b2 = (const float*)in[16];
    const float* cls_w1 = (const float*)in[17];
    const float* cls_b1 = (const float*)in[18];
    const float* cls_w2 = (const float*)in[19];
    const float* cls_b2 = (const float*)in[20];
    const float* cls_w3 = (const float*)in[21];
    const float* cls_b3 = (const float*)in[22];

    // ---- f16 weight arena (~31.7 MB) ----
    char* ws = (char*)d_ws;
    size_t off = 0;
    _Float16* wt_pe  = (_Float16*)(ws + off); off += (size_t)512 * 96 * 2;
    _Float16* wt_qkv = (_Float16*)(ws + off); off += (size_t)4 * 1536 * 512 * 2;
    _Float16* wt_out = (_Float16*)(ws + off); off += (size_t)4 * 512 * 512 * 2;
    _Float16* wt_m1  = (_Float16*)(ws + off); off += (size_t)4 * 2048 * 512 * 2;
    _Float16* wt_m2  = (_Float16*)(ws + off); off += (size_t)4 * 512 * 2048 * 2;
    _Float16* wt_c1  = (_Float16*)(ws + off); off += (size_t)512 * 6144 * 2;
    _Float16* wt_c2  = (_Float16*)(ws + off); off += (size_t)128 * 512 * 2;
    const size_t wbytes = off;

    // per-batch bytes = h32 24576 + abuf 12288 + bbuf 49152
    const size_t per = 86016 + 64;
    int CH = 2048;
    while (CH > 128 && wbytes + (size_t)CH * per > ws_size) CH >>= 1;
    const int nch = 4096 / CH;
    const int M = CH * 12;

    float*    h32  = (float*)(ws + off);    off += (size_t)M * 512 * 4;
    _Float16* abuf = (_Float16*)(ws + off); off += (size_t)M * 512 * 2;
    _Float16* bbuf = (_Float16*)(ws + off); off += (size_t)M * 2048 * 2;

    _Float16* feats = bbuf;                 // dead after pe GEMM
    _Float16* f1 = (_Float16*)h32;          // classifier temp (h32 dead then)
    float* part1 = (float*)bbuf;                          // 8*CH*512 fp32
    float* part2 = part1 + (size_t)8 * CH * 512;          // 4*CH*128 fp32

    // ---- weight prep: fp32 (K,N) -> f16 (N,Kpad) transposed, z-batched ----
    tr_k<<<dim3(16, 3, 1),   dim3(32, 8), 0, stream>>>(pe_w, wt_pe, 88, 512, 96, 0, 0);
    tr_k<<<dim3(48, 16, 4),  dim3(32, 8), 0, stream>>>(qkv_w, wt_qkv, 512, 1536, 512,
        (long long)512 * 1536, (long long)1536 * 512);
    tr_k<<<dim3(16, 16, 4),  dim3(32, 8), 0, stream>>>(out_w, wt_out, 512, 512, 512,
        (long long)512 * 512, (long long)512 * 512);
    tr_k<<<dim3(64, 16, 4),  dim3(32, 8), 0, stream>>>(mlp_w1, wt_m1, 512, 2048, 512,
        (long long)512 * 2048, (long long)2048 * 512);
    tr_k<<<dim3(16, 64, 4),  dim3(32, 8), 0, stream>>>(mlp_w2, wt_m2, 2048, 512, 2048,
        (long long)2048 * 512, (long long)512 * 2048);
    tr_k<<<dim3(16, 192, 1), dim3(32, 8), 0, stream>>>(cls_w1, wt_c1, 6144, 512, 6144, 0, 0);
    tr_k<<<dim3(4, 16, 1),   dim3(32, 8), 0, stream>>>(cls_w2, wt_c2, 512, 128, 512, 0, 0);

    for (int c = 0; c < nch; c++) {
        const float* xc = x + (size_t)c * CH * 480;
        factors_k<<<CH / 4, 384, 0, stream>>>(xc, in_w, in_b, feats, CH);
        gemm_f16g<<<dim3(4, M / 128), 256, 0, stream>>>(
            feats, wt_pe, pe_b, nullptr, h32, nullptr, M, 512, 96, 96, FLAG_W32);

        for (int i = 0; i < 4; i++) {
            ln_rows<<<M / 4, 256, 0, stream>>>(h32, ln1_w + i * 512, ln1_b + i * 512, abuf);
            gemm_f16g<<<dim3(12, M / 128), 256, 0, stream>>>(
                abuf, wt_qkv + (size_t)i * 1536 * 512, qkv_b + i * 1536,
                nullptr, nullptr, bbuf, M, 1536, 512, 512, FLAG_W16);
            attn_k<<<CH * 2, 256, 0, stream>>>(bbuf, abuf);
            gemm_f16g<<<dim3(4, M / 128), 256, 0, stream>>>(
                abuf, wt_out + (size_t)i * 512 * 512, out_b + i * 512,
                h32, h32, nullptr, M, 512, 512, 512, FLAG_RES | FLAG_W32);
            ln_rows<<<M / 4, 256, 0, stream>>>(h32, ln2_w + i * 512, ln2_b + i * 512, abuf);
            // mlp1: reg-staged variant (measured 100us vs 128us gload, r3/r5)
            gemm_f16<<<dim3(16, M / 128), 256, 0, stream>>>(
                abuf, wt_m1 + (size_t)i * 2048 * 512, mlp_b1 + i * 2048,
                nullptr, nullptr, bbuf, M, 2048, 512, 512, FLAG_W16 | FLAG_GELU);
            // at i==3 the fp32 residual stream is dead afterwards
            const int fl = FLAG_RES | (i == 3 ? FLAG_W16 : FLAG_W32);
            gemm_f16g<<<dim3(4, M / 128), 256, 0, stream>>>(
                bbuf, wt_m2 + (size_t)i * 512 * 2048, mlp_b2 + i * 512,
                h32, h32, abuf, M, 512, 2048, 2048, fl);
        }

        // classifier: abuf viewed as (CH, 6144) f16; split-K via fp32 partials
        gemm_f16g<<<dim3(4, CH / 128, 8), 256, 0, stream>>>(
            abuf, wt_c1, nullptr, nullptr, part1, nullptr, CH, 512, 6144, 768, FLAG_PART);
        skred_k<<<(CH * 512 + 255) / 256, 256, 0, stream>>>(
            part1, cls_b1, f1, CH * 512, 512, 8);
        gemm_f16g<<<dim3(1, CH / 128, 4), 256, 0, stream>>>(
            f1, wt_c2, nullptr, nullptr, part2, nullptr, CH, 128, 512, 128, FLAG_PART);
        skcls_k<<<CH / 4, 256, 0, stream>>>(
            part2, cls_b2, cls_w3, cls_b3, (float*)d_out + (size_t)c * CH * 3, CH);
    }
}

// Round 9
// 2666.650 us; speedup vs baseline: 1.4782x; 1.0380x over previous
//
#include <hip/hip_runtime.h>
#include <cstdint>
#include <cstddef>

typedef _Float16 half8 __attribute__((ext_vector_type(8)));
typedef _Float16 half4v __attribute__((ext_vector_type(4)));
typedef float floatx4 __attribute__((ext_vector_type(4)));

#define FLAG_RES  1
#define FLAG_GELU 2
#define FLAG_W32  4
#define FLAG_W16  8
#define FLAG_PART 16

// Fast exact-GELU: erf via Abramowitz-Stegun 7.1.25 (3-term, |err|<=2.5e-5,
// well under f16 ulp; output absmax sits at the f16-rounding floor).
__device__ __forceinline__ float gelu_exact(float x) {
    const float z = fabsf(x) * 0.70710678118654752f;
    const float t = __builtin_amdgcn_rcpf(fmaf(0.47047f, z, 1.f));
    const float p = t * (0.3480242f + t * (-0.0958798f + t * 0.7478556f));
    const float erfa = 1.f - p * __expf(-z * z);
    return 0.5f * x * (1.f + copysignf(erfa, x));
}

// async global->LDS (16B/lane): dest is wave-uniform base + lane*16.
typedef const __attribute__((address_space(1))) void GV;
typedef __attribute__((address_space(3))) void LV;
__device__ __forceinline__ void gl_lds16(const void* g, void* l) {
    __builtin_amdgcn_global_load_lds((GV*)g, (LV*)l, 16, 0, 0);
}

// XCD-aware chunked block swizzle (bijective when nwg % 8 == 0; identity
// otherwise). Verified r6: mlp1 FETCH_SIZE 101.5 -> 37 MB.
__device__ __forceinline__ void swz_bid(int& bx, int& by) {
    const int gx = gridDim.x;
    const int nwg = gx * gridDim.y;
    int id = blockIdx.y * gx + blockIdx.x;
    if ((nwg & 7) == 0) {
        const int q = nwg >> 3;
        id = (id & 7) * q + (id >> 3);
    }
    bx = id % gx;
    by = id / gx;
}

// Shared C^T epilogue (r9): MFMA called as mfma(bf, af, acc) so the D
// fragment holds, per lane, ONE M-row (lane15) x 4 CONSECUTIVE N-cols
// (quad*4 + r). 64 scalar stores -> 16 vector stores; resid/bias become
// float4 loads. Layout rule is the session-verified "D row = first
// operand's lane15 dim".
__device__ __forceinline__ void gemm_epilogue(
    floatx4 acc[4][4], const float* bias, const float* resid,
    float* out32, _Float16* out16, int M, int N,
    int bm, int bn, int wr, int wc, int lane15, int quad, int zslice,
    int flags)
{
    if (flags & FLAG_PART) {
        float* po = out32 + (size_t)zslice * ((size_t)M * N);
#pragma unroll
        for (int mi = 0; mi < 4; mi++) {
            const int gm = bm + wr * 64 + mi * 16 + lane15;
            float* pr = po + (size_t)gm * N + bn + wc * 64 + quad * 4;
#pragma unroll
            for (int ni = 0; ni < 4; ni++) {
                float4 v = {acc[mi][ni][0], acc[mi][ni][1],
                            acc[mi][ni][2], acc[mi][ni][3]};
                *(float4*)(pr + ni * 16) = v;
            }
        }
        return;
    }
    const int cn = bn + wc * 64 + quad * 4;
#pragma unroll
    for (int mi = 0; mi < 4; mi++) {
        const int gm = bm + wr * 64 + mi * 16 + lane15;
        const size_t rowoff = (size_t)gm * N + cn;
#pragma unroll
        for (int ni = 0; ni < 4; ni++) {
            const size_t off = rowoff + ni * 16;
            const float4 bv = *(const float4*)&bias[cn + ni * 16];
            float v[4] = {acc[mi][ni][0] + bv.x, acc[mi][ni][1] + bv.y,
                          acc[mi][ni][2] + bv.z, acc[mi][ni][3] + bv.w};
            if (flags & FLAG_GELU) {
#pragma unroll
                for (int r = 0; r < 4; r++) v[r] = gelu_exact(v[r]);
            }
            if (flags & FLAG_RES) {
                const float4 rv = *(const float4*)&resid[off];
                v[0] += rv.x; v[1] += rv.y; v[2] += rv.z; v[3] += rv.w;
            }
            if (flags & FLAG_W32) {
                float4 o = {v[0], v[1], v[2], v[3]};
                *(float4*)&out32[off] = o;
            }
            if (flags & FLAG_W16) {
                half4v h = {(_Float16)v[0], (_Float16)v[1],
                            (_Float16)v[2], (_Float16)v[3]};
                *(half4v*)&out16[off] = h;
            }
        }
    }
}

// ---------------------------------------------------------------------------
// GEMM (reg-staged): C(MxN) = A(MxK f16 rm) @ Bt(NxK f16 rm)^T + bias(fp32)
// 128x128 tile, BK=32, 256 thr. XOR-swizzled LDS (r2: conflicts 6.3M -> 0).
// Best for mlp1 (short K, big grid): 100 vs 128 us gload_lds (r3/r5).
// ---------------------------------------------------------------------------
__global__ __launch_bounds__(256, 2) void gemm_f16(
    const _Float16* __restrict__ A, const _Float16* __restrict__ Bt,
    const float* __restrict__ bias, const float* __restrict__ resid,
    float* __restrict__ out32, _Float16* __restrict__ out16,
    int M, int N, int K, int klen, int flags)
{
    __shared__ __align__(16) _Float16 As[2][128 * 32];
    __shared__ __align__(16) _Float16 Bs[2][128 * 32];
    const int tid = threadIdx.x;
    const int wid = tid >> 6;
    const int lane = tid & 63;
    int bxs, bys;
    swz_bid(bxs, bys);
    const int bm = bys * 128;
    const int bn = bxs * 128;
    const int wr = wid >> 1, wc = wid & 1;
    const int lane15 = lane & 15, quad = lane >> 4;
    const int kb = blockIdx.z * klen;

    floatx4 acc[4][4];
#pragma unroll
    for (int i = 0; i < 4; i++)
#pragma unroll
        for (int j = 0; j < 4; j++)
            acc[i][j] = floatx4{0.f, 0.f, 0.f, 0.f};

    const int r4 = lane >> 2;
    const int ch = lane & 3;
    const _Float16* Ap = A + ((size_t)bm + wid * 32 + r4) * K + kb + ch * 8;
    const _Float16* Bp = Bt + ((size_t)bn + wid * 32 + r4) * K + kb + ch * 8;
    const size_t row16 = (size_t)16 * K;
    const int lw = wid * 1024 + r4 * 32 + ((ch ^ ((r4 >> 1) & 3)) << 3);

    int aoff[4], boff[4];
#pragma unroll
    for (int mi = 0; mi < 4; mi++)
        aoff[mi] = (wr * 64 + mi * 16 + lane15) * 32 +
                   ((quad ^ ((lane15 >> 1) & 3)) << 3);
#pragma unroll
    for (int ni = 0; ni < 4; ni++)
        boff[ni] = (wc * 64 + ni * 16 + lane15) * 32 +
                   ((quad ^ ((lane15 >> 1) & 3)) << 3);

    int4 ra0 = *(const int4*)(Ap);
    int4 ra1 = *(const int4*)(Ap + row16);
    int4 rb0 = *(const int4*)(Bp);
    int4 rb1 = *(const int4*)(Bp + row16);

    const int nk = klen >> 5;
    for (int ik = 0; ik < nk; ik++) {
        _Float16* a_ = &As[ik & 1][0];
        _Float16* b_ = &Bs[ik & 1][0];
        *(int4*)(a_ + lw) = ra0;
        *(int4*)(a_ + lw + 512) = ra1;
        *(int4*)(b_ + lw) = rb0;
        *(int4*)(b_ + lw + 512) = rb1;
        __syncthreads();
        if (ik + 1 < nk) {
            const int ko = (ik + 1) << 5;
            ra0 = *(const int4*)(Ap + ko);
            ra1 = *(const int4*)(Ap + row16 + ko);
            rb0 = *(const int4*)(Bp + ko);
            rb1 = *(const int4*)(Bp + row16 + ko);
        }
        half8 af[4], bf[4];
#pragma unroll
        for (int mi = 0; mi < 4; mi++) af[mi] = *(const half8*)&a_[aoff[mi]];
#pragma unroll
        for (int ni = 0; ni < 4; ni++) bf[ni] = *(const half8*)&b_[boff[ni]];
#pragma unroll
        for (int mi = 0; mi < 4; mi++)
#pragma unroll
            for (int ni = 0; ni < 4; ni++)
                acc[mi][ni] = __builtin_amdgcn_mfma_f32_16x16x32_f16(
                    bf[ni], af[mi], acc[mi][ni], 0, 0, 0);  // C^T operand order
    }

    gemm_epilogue(acc, bias, resid, out32, out16, M, N,
                  bm, bn, wr, wc, lane15, quad, blockIdx.z, flags);
}

// ---------------------------------------------------------------------------
// GEMM (gload_lds-staged): pre-swizzled SOURCE chunk. Best non-mlp1 (r5/r6).
// ---------------------------------------------------------------------------
__global__ __launch_bounds__(256, 3) void gemm_f16g(
    const _Float16* __restrict__ A, const _Float16* __restrict__ Bt,
    const float* __restrict__ bias, const float* __restrict__ resid,
    float* __restrict__ out32, _Float16* __restrict__ out16,
    int M, int N, int K, int klen, int flags)
{
    __shared__ __align__(16) _Float16 As[2][128 * 32];
    __shared__ __align__(16) _Float16 Bs[2][128 * 32];
    const int tid = threadIdx.x;
    const int wid = tid >> 6;
    const int lane = tid & 63;
    int bxs, bys;
    swz_bid(bxs, bys);
    const int bm = bys * 128;
    const int bn = bxs * 128;
    const int wr = wid >> 1, wc = wid & 1;
    const int lane15 = lane & 15, quad = lane >> 4;
    const int kb = blockIdx.z * klen;

    floatx4 acc[4][4];
#pragma unroll
    for (int i = 0; i < 4; i++)
#pragma unroll
        for (int j = 0; j < 4; j++)
            acc[i][j] = floatx4{0.f, 0.f, 0.f, 0.f};

    const int rr = lane >> 2;
    const int ch = lane & 3;
    const int cs = ch ^ ((rr >> 1) & 3);
    const _Float16* asrc0 = A + ((size_t)bm + wid * 32 + rr) * K + kb + cs * 8;
    const _Float16* asrc1 = asrc0 + (size_t)16 * K;
    const _Float16* bsrc0 = Bt + ((size_t)bn + wid * 32 + rr) * K + kb + cs * 8;
    const _Float16* bsrc1 = bsrc0 + (size_t)16 * K;

    int aoff[4], boff[4];
#pragma unroll
    for (int mi = 0; mi < 4; mi++)
        aoff[mi] = (wr * 64 + mi * 16 + lane15) * 32 +
                   ((quad ^ ((lane15 >> 1) & 3)) << 3);
#pragma unroll
    for (int ni = 0; ni < 4; ni++)
        boff[ni] = (wc * 64 + ni * 16 + lane15) * 32 +
                   ((quad ^ ((lane15 >> 1) & 3)) << 3);

    const int nk = klen >> 5;
    {
        _Float16* ab = &As[0][wid * 1024];
        _Float16* bb = &Bs[0][wid * 1024];
        gl_lds16(asrc0, ab);
        gl_lds16(asrc1, ab + 512);
        gl_lds16(bsrc0, bb);
        gl_lds16(bsrc1, bb + 512);
    }
    for (int ik = 0; ik < nk; ik++) {
        __syncthreads();
        if (ik + 1 < nk) {
            const int ko = (ik + 1) << 5;
            _Float16* ab = &As[(ik + 1) & 1][wid * 1024];
            _Float16* bb = &Bs[(ik + 1) & 1][wid * 1024];
            gl_lds16(asrc0 + ko, ab);
            gl_lds16(asrc1 + ko, ab + 512);
            gl_lds16(bsrc0 + ko, bb);
            gl_lds16(bsrc1 + ko, bb + 512);
        }
        const _Float16* a_ = As[ik & 1];
        const _Float16* b_ = Bs[ik & 1];
        half8 af[4], bf[4];
#pragma unroll
        for (int mi = 0; mi < 4; mi++) af[mi] = *(const half8*)&a_[aoff[mi]];
#pragma unroll
        for (int ni = 0; ni < 4; ni++) bf[ni] = *(const half8*)&b_[boff[ni]];
#pragma unroll
        for (int mi = 0; mi < 4; mi++)
#pragma unroll
            for (int ni = 0; ni < 4; ni++)
                acc[mi][ni] = __builtin_amdgcn_mfma_f32_16x16x32_f16(
                    bf[ni], af[mi], acc[mi][ni], 0, 0, 0);  // C^T operand order
    }

    gemm_epilogue(acc, bias, resid, out32, out16, M, N,
                  bm, bn, wr, wc, lane15, quad, blockIdx.z, flags);
}

// ---------------------------------------------------------------------------
// Split-K reduce: out[i] = gelu(bias[i%N] + sum_z part[z*MN + i]) as f16.
// ---------------------------------------------------------------------------
__global__ __launch_bounds__(256) void skred_k(
    const float* __restrict__ part, const float* __restrict__ bias,
    _Float16* __restrict__ out, int MN, int N, int S)
{
    const int i = blockIdx.x * 256 + threadIdx.x;
    if (i >= MN) return;
    float s = bias[i % N];
    for (int z = 0; z < S; z++) s += part[(size_t)z * MN + i];
    out[i] = (_Float16)gelu_exact(s);
}

// ---------------------------------------------------------------------------
// Fused split-K reduce (S=4, N=128) + gelu + final (128x3) matmul + bias.
// ---------------------------------------------------------------------------
__global__ __launch_bounds__(256) void skcls_k(
    const float* __restrict__ part, const float* __restrict__ b2,
    const float* __restrict__ w3, const float* __restrict__ b3,
    float* __restrict__ out, int CH)
{
    const int wid = threadIdx.x >> 6, lane = threadIdx.x & 63;
    const int b = blockIdx.x * 4 + wid;
    const size_t MN = (size_t)CH * 128;
    const int c0 = lane, c1 = lane + 64;
    float s0 = b2[c0], s1 = b2[c1];
#pragma unroll
    for (int z = 0; z < 4; z++) {
        s0 += part[z * MN + (size_t)b * 128 + c0];
        s1 += part[z * MN + (size_t)b * 128 + c1];
    }
    const float g0 = gelu_exact(s0), g1 = gelu_exact(s1);
    float a0 = g0 * w3[c0 * 3 + 0] + g1 * w3[c1 * 3 + 0];
    float a1 = g0 * w3[c0 * 3 + 1] + g1 * w3[c1 * 3 + 1];
    float a2 = g0 * w3[c0 * 3 + 2] + g1 * w3[c1 * 3 + 2];
#pragma unroll
    for (int m = 32; m >= 1; m >>= 1) {
        a0 += __shfl_xor(a0, m, 64);
        a1 += __shfl_xor(a1, m, 64);
        a2 += __shfl_xor(a2, m, 64);
    }
    if (lane == 0) {
        out[b * 3 + 0] = a0 + b3[0];
        out[b * 3 + 1] = a1 + b3[1];
        out[b * 3 + 2] = a2 + b3[2];
    }
}

// ---------------------------------------------------------------------------
// Row LayerNorm over 512 cols: fp32 in, fp32 params, f16 out. One wave/row.
// ---------------------------------------------------------------------------
__global__ __launch_bounds__(256) void ln_rows(
    const float* __restrict__ x, const float* __restrict__ w,
    const float* __restrict__ b, _Float16* __restrict__ out)
{
    const int wid = threadIdx.x >> 6, lane = threadIdx.x & 63;
    const size_t row = (size_t)blockIdx.x * 4 + wid;
    const int c0 = lane * 8;
    const float* xr = x + row * 512 + c0;
    float4 v0 = *(const float4*)xr;
    float4 v1 = *(const float4*)(xr + 4);
    float xv[8] = {v0.x, v0.y, v0.z, v0.w, v1.x, v1.y, v1.z, v1.w};
    float s = 0.f, q = 0.f;
#pragma unroll
    for (int j = 0; j < 8; j++) { s += xv[j]; q += xv[j] * xv[j]; }
#pragma unroll
    for (int m = 32; m >= 1; m >>= 1) {
        s += __shfl_xor(s, m, 64);
        q += __shfl_xor(q, m, 64);
    }
    const float mean = s * (1.f / 512.f);
    const float rstd = rsqrtf(q * (1.f / 512.f) - mean * mean + 1e-5f);
    half8 o;
#pragma unroll
    for (int j = 0; j < 8; j++)
        o[j] = (_Float16)((xv[j] - mean) * rstd * w[c0 + j] + b[c0 + j]);
    *(half8*)&out[row * 512 + c0] = o;
}

// ---------------------------------------------------------------------------
// Attention via MFMA: 4 (b,head) units per 256-thr block, one wave each.
// (r7: verified, replaced serial-VALU version)
// ---------------------------------------------------------------------------
__global__ __launch_bounds__(256) void attn_k(
    const _Float16* __restrict__ qkv, _Float16* __restrict__ o)
{
    __shared__ float patt[4][16][17];
    const int wid = threadIdx.x >> 6, lane = threadIdx.x & 63;
    const int unit = blockIdx.x * 4 + wid;
    const int b = unit >> 3, hd = unit & 7;
    const int lane15 = lane & 15, quad = lane >> 4;
    const _Float16* base = qkv + (size_t)b * 18432 + hd * 64;

    const int rq = lane15 < 12 ? lane15 : 11;
    const _Float16* qrow = base + (size_t)rq * 1536;
    half8 qa0 = *(const half8*)(qrow + quad * 8);
    half8 qa1 = *(const half8*)(qrow + 32 + quad * 8);
    half8 kb0 = *(const half8*)(qrow + 512 + quad * 8);
    half8 kb1 = *(const half8*)(qrow + 544 + quad * 8);
    floatx4 s = floatx4{0.f, 0.f, 0.f, 0.f};
    s = __builtin_amdgcn_mfma_f32_16x16x32_f16(qa0, kb0, s, 0, 0, 0);
    s = __builtin_amdgcn_mfma_f32_16x16x32_f16(qa1, kb1, s, 0, 0, 0);

    const bool kok = lane15 < 12;
    float p[4];
#pragma unroll
    for (int r = 0; r < 4; r++) {
        const float sv = s[r] * 0.125f;
        float mx = kok ? sv : -1e30f;
#pragma unroll
        for (int m = 1; m <= 8; m <<= 1)
            mx = fmaxf(mx, __shfl_xor(mx, m, 64));
        const float ev = kok ? __expf(sv - mx) : 0.f;
        float ss = ev;
#pragma unroll
        for (int m = 1; m <= 8; m <<= 1)
            ss += __shfl_xor(ss, m, 64);
        p[r] = ev * __builtin_amdgcn_rcpf(ss);
    }
#pragma unroll
    for (int r = 0; r < 4; r++)
        patt[wid][quad * 4 + r][lane15] = p[r];

    half8 pa;
#pragma unroll
    for (int j = 0; j < 8; j++) {
        const int kj = quad * 8 + j;
        pa[j] = (quad < 2) ? (_Float16)patt[wid][lane15][kj & 15]
                           : (_Float16)0.f;
    }

    const _Float16* vbase = base + 1024;
    floatx4 oacc[4];
#pragma unroll
    for (int ni = 0; ni < 4; ni++) {
        half8 vb;
#pragma unroll
        for (int j = 0; j < 8; j++) {
            int kv = quad * 8 + j;
            if (kv > 11) kv = 11;
            vb[j] = vbase[(size_t)kv * 1536 + ni * 16 + lane15];
        }
        oacc[ni] = __builtin_amdgcn_mfma_f32_16x16x32_f16(
            pa, vb, floatx4{0.f, 0.f, 0.f, 0.f}, 0, 0, 0);
    }
    _Float16* ob = o + (size_t)b * 6144 + hd * 64;
#pragma unroll
    for (int r = 0; r < 4; r++) {
        const int qi = quad * 4 + r;
        if (qi < 12) {
#pragma unroll
            for (int ni = 0; ni < 4; ni++)
                ob[(size_t)qi * 512 + ni * 16 + lane15] = (_Float16)oacc[ni][r];
        }
    }
}

// ---------------------------------------------------------------------------
// t-PARALLEL factors + time-norm -> (CH*12, 96) f16 patch rows. (r8 verified:
// 94us -> out of top-5; Hillis-Steele affine scan for the 4 EMA recurrences)
// ---------------------------------------------------------------------------
__global__ __launch_bounds__(384) void factors_k(
    const float* __restrict__ x, const float* __restrict__ in_w,
    const float* __restrict__ in_b, _Float16* __restrict__ feats, int CH)
{
    __shared__ __align__(16) float cls[4][96];
    __shared__ __align__(16) float vls[4][96];
    __shared__ __align__(16) float scratch[4224];
    __shared__ float sstat[4][11][2];

    const int rt = threadIdx.x;
    const int row = rt / 96;
    const int t = rt - row * 96;
    const int b = blockIdx.x * 4 + row;

    const float a12 = 2.f / 13.f, a26 = 2.f / 27.f, a14 = 1.f / 14.f;

    const float* xq = x + ((size_t)b * 96 + t) * 5;
    const float f0 = xq[0], f1 = xq[1], f2 = xq[2], c = xq[3], v = xq[4];
    cls[row][t] = c;
    vls[row][t] = v;
    __syncthreads();

    const float cp = t > 0 ? cls[row][t - 1] : 0.f;
    const float vpr = t > 0 ? vls[row][t - 1] : 0.f;
    const float sv = v > 0.f ? v : 1.f;
    const float delta = t > 0 ? c - cp : 0.f;
    const float gain = fmaxf(delta, 0.f), loss = fmaxf(-delta, 0.f);
    float lr = 0.f, lv = 0.f;
    if (t > 0) {
        lr = logf(fmaxf(c, 1e-8f) / fmaxf(cp, 1e-8f));
        const float svp = vpr > 0.f ? vpr : 1.f;
        lv = logf(sv / (svp + 1e-8f));
    }

    float* sm = scratch;
    float* sb = scratch + 1536;
    const int i0 = row * 96 + t;
    sm[0 * 384 + i0] = t ? (1.f - a12) : 0.f;  sb[0 * 384 + i0] = t ? a12 * c : c;
    sm[1 * 384 + i0] = t ? (1.f - a26) : 0.f;  sb[1 * 384 + i0] = t ? a26 * c : c;
    sm[2 * 384 + i0] = t ? (1.f - a14) : 0.f;  sb[2 * 384 + i0] = t ? a14 * gain : 0.f;
    sm[3 * 384 + i0] = t ? (1.f - a14) : 0.f;  sb[3 * 384 + i0] = t ? a14 * loss : 0.f;
    __syncthreads();
#pragma unroll
    for (int s = 1; s < 96; s <<= 1) {
        float pm[4], pb[4];
        const bool act = (t >= s);
        if (act) {
            const int ip = i0 - s;
#pragma unroll
            for (int sc = 0; sc < 4; sc++) {
                pm[sc] = sm[sc * 384 + ip];
                pb[sc] = sb[sc * 384 + ip];
            }
        }
        __syncthreads();
        if (act) {
#pragma unroll
            for (int sc = 0; sc < 4; sc++) {
                const float m2 = sm[sc * 384 + i0];
                const float b2 = sb[sc * 384 + i0];
                sm[sc * 384 + i0] = pm[sc] * m2;
                sb[sc * 384 + i0] = fmaf(m2, pb[sc], b2);
            }
        }
        __syncthreads();
    }
    const float e12 = sb[0 * 384 + i0];
    const float e26 = sb[1 * 384 + i0];
    const float ag  = sb[2 * 384 + i0];
    const float al  = sb[3 * 384 + i0];

    const float macd = e12 - e26;
    const float rs = ag / (al + 1e-10f);
    const float rsi = (100.f - 100.f / (1.f + rs)) * 0.01f;

    float bb = 0.f, vmr = 1.f;
    if (t >= 19) {
        float s1c = 0.f, s2c = 0.f, s1v = 0.f;
#pragma unroll
        for (int k = 0; k < 20; k++) {
            const float cc = cls[row][t - k];
            const float vv = vls[row][t - k];
            s1c += cc; s2c += cc * cc; s1v += vv > 0.f ? vv : 1.f;
        }
        const float mean = s1c * 0.05f;
        const float sq = s2c * 0.05f;
        const float sd = sqrtf(fmaxf(sq - mean * mean, 0.f));
        bb = 4.f * sd / (mean + 1e-8f);
        vmr = sv / (s1v * 0.05f + 1e-8f);
    }

    float fvv[11];
    fvv[0] = f0; fvv[1] = f1; fvv[2] = f2; fvv[3] = c; fvv[4] = v;
    fvv[5] = isfinite(macd) ? macd : 0.f;
    fvv[6] = isfinite(rsi) ? rsi : 0.f;
    fvv[7] = isfinite(bb) ? bb : 0.f;
    fvv[8] = isfinite(lr) ? lr : 0.f;
    fvv[9] = isfinite(lv) ? lv : 0.f;
    fvv[10] = isfinite(vmr) ? vmr : 0.f;

    __syncthreads();
    float* fv = scratch;
#pragma unroll
    for (int f = 0; f < 11; f++)
        fv[(row * 11 + f) * 96 + t] = fvv[f];
    __syncthreads();

    if (t < 11) {
        const float* p = &fv[(row * 11 + t) * 96];
        float s = 0.f, q = 0.f;
        for (int k = 0; k < 96; k++) { const float u = p[k]; s += u; q += u * u; }
        const float m = s * (1.f / 96.f);
        const float var = q * (1.f / 96.f) - m * m;
        const float r = rsqrtf(var + 1e-5f);
        const float sc = r * in_w[t];
        sstat[row][t][0] = sc;
        sstat[row][t][1] = in_b[t] - m * sc;
    }
    __syncthreads();

    _Float16* orow = feats + (size_t)b * 1152 + (t >> 3) * 96;
    _Float16* op = orow + (t & 7) * 11;
#pragma unroll
    for (int f = 0; f < 11; f++)
        op[f] = (_Float16)(fv[(row * 11 + f) * 96 + t] * sstat[row][f][0] +
                           sstat[row][f][1]);
    if ((t & 7) == 0) {
        const int4 z4 = {0, 0, 0, 0};
        *(int4*)(orow + 88) = z4;
    }
}

// ---------------------------------------------------------------------------
// Tiled transpose + cast, z-batched: W (K x N) fp32 -> Wt (N x Kpad) f16.
// ---------------------------------------------------------------------------
__global__ __launch_bounds__(256) void tr_k(
    const float* __restrict__ W, _Float16* __restrict__ Wt,
    int K, int N, int Kpad, long long ss, long long ds)
{
    W  += (size_t)blockIdx.z * ss;
    Wt += (size_t)blockIdx.z * ds;
    __shared__ _Float16 t[32][33];
    const int n0 = blockIdx.x * 32, k0 = blockIdx.y * 32;
#pragma unroll
    for (int j = 0; j < 4; j++) {
        const int k = k0 + threadIdx.y + j * 8;
        t[threadIdx.y + j * 8][threadIdx.x] =
            (k < K) ? (_Float16)W[(size_t)k * N + n0 + threadIdx.x] : (_Float16)0.f;
    }
    __syncthreads();
#pragma unroll
    for (int j = 0; j < 4; j++) {
        const int n = n0 + threadIdx.y + j * 8;
        Wt[(size_t)n * Kpad + k0 + threadIdx.x] = t[threadIdx.x][threadIdx.y + j * 8];
    }
}

// ---------------------------------------------------------------------------
extern "C" void kernel_launch(void* const* d_in, const int* in_sizes, int n_in,
                              void* d_out, int out_size, void* d_ws, size_t ws_size,
                              hipStream_t stream)
{
    static const int EXP[23] = {1966080, 11, 11, 45056, 512, 2048, 2048,
        3145728, 6144, 1048576, 2048, 2048, 2048, 4194304, 8192, 4194304, 2048,
        3145728, 512, 65536, 128, 384, 3};
    static const int S2D[23] = {18, 20, 22, 17, 19, 21, 2, 1, 6, 5, 12, 11,
        14, 16, 13, 15, 10, 9, 4, 3, 8, 7, 0};
    const void* in[23];
    if (n_in != 23 || out_size != 12288) return;
    bool ok = true;
    for (int i = 0; i < 23; i++) ok = ok && (in_sizes[i] == EXP[i]);
    if (ok) {
        for (int i = 0; i < 23; i++) in[i] = d_in[i];
    } else {
        bool ok2 = true;
        for (int s = 0; s < 23; s++) ok2 = ok2 && (in_sizes[s] == EXP[S2D[s]]);
        if (!ok2) return;
        for (int s = 0; s < 23; s++) in[S2D[s]] = d_in[s];
    }
    const float* x      = (const float*)in[0];
    const float* in_w   = (const float*)in[1];
    const float* in_b   = (const float*)in[2];
    const float* pe_w   = (const float*)in[3];
    const float* pe_b   = (const float*)in[4];
    const float* ln1_w  = (const float*)in[5];
    const float* ln1_b  = (const float*)in[6];
    const float* qkv_w  = (const float*)in[7];
    const float* qkv_b  = (const float*)in[8];
    const float* out_w  = (const float*)in[9];
    const float* out_b  = (const float*)in[10];
    const float* ln2_w  = (const float*)in[11];
    const float* ln2_b  = (const float*)in[12];
    const float* mlp_w1 = (const float*)in[13];
    const float* mlp_b1 = (const float*)in[14];
    const float* mlp_w2 = (const float*)in[15];
    const float* mlp_b2 = (const float*)in[16];
    const float* cls_w1 = (const float*)in[17];
    const float* cls_b1 = (const float*)in[18];
    const float* cls_w2 = (const float*)in[19];
    const float* cls_b2 = (const float*)in[20];
    const float* cls_w3 = (const float*)in[21];
    const float* cls_b3 = (const float*)in[22];

    // ---- f16 weight arena (~31.7 MB) ----
    char* ws = (char*)d_ws;
    size_t off = 0;
    _Float16* wt_pe  = (_Float16*)(ws + off); off += (size_t)512 * 96 * 2;
    _Float16* wt_qkv = (_Float16*)(ws + off); off += (size_t)4 * 1536 * 512 * 2;
    _Float16* wt_out = (_Float16*)(ws + off); off += (size_t)4 * 512 * 512 * 2;
    _Float16* wt_m1  = (_Float16*)(ws + off); off += (size_t)4 * 2048 * 512 * 2;
    _Float16* wt_m2  = (_Float16*)(ws + off); off += (size_t)4 * 512 * 2048 * 2;
    _Float16* wt_c1  = (_Float16*)(ws + off); off += (size_t)512 * 6144 * 2;
    _Float16* wt_c2  = (_Float16*)(ws + off); off += (size_t)128 * 512 * 2;
    const size_t wbytes = off;

    // per-batch bytes = h32 24576 + abuf 12288 + bbuf 49152
    const size_t per = 86016 + 64;
    int CH = 2048;
    while (CH > 128 && wbytes + (size_t)CH * per > ws_size) CH >>= 1;
    const int nch = 4096 / CH;
    const int M = CH * 12;

    float*    h32  = (float*)(ws + off);    off += (size_t)M * 512 * 4;
    _Float16* abuf = (_Float16*)(ws + off); off += (size_t)M * 512 * 2;
    _Float16* bbuf = (_Float16*)(ws + off); off += (size_t)M * 2048 * 2;

    _Float16* feats = bbuf;                 // dead after pe GEMM
    _Float16* f1 = (_Float16*)h32;          // classifier temp (h32 dead then)
    float* part1 = (float*)bbuf;                          // 8*CH*512 fp32
    float* part2 = part1 + (size_t)8 * CH * 512;          // 4*CH*128 fp32

    // ---- weight prep: fp32 (K,N) -> f16 (N,Kpad) transposed, z-batched ----
    tr_k<<<dim3(16, 3, 1),   dim3(32, 8), 0, stream>>>(pe_w, wt_pe, 88, 512, 96, 0, 0);
    tr_k<<<dim3(48, 16, 4),  dim3(32, 8), 0, stream>>>(qkv_w, wt_qkv, 512, 1536, 512,
        (long long)512 * 1536, (long long)1536 * 512);
    tr_k<<<dim3(16, 16, 4),  dim3(32, 8), 0, stream>>>(out_w, wt_out, 512, 512, 512,
        (long long)512 * 512, (long long)512 * 512);
    tr_k<<<dim3(64, 16, 4),  dim3(32, 8), 0, stream>>>(mlp_w1, wt_m1, 512, 2048, 512,
        (long long)512 * 2048, (long long)2048 * 512);
    tr_k<<<dim3(16, 64, 4),  dim3(32, 8), 0, stream>>>(mlp_w2, wt_m2, 2048, 512, 2048,
        (long long)2048 * 512, (long long)512 * 2048);
    tr_k<<<dim3(16, 192, 1), dim3(32, 8), 0, stream>>>(cls_w1, wt_c1, 6144, 512, 6144, 0, 0);
    tr_k<<<dim3(4, 16, 1),   dim3(32, 8), 0, stream>>>(cls_w2, wt_c2, 512, 128, 512, 0, 0);

    for (int c = 0; c < nch; c++) {
        const float* xc = x + (size_t)c * CH * 480;
        factors_k<<<CH / 4, 384, 0, stream>>>(xc, in_w, in_b, feats, CH);
        gemm_f16g<<<dim3(4, M / 128), 256, 0, stream>>>(
            feats, wt_pe, pe_b, nullptr, h32, nullptr, M, 512, 96, 96, FLAG_W32);

        for (int i = 0; i < 4; i++) {
            ln_rows<<<M / 4, 256, 0, stream>>>(h32, ln1_w + i * 512, ln1_b + i * 512, abuf);
            gemm_f16g<<<dim3(12, M / 128), 256, 0, stream>>>(
                abuf, wt_qkv + (size_t)i * 1536 * 512, qkv_b + i * 1536,
                nullptr, nullptr, bbuf, M, 1536, 512, 512, FLAG_W16);
            attn_k<<<CH * 2, 256, 0, stream>>>(bbuf, abuf);
            gemm_f16g<<<dim3(4, M / 128), 256, 0, stream>>>(
                abuf, wt_out + (size_t)i * 512 * 512, out_b + i * 512,
                h32, h32, nullptr, M, 512, 512, 512, FLAG_RES | FLAG_W32);
            ln_rows<<<M / 4, 256, 0, stream>>>(h32, ln2_w + i * 512, ln2_b + i * 512, abuf);
            // mlp1: reg-staged variant (measured 100us vs 128us gload, r3/r5)
            gemm_f16<<<dim3(16, M / 128), 256, 0, stream>>>(
                abuf, wt_m1 + (size_t)i * 2048 * 512, mlp_b1 + i * 2048,
                nullptr, nullptr, bbuf, M, 2048, 512, 512, FLAG_W16 | FLAG_GELU);
            // at i==3 the fp32 residual stream is dead afterwards
            const int fl = FLAG_RES | (i == 3 ? FLAG_W16 : FLAG_W32);
            gemm_f16g<<<dim3(4, M / 128), 256, 0, stream>>>(
                bbuf, wt_m2 + (size_t)i * 512 * 2048, mlp_b2 + i * 512,
                h32, h32, abuf, M, 512, 2048, 2048, fl);
        }

        // classifier: abuf viewed as (CH, 6144) f16; split-K via fp32 partials
        gemm_f16g<<<dim3(4, CH / 128, 8), 256, 0, stream>>>(
            abuf, wt_c1, nullptr, nullptr, part1, nullptr, CH, 512, 6144, 768, FLAG_PART);
        skred_k<<<(CH * 512 + 255) / 256, 256, 0, stream>>>(
            part1, cls_b1, f1, CH * 512, 512, 8);
        gemm_f16g<<<dim3(1, CH / 128, 4), 256, 0, stream>>>(
            f1, wt_c2, nullptr, nullptr, part2, nullptr, CH, 128, 512, 128, FLAG_PART);
        skcls_k<<<CH / 4, 256, 0, stream>>>(
            part2, cls_b2, cls_w3, cls_b3, (float*)d_out + (size_t)c * CH * 3, CH);
    }
}

// Round 10
// 2640.973 us; speedup vs baseline: 1.4926x; 1.0097x over previous
//
#include <hip/hip_runtime.h>
#include <cstdint>
#include <cstddef>

typedef _Float16 half8 __attribute__((ext_vector_type(8)));
typedef _Float16 half4v __attribute__((ext_vector_type(4)));
typedef float floatx4 __attribute__((ext_vector_type(4)));

#define FLAG_RES  1
#define FLAG_GELU 2
#define FLAG_W32  4
#define FLAG_W16  8
#define FLAG_PART 16

// Fast exact-GELU: erf via Abramowitz-Stegun 7.1.25 (3-term, |err|<=2.5e-5).
__device__ __forceinline__ float gelu_exact(float x) {
    const float z = fabsf(x) * 0.70710678118654752f;
    const float t = __builtin_amdgcn_rcpf(fmaf(0.47047f, z, 1.f));
    const float p = t * (0.3480242f + t * (-0.0958798f + t * 0.7478556f));
    const float erfa = 1.f - p * __expf(-z * z);
    return 0.5f * x * (1.f + copysignf(erfa, x));
}

// async global->LDS (16B/lane): dest is wave-uniform base + lane*16.
typedef const __attribute__((address_space(1))) void GV;
typedef __attribute__((address_space(3))) void LV;
__device__ __forceinline__ void gl_lds16(const void* g, void* l) {
    __builtin_amdgcn_global_load_lds((GV*)g, (LV*)l, 16, 0, 0);
}

// XCD-aware chunked block swizzle (bijective when nwg % 8 == 0; identity
// otherwise). Verified r6: mlp1 FETCH_SIZE 101.5 -> 37 MB.
__device__ __forceinline__ void swz_bid(int& bx, int& by) {
    const int gx = gridDim.x;
    const int nwg = gx * gridDim.y;
    int id = blockIdx.y * gx + blockIdx.x;
    if ((nwg & 7) == 0) {
        const int q = nwg >> 3;
        id = (id & 7) * q + (id >> 3);
    }
    bx = id % gx;
    by = id / gx;
}

// Shared C^T epilogue (r9 verified): MFMA called as mfma(bf, af, acc) so the
// D fragment holds one M-row (lane15) x 4 consecutive N-cols (quad*4+r).
__device__ __forceinline__ void gemm_epilogue(
    floatx4 acc[4][4], const float* bias, const float* resid,
    float* out32, _Float16* out16, int M, int N,
    int bm, int bn, int wr, int wc, int lane15, int quad, int zslice,
    int flags)
{
    if (flags & FLAG_PART) {
        float* po = out32 + (size_t)zslice * ((size_t)M * N);
#pragma unroll
        for (int mi = 0; mi < 4; mi++) {
            const int gm = bm + wr * 64 + mi * 16 + lane15;
            float* pr = po + (size_t)gm * N + bn + wc * 64 + quad * 4;
#pragma unroll
            for (int ni = 0; ni < 4; ni++) {
                float4 v = {acc[mi][ni][0], acc[mi][ni][1],
                            acc[mi][ni][2], acc[mi][ni][3]};
                *(float4*)(pr + ni * 16) = v;
            }
        }
        return;
    }
    const int cn = bn + wc * 64 + quad * 4;
#pragma unroll
    for (int mi = 0; mi < 4; mi++) {
        const int gm = bm + wr * 64 + mi * 16 + lane15;
        const size_t rowoff = (size_t)gm * N + cn;
#pragma unroll
        for (int ni = 0; ni < 4; ni++) {
            const size_t off = rowoff + ni * 16;
            const float4 bv = *(const float4*)&bias[cn + ni * 16];
            float v[4] = {acc[mi][ni][0] + bv.x, acc[mi][ni][1] + bv.y,
                          acc[mi][ni][2] + bv.z, acc[mi][ni][3] + bv.w};
            if (flags & FLAG_GELU) {
#pragma unroll
                for (int r = 0; r < 4; r++) v[r] = gelu_exact(v[r]);
            }
            if (flags & FLAG_RES) {
                const float4 rv = *(const float4*)&resid[off];
                v[0] += rv.x; v[1] += rv.y; v[2] += rv.z; v[3] += rv.w;
            }
            if (flags & FLAG_W32) {
                float4 o = {v[0], v[1], v[2], v[3]};
                *(float4*)&out32[off] = o;
            }
            if (flags & FLAG_W16) {
                half4v h = {(_Float16)v[0], (_Float16)v[1],
                            (_Float16)v[2], (_Float16)v[3]};
                *(half4v*)&out16[off] = h;
            }
        }
    }
}

// ---------------------------------------------------------------------------
// GEMM (3-deep counted-vmcnt pipeline): C = A(MxK) @ Bt(NxK)^T + bias.
// 128x128 tile, BK=32, 256 thr. Staging via global_load_lds with
// pre-swizzled SOURCE chunk (r5-verified) into a 3-buffer LDS ring.
// Sync: raw s_barrier + explicit s_waitcnt vmcnt(4) -- tile t+1's loads
// stay IN FLIGHT across the barrier (never drained to 0 in the loop, the
// AITER pattern). At iter t: wait t's 4 loads (vmcnt(4)), barrier, issue
// t+2 into buf[(t+2)%3], read t, MFMA. Buffer t+2 == t-1 is safe: every
// wave's t-1 ds_reads retired before it reached this barrier.
// Cross-wave LDS visibility: each wave waits its OWN vmcnt before the
// barrier, so after the barrier all waves' tile-t writes are complete.
// "memory"-clobber asm + sched_barrier(0) pin ordering (guide rule #18).
// ---------------------------------------------------------------------------
__global__ __launch_bounds__(256, 2) void gemm_f16p(
    const _Float16* __restrict__ A, const _Float16* __restrict__ Bt,
    const float* __restrict__ bias, const float* __restrict__ resid,
    float* __restrict__ out32, _Float16* __restrict__ out16,
    int M, int N, int K, int klen, int flags)
{
    __shared__ __align__(16) _Float16 As[3][128 * 32];
    __shared__ __align__(16) _Float16 Bs[3][128 * 32];
    const int tid = threadIdx.x;
    const int wid = tid >> 6;
    const int lane = tid & 63;
    int bxs, bys;
    swz_bid(bxs, bys);
    const int bm = bys * 128;
    const int bn = bxs * 128;
    const int wr = wid >> 1, wc = wid & 1;
    const int lane15 = lane & 15, quad = lane >> 4;
    const int kb = blockIdx.z * klen;

    floatx4 acc[4][4];
#pragma unroll
    for (int i = 0; i < 4; i++)
#pragma unroll
        for (int j = 0; j < 4; j++)
            acc[i][j] = floatx4{0.f, 0.f, 0.f, 0.f};

    // staging map: lane -> row rr (16-row group), chunk ch; source chunk
    // pre-swizzled so the linear LDS dest ends up XOR-swizzled (r2: 0 conf).
    const int rr = lane >> 2;
    const int ch = lane & 3;
    const int cs = ch ^ ((rr >> 1) & 3);
    const _Float16* asrc0 = A + ((size_t)bm + wid * 32 + rr) * K + kb + cs * 8;
    const _Float16* asrc1 = asrc0 + (size_t)16 * K;
    const _Float16* bsrc0 = Bt + ((size_t)bn + wid * 32 + rr) * K + kb + cs * 8;
    const _Float16* bsrc1 = bsrc0 + (size_t)16 * K;

    int aoff[4], boff[4];
#pragma unroll
    for (int mi = 0; mi < 4; mi++)
        aoff[mi] = (wr * 64 + mi * 16 + lane15) * 32 +
                   ((quad ^ ((lane15 >> 1) & 3)) << 3);
#pragma unroll
    for (int ni = 0; ni < 4; ni++)
        boff[ni] = (wc * 64 + ni * 16 + lane15) * 32 +
                   ((quad ^ ((lane15 >> 1) & 3)) << 3);

    const int nk = klen >> 5;
    const int lbase = wid * 1024;

    // prologue: stage tiles 0 and 1 (4 vmem ops each, issue order matters)
    {
        _Float16* ab = &As[0][lbase];
        _Float16* bb = &Bs[0][lbase];
        gl_lds16(asrc0, ab);
        gl_lds16(asrc1, ab + 512);
        gl_lds16(bsrc0, bb);
        gl_lds16(bsrc1, bb + 512);
    }
    if (nk > 1) {
        _Float16* ab = &As[1][lbase];
        _Float16* bb = &Bs[1][lbase];
        gl_lds16(asrc0 + 32, ab);
        gl_lds16(asrc1 + 32, ab + 512);
        gl_lds16(bsrc0 + 32, bb);
        gl_lds16(bsrc1 + 32, bb + 512);
    }

    for (int ik = 0; ik < nk; ik++) {
        // wait tile ik's loads; keep tile ik+1's (if any) in flight
        if (ik + 1 < nk) {
            asm volatile("s_waitcnt vmcnt(4)" ::: "memory");
        } else {
            asm volatile("s_waitcnt vmcnt(0)" ::: "memory");
        }
        __builtin_amdgcn_sched_barrier(0);
        __builtin_amdgcn_s_barrier();
        __builtin_amdgcn_sched_barrier(0);
        if (ik + 2 < nk) {              // stage tile ik+2 into ring slot
            const int bufi = (ik + 2) % 3;
            const int ko = (ik + 2) << 5;
            _Float16* ab = &As[bufi][lbase];
            _Float16* bb = &Bs[bufi][lbase];
            gl_lds16(asrc0 + ko, ab);
            gl_lds16(asrc1 + ko, ab + 512);
            gl_lds16(bsrc0 + ko, bb);
            gl_lds16(bsrc1 + ko, bb + 512);
        }
        const _Float16* a_ = As[ik % 3];
        const _Float16* b_ = Bs[ik % 3];
        half8 af[4], bf[4];
#pragma unroll
        for (int mi = 0; mi < 4; mi++) af[mi] = *(const half8*)&a_[aoff[mi]];
#pragma unroll
        for (int ni = 0; ni < 4; ni++) bf[ni] = *(const half8*)&b_[boff[ni]];
#pragma unroll
        for (int mi = 0; mi < 4; mi++)
#pragma unroll
            for (int ni = 0; ni < 4; ni++)
                acc[mi][ni] = __builtin_amdgcn_mfma_f32_16x16x32_f16(
                    bf[ni], af[mi], acc[mi][ni], 0, 0, 0);  // C^T operand order
    }

    gemm_epilogue(acc, bias, resid, out32, out16, M, N,
                  bm, bn, wr, wc, lane15, quad, blockIdx.z, flags);
}

// ---------------------------------------------------------------------------
// Split-K reduce: out[i] = gelu(bias[i%N] + sum_z part[z*MN + i]) as f16.
// ---------------------------------------------------------------------------
__global__ __launch_bounds__(256) void skred_k(
    const float* __restrict__ part, const float* __restrict__ bias,
    _Float16* __restrict__ out, int MN, int N, int S)
{
    const int i = blockIdx.x * 256 + threadIdx.x;
    if (i >= MN) return;
    float s = bias[i % N];
    for (int z = 0; z < S; z++) s += part[(size_t)z * MN + i];
    out[i] = (_Float16)gelu_exact(s);
}

// ---------------------------------------------------------------------------
// Fused split-K reduce (S=4, N=128) + gelu + final (128x3) matmul + bias.
// ---------------------------------------------------------------------------
__global__ __launch_bounds__(256) void skcls_k(
    const float* __restrict__ part, const float* __restrict__ b2,
    const float* __restrict__ w3, const float* __restrict__ b3,
    float* __restrict__ out, int CH)
{
    const int wid = threadIdx.x >> 6, lane = threadIdx.x & 63;
    const int b = blockIdx.x * 4 + wid;
    const size_t MN = (size_t)CH * 128;
    const int c0 = lane, c1 = lane + 64;
    float s0 = b2[c0], s1 = b2[c1];
#pragma unroll
    for (int z = 0; z < 4; z++) {
        s0 += part[z * MN + (size_t)b * 128 + c0];
        s1 += part[z * MN + (size_t)b * 128 + c1];
    }
    const float g0 = gelu_exact(s0), g1 = gelu_exact(s1);
    float a0 = g0 * w3[c0 * 3 + 0] + g1 * w3[c1 * 3 + 0];
    float a1 = g0 * w3[c0 * 3 + 1] + g1 * w3[c1 * 3 + 1];
    float a2 = g0 * w3[c0 * 3 + 2] + g1 * w3[c1 * 3 + 2];
#pragma unroll
    for (int m = 32; m >= 1; m >>= 1) {
        a0 += __shfl_xor(a0, m, 64);
        a1 += __shfl_xor(a1, m, 64);
        a2 += __shfl_xor(a2, m, 64);
    }
    if (lane == 0) {
        out[b * 3 + 0] = a0 + b3[0];
        out[b * 3 + 1] = a1 + b3[1];
        out[b * 3 + 2] = a2 + b3[2];
    }
}

// ---------------------------------------------------------------------------
// Row LayerNorm over 512 cols: fp32 in, fp32 params, f16 out. One wave/row.
// ---------------------------------------------------------------------------
__global__ __launch_bounds__(256) void ln_rows(
    const float* __restrict__ x, const float* __restrict__ w,
    const float* __restrict__ b, _Float16* __restrict__ out)
{
    const int wid = threadIdx.x >> 6, lane = threadIdx.x & 63;
    const size_t row = (size_t)blockIdx.x * 4 + wid;
    const int c0 = lane * 8;
    const float* xr = x + row * 512 + c0;
    float4 v0 = *(const float4*)xr;
    float4 v1 = *(const float4*)(xr + 4);
    float xv[8] = {v0.x, v0.y, v0.z, v0.w, v1.x, v1.y, v1.z, v1.w};
    float s = 0.f, q = 0.f;
#pragma unroll
    for (int j = 0; j < 8; j++) { s += xv[j]; q += xv[j] * xv[j]; }
#pragma unroll
    for (int m = 32; m >= 1; m >>= 1) {
        s += __shfl_xor(s, m, 64);
        q += __shfl_xor(q, m, 64);
    }
    const float mean = s * (1.f / 512.f);
    const float rstd = rsqrtf(q * (1.f / 512.f) - mean * mean + 1e-5f);
    half8 o;
#pragma unroll
    for (int j = 0; j < 8; j++)
        o[j] = (_Float16)((xv[j] - mean) * rstd * w[c0 + j] + b[c0 + j]);
    *(half8*)&out[row * 512 + c0] = o;
}

// ---------------------------------------------------------------------------
// Attention via MFMA: 4 (b,head) units per 256-thr block, one wave each.
// (r7: verified)
// ---------------------------------------------------------------------------
__global__ __launch_bounds__(256) void attn_k(
    const _Float16* __restrict__ qkv, _Float16* __restrict__ o)
{
    __shared__ float patt[4][16][17];
    const int wid = threadIdx.x >> 6, lane = threadIdx.x & 63;
    const int unit = blockIdx.x * 4 + wid;
    const int b = unit >> 3, hd = unit & 7;
    const int lane15 = lane & 15, quad = lane >> 4;
    const _Float16* base = qkv + (size_t)b * 18432 + hd * 64;

    const int rq = lane15 < 12 ? lane15 : 11;
    const _Float16* qrow = base + (size_t)rq * 1536;
    half8 qa0 = *(const half8*)(qrow + quad * 8);
    half8 qa1 = *(const half8*)(qrow + 32 + quad * 8);
    half8 kb0 = *(const half8*)(qrow + 512 + quad * 8);
    half8 kb1 = *(const half8*)(qrow + 544 + quad * 8);
    floatx4 s = floatx4{0.f, 0.f, 0.f, 0.f};
    s = __builtin_amdgcn_mfma_f32_16x16x32_f16(qa0, kb0, s, 0, 0, 0);
    s = __builtin_amdgcn_mfma_f32_16x16x32_f16(qa1, kb1, s, 0, 0, 0);

    const bool kok = lane15 < 12;
    float p[4];
#pragma unroll
    for (int r = 0; r < 4; r++) {
        const float sv = s[r] * 0.125f;
        float mx = kok ? sv : -1e30f;
#pragma unroll
        for (int m = 1; m <= 8; m <<= 1)
            mx = fmaxf(mx, __shfl_xor(mx, m, 64));
        const float ev = kok ? __expf(sv - mx) : 0.f;
        float ss = ev;
#pragma unroll
        for (int m = 1; m <= 8; m <<= 1)
            ss += __shfl_xor(ss, m, 64);
        p[r] = ev * __builtin_amdgcn_rcpf(ss);
    }
#pragma unroll
    for (int r = 0; r < 4; r++)
        patt[wid][quad * 4 + r][lane15] = p[r];

    half8 pa;
#pragma unroll
    for (int j = 0; j < 8; j++) {
        const int kj = quad * 8 + j;
        pa[j] = (quad < 2) ? (_Float16)patt[wid][lane15][kj & 15]
                           : (_Float16)0.f;
    }

    const _Float16* vbase = base + 1024;
    floatx4 oacc[4];
#pragma unroll
    for (int ni = 0; ni < 4; ni++) {
        half8 vb;
#pragma unroll
        for (int j = 0; j < 8; j++) {
            int kv = quad * 8 + j;
            if (kv > 11) kv = 11;
            vb[j] = vbase[(size_t)kv * 1536 + ni * 16 + lane15];
        }
        oacc[ni] = __builtin_amdgcn_mfma_f32_16x16x32_f16(
            pa, vb, floatx4{0.f, 0.f, 0.f, 0.f}, 0, 0, 0);
    }
    _Float16* ob = o + (size_t)b * 6144 + hd * 64;
#pragma unroll
    for (int r = 0; r < 4; r++) {
        const int qi = quad * 4 + r;
        if (qi < 12) {
#pragma unroll
            for (int ni = 0; ni < 4; ni++)
                ob[(size_t)qi * 512 + ni * 16 + lane15] = (_Float16)oacc[ni][r];
        }
    }
}

// ---------------------------------------------------------------------------
// t-PARALLEL factors + time-norm -> (CH*12, 96) f16 patch rows. (r8 verified)
// ---------------------------------------------------------------------------
__global__ __launch_bounds__(384) void factors_k(
    const float* __restrict__ x, const float* __restrict__ in_w,
    const float* __restrict__ in_b, _Float16* __restrict__ feats, int CH)
{
    __shared__ __align__(16) float cls[4][96];
    __shared__ __align__(16) float vls[4][96];
    __shared__ __align__(16) float scratch[4224];
    __shared__ float sstat[4][11][2];

    const int rt = threadIdx.x;
    const int row = rt / 96;
    const int t = rt - row * 96;
    const int b = blockIdx.x * 4 + row;

    const float a12 = 2.f / 13.f, a26 = 2.f / 27.f, a14 = 1.f / 14.f;

    const float* xq = x + ((size_t)b * 96 + t) * 5;
    const float f0 = xq[0], f1 = xq[1], f2 = xq[2], c = xq[3], v = xq[4];
    cls[row][t] = c;
    vls[row][t] = v;
    __syncthreads();

    const float cp = t > 0 ? cls[row][t - 1] : 0.f;
    const float vpr = t > 0 ? vls[row][t - 1] : 0.f;
    const float sv = v > 0.f ? v : 1.f;
    const float delta = t > 0 ? c - cp : 0.f;
    const float gain = fmaxf(delta, 0.f), loss = fmaxf(-delta, 0.f);
    float lr = 0.f, lv = 0.f;
    if (t > 0) {
        lr = logf(fmaxf(c, 1e-8f) / fmaxf(cp, 1e-8f));
        const float svp = vpr > 0.f ? vpr : 1.f;
        lv = logf(sv / (svp + 1e-8f));
    }

    float* sm = scratch;
    float* sb = scratch + 1536;
    const int i0 = row * 96 + t;
    sm[0 * 384 + i0] = t ? (1.f - a12) : 0.f;  sb[0 * 384 + i0] = t ? a12 * c : c;
    sm[1 * 384 + i0] = t ? (1.f - a26) : 0.f;  sb[1 * 384 + i0] = t ? a26 * c : c;
    sm[2 * 384 + i0] = t ? (1.f - a14) : 0.f;  sb[2 * 384 + i0] = t ? a14 * gain : 0.f;
    sm[3 * 384 + i0] = t ? (1.f - a14) : 0.f;  sb[3 * 384 + i0] = t ? a14 * loss : 0.f;
    __syncthreads();
#pragma unroll
    for (int s = 1; s < 96; s <<= 1) {
        float pm[4], pb[4];
        const bool act = (t >= s);
        if (act) {
            const int ip = i0 - s;
#pragma unroll
            for (int sc = 0; sc < 4; sc++) {
                pm[sc] = sm[sc * 384 + ip];
                pb[sc] = sb[sc * 384 + ip];
            }
        }
        __syncthreads();
        if (act) {
#pragma unroll
            for (int sc = 0; sc < 4; sc++) {
                const float m2 = sm[sc * 384 + i0];
                const float b2 = sb[sc * 384 + i0];
                sm[sc * 384 + i0] = pm[sc] * m2;
                sb[sc * 384 + i0] = fmaf(m2, pb[sc], b2);
            }
        }
        __syncthreads();
    }
    const float e12 = sb[0 * 384 + i0];
    const float e26 = sb[1 * 384 + i0];
    const float ag  = sb[2 * 384 + i0];
    const float al  = sb[3 * 384 + i0];

    const float macd = e12 - e26;
    const float rs = ag / (al + 1e-10f);
    const float rsi = (100.f - 100.f / (1.f + rs)) * 0.01f;

    float bb = 0.f, vmr = 1.f;
    if (t >= 19) {
        float s1c = 0.f, s2c = 0.f, s1v = 0.f;
#pragma unroll
        for (int k = 0; k < 20; k++) {
            const float cc = cls[row][t - k];
            const float vv = vls[row][t - k];
            s1c += cc; s2c += cc * cc; s1v += vv > 0.f ? vv : 1.f;
        }
        const float mean = s1c * 0.05f;
        const float sq = s2c * 0.05f;
        const float sd = sqrtf(fmaxf(sq - mean * mean, 0.f));
        bb = 4.f * sd / (mean + 1e-8f);
        vmr = sv / (s1v * 0.05f + 1e-8f);
    }

    float fvv[11];
    fvv[0] = f0; fvv[1] = f1; fvv[2] = f2; fvv[3] = c; fvv[4] = v;
    fvv[5] = isfinite(macd) ? macd : 0.f;
    fvv[6] = isfinite(rsi) ? rsi : 0.f;
    fvv[7] = isfinite(bb) ? bb : 0.f;
    fvv[8] = isfinite(lr) ? lr : 0.f;
    fvv[9] = isfinite(lv) ? lv : 0.f;
    fvv[10] = isfinite(vmr) ? vmr : 0.f;

    __syncthreads();
    float* fv = scratch;
#pragma unroll
    for (int f = 0; f < 11; f++)
        fv[(row * 11 + f) * 96 + t] = fvv[f];
    __syncthreads();

    if (t < 11) {
        const float* p = &fv[(row * 11 + t) * 96];
        float s = 0.f, q = 0.f;
        for (int k = 0; k < 96; k++) { const float u = p[k]; s += u; q += u * u; }
        const float m = s * (1.f / 96.f);
        const float var = q * (1.f / 96.f) - m * m;
        const float r = rsqrtf(var + 1e-5f);
        const float sc = r * in_w[t];
        sstat[row][t][0] = sc;
        sstat[row][t][1] = in_b[t] - m * sc;
    }
    __syncthreads();

    _Float16* orow = feats + (size_t)b * 1152 + (t >> 3) * 96;
    _Float16* op = orow + (t & 7) * 11;
#pragma unroll
    for (int f = 0; f < 11; f++)
        op[f] = (_Float16)(fv[(row * 11 + f) * 96 + t] * sstat[row][f][0] +
                           sstat[row][f][1]);
    if ((t & 7) == 0) {
        const int4 z4 = {0, 0, 0, 0};
        *(int4*)(orow + 88) = z4;
    }
}

// ---------------------------------------------------------------------------
// Tiled transpose + cast, z-batched: W (K x N) fp32 -> Wt (N x Kpad) f16.
// ---------------------------------------------------------------------------
__global__ __launch_bounds__(256) void tr_k(
    const float* __restrict__ W, _Float16* __restrict__ Wt,
    int K, int N, int Kpad, long long ss, long long ds)
{
    W  += (size_t)blockIdx.z * ss;
    Wt += (size_t)blockIdx.z * ds;
    __shared__ _Float16 t[32][33];
    const int n0 = blockIdx.x * 32, k0 = blockIdx.y * 32;
#pragma unroll
    for (int j = 0; j < 4; j++) {
        const int k = k0 + threadIdx.y + j * 8;
        t[threadIdx.y + j * 8][threadIdx.x] =
            (k < K) ? (_Float16)W[(size_t)k * N + n0 + threadIdx.x] : (_Float16)0.f;
    }
    __syncthreads();
#pragma unroll
    for (int j = 0; j < 4; j++) {
        const int n = n0 + threadIdx.y + j * 8;
        Wt[(size_t)n * Kpad + k0 + threadIdx.x] = t[threadIdx.x][threadIdx.y + j * 8];
    }
}

// ---------------------------------------------------------------------------
extern "C" void kernel_launch(void* const* d_in, const int* in_sizes, int n_in,
                              void* d_out, int out_size, void* d_ws, size_t ws_size,
                              hipStream_t stream)
{
    static const int EXP[23] = {1966080, 11, 11, 45056, 512, 2048, 2048,
        3145728, 6144, 1048576, 2048, 2048, 2048, 4194304, 8192, 4194304, 2048,
        3145728, 512, 65536, 128, 384, 3};
    static const int S2D[23] = {18, 20, 22, 17, 19, 21, 2, 1, 6, 5, 12, 11,
        14, 16, 13, 15, 10, 9, 4, 3, 8, 7, 0};
    const void* in[23];
    if (n_in != 23 || out_size != 12288) return;
    bool ok = true;
    for (int i = 0; i < 23; i++) ok = ok && (in_sizes[i] == EXP[i]);
    if (ok) {
        for (int i = 0; i < 23; i++) in[i] = d_in[i];
    } else {
        bool ok2 = true;
        for (int s = 0; s < 23; s++) ok2 = ok2 && (in_sizes[s] == EXP[S2D[s]]);
        if (!ok2) return;
        for (int s = 0; s < 23; s++) in[S2D[s]] = d_in[s];
    }
    const float* x      = (const float*)in[0];
    const float* in_w   = (const float*)in[1];
    const float* in_b   = (const float*)in[2];
    const float* pe_w   = (const float*)in[3];
    const float* pe_b   = (const float*)in[4];
    const float* ln1_w  = (const float*)in[5];
    const float* ln1_b  = (const float*)in[6];
    const float* qkv_w  = (const float*)in[7];
    const float* qkv_b  = (const float*)in[8];
    const float* out_w  = (const float*)in[9];
    const float* out_b  = (const float*)in[10];
    const float* ln2_w  = (const float*)in[11];
    const float* ln2_b  = (const float*)in[12];
    const float* mlp_w1 = (const float*)in[13];
    const float* mlp_b1 = (const float*)in[14];
    const float* mlp_w2 = (const float*)in[15];
    const float* mlp_b2 = (const float*)in[16];
    const float* cls_w1 = (const float*)in[17];
    const float* cls_b1 = (const float*)in[18];
    const float* cls_w2 = (const float*)in[19];
    const float* cls_b2 = (const float*)in[20];
    const float* cls_w3 = (const float*)in[21];
    const float* cls_b3 = (const float*)in[22];

    // ---- f16 weight arena (~31.7 MB) ----
    char* ws = (char*)d_ws;
    size_t off = 0;
    _Float16* wt_pe  = (_Float16*)(ws + off); off += (size_t)512 * 96 * 2;
    _Float16* wt_qkv = (_Float16*)(ws + off); off += (size_t)4 * 1536 * 512 * 2;
    _Float16* wt_out = (_Float16*)(ws + off); off += (size_t)4 * 512 * 512 * 2;
    _Float16* wt_m1  = (_Float16*)(ws + off); off += (size_t)4 * 2048 * 512 * 2;
    _Float16* wt_m2  = (_Float16*)(ws + off); off += (size_t)4 * 512 * 2048 * 2;
    _Float16* wt_c1  = (_Float16*)(ws + off); off += (size_t)512 * 6144 * 2;
    _Float16* wt_c2  = (_Float16*)(ws + off); off += (size_t)128 * 512 * 2;
    const size_t wbytes = off;

    // per-batch bytes = h32 24576 + abuf 12288 + bbuf 49152
    const size_t per = 86016 + 64;
    int CH = 2048;
    while (CH > 128 && wbytes + (size_t)CH * per > ws_size) CH >>= 1;
    const int nch = 4096 / CH;
    const int M = CH * 12;

    float*    h32  = (float*)(ws + off);    off += (size_t)M * 512 * 4;
    _Float16* abuf = (_Float16*)(ws + off); off += (size_t)M * 512 * 2;
    _Float16* bbuf = (_Float16*)(ws + off); off += (size_t)M * 2048 * 2;

    _Float16* feats = bbuf;                 // dead after pe GEMM
    _Float16* f1 = (_Float16*)h32;          // classifier temp (h32 dead then)
    float* part1 = (float*)bbuf;                          // 8*CH*512 fp32
    float* part2 = part1 + (size_t)8 * CH * 512;          // 4*CH*128 fp32

    // ---- weight prep: fp32 (K,N) -> f16 (N,Kpad) transposed, z-batched ----
    tr_k<<<dim3(16, 3, 1),   dim3(32, 8), 0, stream>>>(pe_w, wt_pe, 88, 512, 96, 0, 0);
    tr_k<<<dim3(48, 16, 4),  dim3(32, 8), 0, stream>>>(qkv_w, wt_qkv, 512, 1536, 512,
        (long long)512 * 1536, (long long)1536 * 512);
    tr_k<<<dim3(16, 16, 4),  dim3(32, 8), 0, stream>>>(out_w, wt_out, 512, 512, 512,
        (long long)512 * 512, (long long)512 * 512);
    tr_k<<<dim3(64, 16, 4),  dim3(32, 8), 0, stream>>>(mlp_w1, wt_m1, 512, 2048, 512,
        (long long)512 * 2048, (long long)2048 * 512);
    tr_k<<<dim3(16, 64, 4),  dim3(32, 8), 0, stream>>>(mlp_w2, wt_m2, 2048, 512, 2048,
        (long long)2048 * 512, (long long)512 * 2048);
    tr_k<<<dim3(16, 192, 1), dim3(32, 8), 0, stream>>>(cls_w1, wt_c1, 6144, 512, 6144, 0, 0);
    tr_k<<<dim3(4, 16, 1),   dim3(32, 8), 0, stream>>>(cls_w2, wt_c2, 512, 128, 512, 0, 0);

    for (int c = 0; c < nch; c++) {
        const float* xc = x + (size_t)c * CH * 480;
        factors_k<<<CH / 4, 384, 0, stream>>>(xc, in_w, in_b, feats, CH);
        gemm_f16p<<<dim3(4, M / 128), 256, 0, stream>>>(
            feats, wt_pe, pe_b, nullptr, h32, nullptr, M, 512, 96, 96, FLAG_W32);

        for (int i = 0; i < 4; i++) {
            ln_rows<<<M / 4, 256, 0, stream>>>(h32, ln1_w + i * 512, ln1_b + i * 512, abuf);
            gemm_f16p<<<dim3(12, M / 128), 256, 0, stream>>>(
                abuf, wt_qkv + (size_t)i * 1536 * 512, qkv_b + i * 1536,
                nullptr, nullptr, bbuf, M, 1536, 512, 512, FLAG_W16);
            attn_k<<<CH * 2, 256, 0, stream>>>(bbuf, abuf);
            gemm_f16p<<<dim3(4, M / 128), 256, 0, stream>>>(
                abuf, wt_out + (size_t)i * 512 * 512, out_b + i * 512,
                h32, h32, nullptr, M, 512, 512, 512, FLAG_RES | FLAG_W32);
            ln_rows<<<M / 4, 256, 0, stream>>>(h32, ln2_w + i * 512, ln2_b + i * 512, abuf);
            gemm_f16p<<<dim3(16, M / 128), 256, 0, stream>>>(
                abuf, wt_m1 + (size_t)i * 2048 * 512, mlp_b1 + i * 2048,
                nullptr, nullptr, bbuf, M, 2048, 512, 512, FLAG_W16 | FLAG_GELU);
            // at i==3 the fp32 residual stream is dead afterwards
            const int fl = FLAG_RES | (i == 3 ? FLAG_W16 : FLAG_W32);
            gemm_f16p<<<dim3(4, M / 128), 256, 0, stream>>>(
                bbuf, wt_m2 + (size_t)i * 512 * 2048, mlp_b2 + i * 512,
                h32, h32, abuf, M, 512, 2048, 2048, fl);
        }

        // classifier: abuf viewed as (CH, 6144) f16; split-K via fp32 partials
        gemm_f16p<<<dim3(4, CH / 128, 8), 256, 0, stream>>>(
            abuf, wt_c1, nullptr, nullptr, part1, nullptr, CH, 512, 6144, 768, FLAG_PART);
        skred_k<<<(CH * 512 + 255) / 256, 256, 0, stream>>>(
            part1, cls_b1, f1, CH * 512, 512, 8);
        gemm_f16p<<<dim3(1, CH / 128, 4), 256, 0, stream>>>(
            f1, wt_c2, nullptr, nullptr, part2, nullptr, CH, 128, 512, 128, FLAG_PART);
        skcls_k<<<CH / 4, 256, 0, stream>>>(
            part2, cls_b2, cls_w3, cls_b3, (float*)d_out + (size_t)c * CH * 3, CH);
    }
}